// Round 14
// baseline (579.817 us; speedup 1.0000x reference)
//
#include <hip/hip_runtime.h>

typedef __attribute__((ext_vector_type(8))) __bf16 bf16x8;
typedef __attribute__((ext_vector_type(4))) float f32x4;
typedef __attribute__((ext_vector_type(4))) unsigned int u32x4;
typedef __attribute__((ext_vector_type(4))) unsigned short u16x4;
typedef __attribute__((ext_vector_type(8))) unsigned short u16x8;

__device__ __forceinline__ unsigned short f2bf(float x) {
  unsigned u = __builtin_bit_cast(unsigned, x);
  u += 0x7fffu + ((u >> 16) & 1u);
  return (unsigned short)(u >> 16);
}
__device__ __forceinline__ float bf2f(unsigned short h) {
  unsigned u = ((unsigned)h) << 16;
  return __builtin_bit_cast(float, u);
}
__device__ __forceinline__ bf16x8 ld_frag(const unsigned short* p) {
  u32x4 u = *(const u32x4*)p;
  return __builtin_bit_cast(bf16x8, u);
}
__device__ __forceinline__ void gload_lds16(const unsigned short* g, unsigned short* l) {
  __builtin_amdgcn_global_load_lds(
      (const __attribute__((address_space(1))) void*)g,
      (__attribute__((address_space(3))) void*)l, 16, 0, 0);
}

// ---------------- f32 -> bf16 conversion (vectorized) ----------------
__global__ __launch_bounds__(256) void cvt_bf16(const float* __restrict__ in,
                                                unsigned short* __restrict__ out, int n4) {
  int i = blockIdx.x * 256 + threadIdx.x;
  if (i >= n4) return;
  f32x4 v = *((const f32x4*)in + i);
  u16x4 o;
  #pragma unroll
  for (int j = 0; j < 4; ++j) o[j] = f2bf(v[j]);
  *((u16x4*)out + i) = o;
}

// ---- 8-phase GEMM, 4M x 2N wave map (unchanged r12) ----
template <int MODE>
__global__ __launch_bounds__(512, 2) void gemm8p(const unsigned short* __restrict__ A,
                                                 const unsigned short* __restrict__ B,
                                                 void* __restrict__ Cv,
                                                 const float* __restrict__ cs,
                                                 const float* __restrict__ sn,
                                                 int M, int N, int K) {
  __shared__ __align__(16) unsigned short SM[57344];  // 112 KB
  const int nwg = gridDim.x;
  const int swz = (blockIdx.x & 7) * (nwg >> 3) + (blockIdx.x >> 3);
  const int bx = swz & 15, by = swz >> 4;      // M/256 == 16 for both GEMMs
  const int row0 = bx * 256, col0 = by * 192;
  const int tid = threadIdx.x;
  const int wave = tid >> 6, lane = tid & 63;
  const int g = lane >> 4, r = lane & 15;
  const int wm = (wave >> 1) * 64, wn = (wave & 1) * 96;
  const int NT = K >> 6;

  const unsigned short* Agb = A + (size_t)row0 * K;
  const unsigned short* Bgb = B + (size_t)col0 * K;

  f32x4 acc[4][6] = {};

  auto SU = [&](const unsigned short* src, unsigned short* dst, int u) {
    const int pos = u * 512 + tid;
    const int rw = pos >> 3, cc = pos & 7;
    gload_lds16(src + (size_t)rw * K + ((cc ^ (rw & 7)) * 8), dst + pos * 8);
  };
  auto LDA = [&](const unsigned short* base, int mi, int dk) {
    const int rw = wm + mi * 16 + r;
    return ld_frag(base + rw * 64 + (((dk * 4 + g) ^ (r & 7)) * 8));
  };
  auto LDB = [&](const unsigned short* base, int ni, int dk) {
    const int rw = wn + ni * 16 + r;
    return ld_frag(base + rw * 64 + (((dk * 4 + g) ^ (r & 7)) * 8));
  };

  SU(Agb, SM, 0); SU(Agb, SM, 1); SU(Agb, SM, 2); SU(Agb, SM, 3);
  SU(Bgb, SM + 16384, 0); SU(Bgb, SM + 16384, 1); SU(Bgb, SM + 16384, 2);
  __syncthreads();

  for (int t = 0; t < NT; ++t) {
    const int d = t & 1;
    const unsigned short* Ab = SM + d * 28672;
    const unsigned short* Bb = Ab + 16384;
    unsigned short* An = SM + (d ^ 1) * 28672;
    unsigned short* Bn = An + 16384;
    const unsigned short* Asrc = Agb + (t + 1) * 64;
    const unsigned short* Bsrc = Bgb + (t + 1) * 64;
    const bool pf = (t + 1 < NT);

    bf16x8 a0, a1, b[6];

    b[0] = LDB(Bb, 0, 0); b[1] = LDB(Bb, 1, 0); b[2] = LDB(Bb, 2, 0);
    b[3] = LDB(Bb, 3, 0); b[4] = LDB(Bb, 4, 0); b[5] = LDB(Bb, 5, 0);
    a0 = LDA(Ab, 0, 0); a1 = LDA(Ab, 1, 0);
    if (pf) { SU(Asrc, An, 0); SU(Asrc, An, 1); SU(Asrc, An, 2); }
    __builtin_amdgcn_s_barrier();
    asm volatile("s_waitcnt lgkmcnt(0)" ::: "memory");
    __builtin_amdgcn_sched_barrier(0);
    __builtin_amdgcn_s_setprio(1);
    #pragma unroll
    for (int n = 0; n < 6; ++n) {
      acc[0][n] = __builtin_amdgcn_mfma_f32_16x16x32_bf16(a0, b[n], acc[0][n], 0, 0, 0);
      acc[1][n] = __builtin_amdgcn_mfma_f32_16x16x32_bf16(a1, b[n], acc[1][n], 0, 0, 0);
    }
    __builtin_amdgcn_s_setprio(0);
    __builtin_amdgcn_s_barrier();

    a0 = LDA(Ab, 2, 0); a1 = LDA(Ab, 3, 0);
    if (pf) { SU(Asrc, An, 3); SU(Bsrc, Bn, 0); }
    __builtin_amdgcn_s_barrier();
    asm volatile("s_waitcnt lgkmcnt(0)" ::: "memory");
    __builtin_amdgcn_sched_barrier(0);
    __builtin_amdgcn_s_setprio(1);
    #pragma unroll
    for (int n = 0; n < 6; ++n) {
      acc[2][n] = __builtin_amdgcn_mfma_f32_16x16x32_bf16(a0, b[n], acc[2][n], 0, 0, 0);
      acc[3][n] = __builtin_amdgcn_mfma_f32_16x16x32_bf16(a1, b[n], acc[3][n], 0, 0, 0);
    }
    __builtin_amdgcn_s_setprio(0);
    __builtin_amdgcn_s_barrier();

    b[0] = LDB(Bb, 0, 1); b[1] = LDB(Bb, 1, 1); b[2] = LDB(Bb, 2, 1);
    b[3] = LDB(Bb, 3, 1); b[4] = LDB(Bb, 4, 1); b[5] = LDB(Bb, 5, 1);
    a0 = LDA(Ab, 0, 1); a1 = LDA(Ab, 1, 1);
    if (pf) { SU(Bsrc, Bn, 1); SU(Bsrc, Bn, 2); }
    __builtin_amdgcn_s_barrier();
    asm volatile("s_waitcnt lgkmcnt(0)" ::: "memory");
    __builtin_amdgcn_sched_barrier(0);
    __builtin_amdgcn_s_setprio(1);
    #pragma unroll
    for (int n = 0; n < 6; ++n) {
      acc[0][n] = __builtin_amdgcn_mfma_f32_16x16x32_bf16(a0, b[n], acc[0][n], 0, 0, 0);
      acc[1][n] = __builtin_amdgcn_mfma_f32_16x16x32_bf16(a1, b[n], acc[1][n], 0, 0, 0);
    }
    __builtin_amdgcn_s_setprio(0);
    __builtin_amdgcn_s_barrier();

    a0 = LDA(Ab, 2, 1); a1 = LDA(Ab, 3, 1);
    __builtin_amdgcn_s_barrier();
    asm volatile("s_waitcnt lgkmcnt(0)" ::: "memory");
    __builtin_amdgcn_sched_barrier(0);
    __builtin_amdgcn_s_setprio(1);
    #pragma unroll
    for (int n = 0; n < 6; ++n) {
      acc[2][n] = __builtin_amdgcn_mfma_f32_16x16x32_bf16(a0, b[n], acc[2][n], 0, 0, 0);
      acc[3][n] = __builtin_amdgcn_mfma_f32_16x16x32_bf16(a1, b[n], acc[3][n], 0, 0, 0);
    }
    __builtin_amdgcn_s_setprio(0);
    asm volatile("s_waitcnt vmcnt(0)" ::: "memory");
    __builtin_amdgcn_s_barrier();
  }

  if (MODE == 0) {
    float* outp = (float*)Cv;
    #pragma unroll
    for (int mi = 0; mi < 4; ++mi)
      #pragma unroll
      for (int n = 0; n < 6; ++n)
        #pragma unroll
        for (int rr = 0; rr < 4; ++rr) {
          const size_t idx = (size_t)(row0 + wm + mi * 16 + g * 4 + rr) * (size_t)N
                           + (col0 + wn + n * 16 + r);
          outp[idx] = acc[mi][n][rr];
        }
  } else {
    unsigned short* outp = (unsigned short*)Cv;
    const int hc0 = col0 + wn;               // head-aligned (multiple of 96)
    if (hc0 < 3840) {                        // Q or K head: fused RoPE
      #pragma unroll
      for (int mi = 0; mi < 4; ++mi)
        #pragma unroll
        for (int rr = 0; rr < 4; ++rr) {
          const int row = row0 + wm + mi * 16 + g * 4 + rr;
          const int cb = row * 96;
          const size_t rb = (size_t)row * N + hc0;
          #pragma unroll
          for (int n = 0; n < 3; ++n) {
            const int d = n * 16 + r;
            const float x1 = acc[mi][n][rr], x2 = acc[mi][n + 3][rr];
            const float c1 = cs[cb + d], s1 = sn[cb + d];
            const float c2 = cs[cb + d + 48], s2 = sn[cb + d + 48];
            outp[rb + d]      = f2bf(x1 * c1 - x2 * s1);
            outp[rb + d + 48] = f2bf(x2 * c2 + x1 * s2);
          }
        }
    } else {                                 // V head: plain bf16
      #pragma unroll
      for (int mi = 0; mi < 4; ++mi)
        #pragma unroll
        for (int n = 0; n < 6; ++n)
          #pragma unroll
          for (int rr = 0; rr < 4; ++rr) {
            const size_t idx = (size_t)(row0 + wm + mi * 16 + g * 4 + rr) * (size_t)N
                             + (col0 + wn + n * 16 + r);
            outp[idx] = f2bf(acc[mi][n][rr]);
          }
    }
  }
}

// ---------------- V transpose: qkv[b,s,3840+kvh*96+d] -> vt[b,kvh,d,s] ----------------
__global__ __launch_bounds__(256) void vtrans(const unsigned short* __restrict__ qkv,
                                              unsigned short* __restrict__ vt) {
  __shared__ __align__(16) unsigned short T[64 * 104];
  const int s0 = blockIdx.x * 64;
  const int kvh = blockIdx.y, b = blockIdx.z;
  const int tid = threadIdx.x;
  #pragma unroll
  for (int it = 0; it < 3; ++it) {
    const int c = it * 256 + tid;
    const int sr = c / 12, d0 = (c % 12) * 8;
    *(u32x4*)&T[sr * 104 + d0] =
        *(const u32x4*)&qkv[(size_t)(b * 2048 + s0 + sr) * 4608 + 3840 + kvh * 96 + d0];
  }
  __syncthreads();
  #pragma unroll
  for (int it = 0; it < 3; ++it) {
    const int c = it * 256 + tid;
    const int dr = c >> 3, k0 = (c & 7) * 8;
    u16x8 o;
    #pragma unroll
    for (int j = 0; j < 8; ++j) o[j] = T[(k0 + j) * 104 + dr];
    *(u16x8*)&vt[((size_t)(b * 8 + kvh) * 96 + dr) * 2048 + s0 + k0] = o;
  }
}

// ---------------- Flash attention, causal GQA, swapped QK^T ----------------
// r14: r12 attn body (V in LDS — V-from-global refuted r13), but grid = 512
// FULL-SIZE blocks so 2 can co-reside per CU (r13 showed grid=256 caps
// occupancy at 1 block/CU regardless of resources). Fold-pair unfolded across
// dispatch halves: wg<256 -> qt=7-pr (heavy), wg>=256 -> qt=pr (light);
// pair sums uniform (36 tile-units per CU), same XCD bits. (512,4) forces
// VGPR<=128 so 16 waves/CU fit; LDS 80KB x2 = exactly 160KiB.
__global__ __launch_bounds__(512, 4) void attn_fwd(const unsigned short* __restrict__ qkv,
                                                   const unsigned short* __restrict__ vt,
                                                   unsigned short* __restrict__ ctx) {
  __shared__ __align__(16) unsigned short SMEM[40960];  // 80 KB
  const int wg = blockIdx.x;             // 0..511
  const int half = wg >> 8;              // 0 = heavy, 1 = light
  const int w = wg & 255;
  const int xcd = w & 7, j = w >> 3;     // j 0..31
  const int c = xcd + ((j >> 4) << 3);   // (b,kvh) id, 0..15
  const int b = c >> 3, kvh = c & 7;
  const int rj = j & 15;
  const int h = kvh * 4 + (rj >> 2);
  const int pr = rj & 3;
  const int qt = half ? pr : 7 - pr;
  const int nt = qt * 4 + 4;
  const int tid = threadIdx.x;
  const int wave = tid >> 6, lane = tid & 63;
  const int g = lane >> 4, r = lane & 15;
  const int q0 = qt * 256 + wave * 32;
  const float kLS = 0.14724445f;         // (1/sqrt(96)) * log2(e)

  const unsigned short* kgbase = qkv + (size_t)(b * 2048) * 4608 + 3072 + kvh * 96;
  const unsigned short* vgbase = vt + (size_t)(b * 8 + kvh) * 96 * 2048;

  // STAGE tile t into buffer bi: K 768 + V 768 chunks, 3 iters x 512 thr
  auto STAGE = [&](int t, int bi) {
    const int kv0 = t * 64;
    unsigned short* kd = SMEM + bi * 6144;
    unsigned short* vd = SMEM + 12288 + bi * 6144;
    #pragma unroll
    for (int i = 0; i < 3; ++i) {
      const int l = i * 512 + tid;
      if (l < 768) {  // K: [dk][row][c], src chunk c^((row>>1)&3)
        const int dk = l >> 8, rem = l & 255;
        const int row = rem >> 2, cc = rem & 3;
        const int csrc = cc ^ ((row >> 1) & 3);
        gload_lds16(kgbase + (size_t)(kv0 + row) * 4608 + dk * 32 + csrc * 8, kd + l * 8);
      } else {        // V: [row][c], src chunk c^(row&7)
        const int lv = l - 768;
        const int row = lv >> 3, cc = lv & 7;
        const int csrc = cc ^ (row & 7);
        gload_lds16(vgbase + (size_t)row * 2048 + kv0 + csrc * 8, vd + lv * 8);
      }
    }
  };

  bf16x8 qf[2][3];
  #pragma unroll
  for (int qb = 0; qb < 2; ++qb)
    #pragma unroll
    for (int dk = 0; dk < 3; ++dk)
      qf[qb][dk] = ld_frag(&qkv[(size_t)(b * 2048 + q0 + qb * 16 + r) * 4608 + h * 96 + dk * 32 + g * 8]);

  f32x4 o[6][2] = {};
  float m_[2] = {-1e30f, -1e30f};
  float l_[2] = {0.f, 0.f};

  STAGE(0, 0);
  __syncthreads();

  for (int t = 0; t < nt; ++t) {
    const int cur = t & 1;
    if (t + 1 < nt) STAGE(t + 1, cur ^ 1);
    const int kv0 = t * 64;
    const unsigned short* Ks = SMEM + cur * 6144;
    const unsigned short* Vs = SMEM + 12288 + cur * 6144;
    unsigned short* Ps = SMEM + 24576 + wave * 2048;

    if (kv0 <= q0 + 31) {  // wave has at least one unmasked element
      f32x4 st[4][2] = {};
      #pragma unroll
      for (int dk = 0; dk < 3; ++dk) {
        bf16x8 af[4];
        #pragma unroll
        for (int kb = 0; kb < 4; ++kb)
          af[kb] = ld_frag(&Ks[dk * 2048 + (kb * 16 + r) * 32 + ((g ^ ((r >> 1) & 3)) * 8)]);
        __builtin_amdgcn_s_setprio(1);
        #pragma unroll
        for (int kb = 0; kb < 4; ++kb)
          #pragma unroll
          for (int qb = 0; qb < 2; ++qb)
            st[kb][qb] = __builtin_amdgcn_mfma_f32_16x16x32_bf16(af[kb], qf[qb][dk], st[kb][qb], 0, 0, 0);
        __builtin_amdgcn_s_setprio(0);
      }
      // scale (exp2 domain) + causal mask (k_abs <= q_abs)
      if (kv0 + 63 > q0) {
        #pragma unroll
        for (int kb = 0; kb < 4; ++kb)
          #pragma unroll
          for (int qb = 0; qb < 2; ++qb)
            #pragma unroll
            for (int rr = 0; rr < 4; ++rr) {
              const int ka = kv0 + kb * 16 + g * 4 + rr;
              const int qa = q0 + qb * 16 + r;
              const float s = st[kb][qb][rr] * kLS;
              st[kb][qb][rr] = (ka <= qa) ? s : -1e30f;
            }
      } else {
        #pragma unroll
        for (int kb = 0; kb < 4; ++kb)
          #pragma unroll
          for (int qb = 0; qb < 2; ++qb)
            #pragma unroll
            for (int rr = 0; rr < 4; ++rr)
              st[kb][qb][rr] *= kLS;
      }
      // online softmax (exp2 domain), per lane = its q column; T13 exact defer
      #pragma unroll
      for (int qb = 0; qb < 2; ++qb) {
        float mx = st[0][qb][0];
        #pragma unroll
        for (int kb = 0; kb < 4; ++kb)
          #pragma unroll
          for (int rr = 0; rr < 4; ++rr) mx = fmaxf(mx, st[kb][qb][rr]);
        mx = fmaxf(mx, __shfl_xor(mx, 16));
        mx = fmaxf(mx, __shfl_xor(mx, 32));
        if (__all(mx <= m_[qb])) {
          float rs = 0.f;
          #pragma unroll
          for (int kb = 0; kb < 4; ++kb)
            #pragma unroll
            for (int rr = 0; rr < 4; ++rr) {
              const float p = __builtin_amdgcn_exp2f(st[kb][qb][rr] - m_[qb]);
              st[kb][qb][rr] = p;
              rs += p;
            }
          rs += __shfl_xor(rs, 16);
          rs += __shfl_xor(rs, 32);
          l_[qb] += rs;
        } else {
          const float mnew = fmaxf(m_[qb], mx);
          const float corr = __builtin_amdgcn_exp2f(m_[qb] - mnew);
          m_[qb] = mnew;
          float rs = 0.f;
          #pragma unroll
          for (int kb = 0; kb < 4; ++kb)
            #pragma unroll
            for (int rr = 0; rr < 4; ++rr) {
              const float p = __builtin_amdgcn_exp2f(st[kb][qb][rr] - mnew);
              st[kb][qb][rr] = p;
              rs += p;
            }
          rs += __shfl_xor(rs, 16);
          rs += __shfl_xor(rs, 32);
          l_[qb] = l_[qb] * corr + rs;
          #pragma unroll
          for (int db = 0; db < 6; ++db) o[db][qb] *= corr;
        }
      }
      // P[q][k] (bf16) to per-wave LDS, swizzled
      #pragma unroll
      for (int kb = 0; kb < 4; ++kb)
        #pragma unroll
        for (int qb = 0; qb < 2; ++qb) {
          u16x4 wv;
          #pragma unroll
          for (int rr = 0; rr < 4; ++rr) wv[rr] = f2bf(st[kb][qb][rr]);
          const int q = qb * 16 + r;
          *(u16x4*)&Ps[q * 64 + (((2 * kb + (g >> 1)) ^ (r & 7)) << 3) + (g & 1) * 4] = wv;
        }
      // O^T += V^T * P^T
      #pragma unroll
      for (int kk = 0; kk < 2; ++kk) {
        bf16x8 pb[2];
        #pragma unroll
        for (int qb = 0; qb < 2; ++qb)
          pb[qb] = ld_frag(&Ps[(qb * 16 + r) * 64 + ((kk * 4 + g) ^ (r & 7)) * 8]);
        __builtin_amdgcn_s_setprio(1);
        #pragma unroll
        for (int db = 0; db < 6; ++db) {
          const bf16x8 va = ld_frag(&Vs[(db * 16 + r) * 64 + ((kk * 4 + g) ^ (r & 7)) * 8]);
          #pragma unroll
          for (int qb = 0; qb < 2; ++qb)
            o[db][qb] = __builtin_amdgcn_mfma_f32_16x16x32_bf16(va, pb[qb], o[db][qb], 0, 0, 0);
        }
        __builtin_amdgcn_s_setprio(0);
      }
    }
    __syncthreads();
  }

  // epilogue: normalize, transpose through LDS (per-wave region), coalesced stores
  const float inv_l[2] = {1.f / l_[0], 1.f / l_[1]};
  unsigned short* obuf = SMEM + wave * 3328;  // 32 x 104 per wave
  #pragma unroll
  for (int db = 0; db < 6; ++db)
    #pragma unroll
    for (int qb = 0; qb < 2; ++qb) {
      u16x4 wv;
      #pragma unroll
      for (int rr = 0; rr < 4; ++rr) wv[rr] = f2bf(o[db][qb][rr] * inv_l[qb]);
      *(u16x4*)&obuf[(qb * 16 + r) * 104 + db * 16 + g * 4] = wv;
    }
  #pragma unroll
  for (int it = 0; it < 6; ++it) {
    const int cc = it * 64 + lane;
    const int qr = cc / 12, d0 = (cc % 12) * 8;
    *(u32x4*)&ctx[(size_t)(b * 2048 + q0 - wave * 32 + wave * 32 + qr) * 3072 + h * 96 + d0] =
        *(const u32x4*)&obuf[qr * 104 + d0];
  }
}

extern "C" void kernel_launch(void* const* d_in, const int* in_sizes, int n_in,
                              void* d_out, int out_size, void* d_ws, size_t ws_size,
                              hipStream_t stream) {
  const float* hs   = (const float*)d_in[0];
  const float* cosp = (const float*)d_in[1];
  const float* sinp = (const float*)d_in[2];
  const float* wqkv = (const float*)d_in[4];
  const float* wo   = (const float*)d_in[5];
  float* out = (float*)d_out;

  // workspace layout (bf16 elems): qkv 18,874,368 | hsb 12,582,912 | wqb 14,155,776
  // after GEMM1: hsb region reused as vt (3,145,728) + wob (9,437,184); wqb as ctx.
  unsigned short* qkv = (unsigned short*)d_ws;
  unsigned short* hsb = qkv + 18874368;
  unsigned short* wqb = hsb + 12582912;
  unsigned short* vt  = hsb;
  unsigned short* wob = hsb + 3145728;
  unsigned short* ctx = wqb;

  cvt_bf16<<<12288, 256, 0, stream>>>(hs,   hsb, 3145728);
  cvt_bf16<<<13824, 256, 0, stream>>>(wqkv, wqb, 3538944);
  gemm8p<1><<<384, 512, 0, stream>>>(hsb, wqb, (void*)qkv, cosp, sinp, 4096, 4608, 3072);
  vtrans<<<dim3(32, 8, 2), 256, 0, stream>>>(qkv, vt);
  cvt_bf16<<<9216, 256, 0, stream>>>(wo, wob, 2359296);
  attn_fwd<<<512, 512, 0, stream>>>(qkv, vt, ctx);
  gemm8p<0><<<256, 512, 0, stream>>>(ctx, wob, (void*)out, cosp, sinp, 4096, 3072, 3072);
}

// Round 15
// 402.584 us; speedup vs baseline: 1.4402x; 1.4402x over previous
//
#include <hip/hip_runtime.h>

typedef __attribute__((ext_vector_type(8))) __bf16 bf16x8;
typedef __attribute__((ext_vector_type(4))) float f32x4;
typedef __attribute__((ext_vector_type(4))) unsigned int u32x4;
typedef __attribute__((ext_vector_type(4))) unsigned short u16x4;
typedef __attribute__((ext_vector_type(8))) unsigned short u16x8;

__device__ __forceinline__ unsigned short f2bf(float x) {
  unsigned u = __builtin_bit_cast(unsigned, x);
  u += 0x7fffu + ((u >> 16) & 1u);
  return (unsigned short)(u >> 16);
}
__device__ __forceinline__ float bf2f(unsigned short h) {
  unsigned u = ((unsigned)h) << 16;
  return __builtin_bit_cast(float, u);
}
__device__ __forceinline__ bf16x8 ld_frag(const unsigned short* p) {
  u32x4 u = *(const u32x4*)p;
  return __builtin_bit_cast(bf16x8, u);
}
__device__ __forceinline__ void gload_lds16(const unsigned short* g, unsigned short* l) {
  __builtin_amdgcn_global_load_lds(
      (const __attribute__((address_space(1))) void*)g,
      (__attribute__((address_space(3))) void*)l, 16, 0, 0);
}

// ---------------- f32 -> bf16 conversion (vectorized) ----------------
__global__ __launch_bounds__(256) void cvt_bf16(const float* __restrict__ in,
                                                unsigned short* __restrict__ out, int n4) {
  int i = blockIdx.x * 256 + threadIdx.x;
  if (i >= n4) return;
  f32x4 v = *((const f32x4*)in + i);
  u16x4 o;
  #pragma unroll
  for (int j = 0; j < 4; ++j) o[j] = f2bf(v[j]);
  *((u16x4*)out + i) = o;
}

// ---- 8-phase GEMM, 4M x 2N wave map (r12 exact; used for gemm2) ----
template <int MODE>
__global__ __launch_bounds__(512, 2) void gemm8p(const unsigned short* __restrict__ A,
                                                 const unsigned short* __restrict__ B,
                                                 void* __restrict__ Cv,
                                                 const float* __restrict__ cs,
                                                 const float* __restrict__ sn,
                                                 int M, int N, int K) {
  __shared__ __align__(16) unsigned short SM[57344];  // 112 KB
  const int nwg = gridDim.x;
  const int swz = (blockIdx.x & 7) * (nwg >> 3) + (blockIdx.x >> 3);
  const int bx = swz & 15, by = swz >> 4;
  const int row0 = bx * 256, col0 = by * 192;
  const int tid = threadIdx.x;
  const int wave = tid >> 6, lane = tid & 63;
  const int g = lane >> 4, r = lane & 15;
  const int wm = (wave >> 1) * 64, wn = (wave & 1) * 96;
  const int NT = K >> 6;

  const unsigned short* Agb = A + (size_t)row0 * K;
  const unsigned short* Bgb = B + (size_t)col0 * K;

  f32x4 acc[4][6] = {};

  auto SU = [&](const unsigned short* src, unsigned short* dst, int u) {
    const int pos = u * 512 + tid;
    const int rw = pos >> 3, cc = pos & 7;
    gload_lds16(src + (size_t)rw * K + ((cc ^ (rw & 7)) * 8), dst + pos * 8);
  };
  auto LDA = [&](const unsigned short* base, int mi, int dk) {
    const int rw = wm + mi * 16 + r;
    return ld_frag(base + rw * 64 + (((dk * 4 + g) ^ (r & 7)) * 8));
  };
  auto LDB = [&](const unsigned short* base, int ni, int dk) {
    const int rw = wn + ni * 16 + r;
    return ld_frag(base + rw * 64 + (((dk * 4 + g) ^ (r & 7)) * 8));
  };

  SU(Agb, SM, 0); SU(Agb, SM, 1); SU(Agb, SM, 2); SU(Agb, SM, 3);
  SU(Bgb, SM + 16384, 0); SU(Bgb, SM + 16384, 1); SU(Bgb, SM + 16384, 2);
  __syncthreads();

  for (int t = 0; t < NT; ++t) {
    const int d = t & 1;
    const unsigned short* Ab = SM + d * 28672;
    const unsigned short* Bb = Ab + 16384;
    unsigned short* An = SM + (d ^ 1) * 28672;
    unsigned short* Bn = An + 16384;
    const unsigned short* Asrc = Agb + (t + 1) * 64;
    const unsigned short* Bsrc = Bgb + (t + 1) * 64;
    const bool pf = (t + 1 < NT);

    bf16x8 a0, a1, b[6];

    b[0] = LDB(Bb, 0, 0); b[1] = LDB(Bb, 1, 0); b[2] = LDB(Bb, 2, 0);
    b[3] = LDB(Bb, 3, 0); b[4] = LDB(Bb, 4, 0); b[5] = LDB(Bb, 5, 0);
    a0 = LDA(Ab, 0, 0); a1 = LDA(Ab, 1, 0);
    if (pf) { SU(Asrc, An, 0); SU(Asrc, An, 1); SU(Asrc, An, 2); }
    __builtin_amdgcn_s_barrier();
    asm volatile("s_waitcnt lgkmcnt(0)" ::: "memory");
    __builtin_amdgcn_sched_barrier(0);
    __builtin_amdgcn_s_setprio(1);
    #pragma unroll
    for (int n = 0; n < 6; ++n) {
      acc[0][n] = __builtin_amdgcn_mfma_f32_16x16x32_bf16(a0, b[n], acc[0][n], 0, 0, 0);
      acc[1][n] = __builtin_amdgcn_mfma_f32_16x16x32_bf16(a1, b[n], acc[1][n], 0, 0, 0);
    }
    __builtin_amdgcn_s_setprio(0);
    __builtin_amdgcn_s_barrier();

    a0 = LDA(Ab, 2, 0); a1 = LDA(Ab, 3, 0);
    if (pf) { SU(Asrc, An, 3); SU(Bsrc, Bn, 0); }
    __builtin_amdgcn_s_barrier();
    asm volatile("s_waitcnt lgkmcnt(0)" ::: "memory");
    __builtin_amdgcn_sched_barrier(0);
    __builtin_amdgcn_s_setprio(1);
    #pragma unroll
    for (int n = 0; n < 6; ++n) {
      acc[2][n] = __builtin_amdgcn_mfma_f32_16x16x32_bf16(a0, b[n], acc[2][n], 0, 0, 0);
      acc[3][n] = __builtin_amdgcn_mfma_f32_16x16x32_bf16(a1, b[n], acc[3][n], 0, 0, 0);
    }
    __builtin_amdgcn_s_setprio(0);
    __builtin_amdgcn_s_barrier();

    b[0] = LDB(Bb, 0, 1); b[1] = LDB(Bb, 1, 1); b[2] = LDB(Bb, 2, 1);
    b[3] = LDB(Bb, 3, 1); b[4] = LDB(Bb, 4, 1); b[5] = LDB(Bb, 5, 1);
    a0 = LDA(Ab, 0, 1); a1 = LDA(Ab, 1, 1);
    if (pf) { SU(Bsrc, Bn, 1); SU(Bsrc, Bn, 2); }
    __builtin_amdgcn_s_barrier();
    asm volatile("s_waitcnt lgkmcnt(0)" ::: "memory");
    __builtin_amdgcn_sched_barrier(0);
    __builtin_amdgcn_s_setprio(1);
    #pragma unroll
    for (int n = 0; n < 6; ++n) {
      acc[0][n] = __builtin_amdgcn_mfma_f32_16x16x32_bf16(a0, b[n], acc[0][n], 0, 0, 0);
      acc[1][n] = __builtin_amdgcn_mfma_f32_16x16x32_bf16(a1, b[n], acc[1][n], 0, 0, 0);
    }
    __builtin_amdgcn_s_setprio(0);
    __builtin_amdgcn_s_barrier();

    a0 = LDA(Ab, 2, 1); a1 = LDA(Ab, 3, 1);
    __builtin_amdgcn_s_barrier();
    asm volatile("s_waitcnt lgkmcnt(0)" ::: "memory");
    __builtin_amdgcn_sched_barrier(0);
    __builtin_amdgcn_s_setprio(1);
    #pragma unroll
    for (int n = 0; n < 6; ++n) {
      acc[2][n] = __builtin_amdgcn_mfma_f32_16x16x32_bf16(a0, b[n], acc[2][n], 0, 0, 0);
      acc[3][n] = __builtin_amdgcn_mfma_f32_16x16x32_bf16(a1, b[n], acc[3][n], 0, 0, 0);
    }
    __builtin_amdgcn_s_setprio(0);
    asm volatile("s_waitcnt vmcnt(0)" ::: "memory");
    __builtin_amdgcn_s_barrier();
  }

  if (MODE == 0) {
    float* outp = (float*)Cv;
    #pragma unroll
    for (int mi = 0; mi < 4; ++mi)
      #pragma unroll
      for (int n = 0; n < 6; ++n)
        #pragma unroll
        for (int rr = 0; rr < 4; ++rr) {
          const size_t idx = (size_t)(row0 + wm + mi * 16 + g * 4 + rr) * (size_t)N
                           + (col0 + wn + n * 16 + r);
          outp[idx] = acc[mi][n][rr];
        }
  } else {
    unsigned short* outp = (unsigned short*)Cv;
    const int hc0 = col0 + wn;
    if (hc0 < 3840) {
      #pragma unroll
      for (int mi = 0; mi < 4; ++mi)
        #pragma unroll
        for (int rr = 0; rr < 4; ++rr) {
          const int row = row0 + wm + mi * 16 + g * 4 + rr;
          const int cb = row * 96;
          const size_t rb = (size_t)row * N + hc0;
          #pragma unroll
          for (int n = 0; n < 3; ++n) {
            const int d = n * 16 + r;
            const float x1 = acc[mi][n][rr], x2 = acc[mi][n + 3][rr];
            const float c1 = cs[cb + d], s1 = sn[cb + d];
            const float c2 = cs[cb + d + 48], s2 = sn[cb + d + 48];
            outp[rb + d]      = f2bf(x1 * c1 - x2 * s1);
            outp[rb + d + 48] = f2bf(x2 * c2 + x1 * s2);
          }
        }
    } else {
      #pragma unroll
      for (int mi = 0; mi < 4; ++mi)
        #pragma unroll
        for (int n = 0; n < 6; ++n)
          #pragma unroll
          for (int rr = 0; rr < 4; ++rr) {
            const size_t idx = (size_t)(row0 + wm + mi * 16 + g * 4 + rr) * (size_t)N
                             + (col0 + wn + n * 16 + r);
            outp[idx] = f2bf(acc[mi][n][rr]);
          }
    }
  }
}

// ---- gemm4w: 256-thr, 4 waves (2M x 2N), BM=128 x BN=192, 2 blocks/CU ----
// Same per-wave tile (64x96, acc[4][6]), same swizzles/phase schedule as
// gemm8p; LDS 80KB (2 bufs x (A 16KB + B 24KB)) -> 2 co-resident blocks.
// Grid 32x24 = 768 (%8==0). Used for gemm1 (finer tail granularity).
template <int MODE>
__global__ __launch_bounds__(256) void gemm4w(const unsigned short* __restrict__ A,
                                              const unsigned short* __restrict__ B,
                                              void* __restrict__ Cv,
                                              const float* __restrict__ cs,
                                              const float* __restrict__ sn,
                                              int M, int N, int K) {
  __shared__ __align__(16) unsigned short SM[40960];  // 80 KB
  const int nwg = gridDim.x;
  const int swz = (blockIdx.x & 7) * (nwg >> 3) + (blockIdx.x >> 3);
  const int bx = swz & 31, by = swz >> 5;      // M/128 == 32
  const int row0 = bx * 128, col0 = by * 192;
  const int tid = threadIdx.x;
  const int wave = tid >> 6, lane = tid & 63;
  const int g = lane >> 4, r = lane & 15;
  const int wm = (wave >> 1) * 64, wn = (wave & 1) * 96;
  const int NT = K >> 6;

  const unsigned short* Agb = A + (size_t)row0 * K;
  const unsigned short* Bgb = B + (size_t)col0 * K;

  f32x4 acc[4][6] = {};

  auto SU = [&](const unsigned short* src, unsigned short* dst, int u) {
    const int pos = u * 256 + tid;
    const int rw = pos >> 3, cc = pos & 7;
    gload_lds16(src + (size_t)rw * K + ((cc ^ (rw & 7)) * 8), dst + pos * 8);
  };
  auto LDA = [&](const unsigned short* base, int mi, int dk) {
    const int rw = wm + mi * 16 + r;
    return ld_frag(base + rw * 64 + (((dk * 4 + g) ^ (r & 7)) * 8));
  };
  auto LDB = [&](const unsigned short* base, int ni, int dk) {
    const int rw = wn + ni * 16 + r;
    return ld_frag(base + rw * 64 + (((dk * 4 + g) ^ (r & 7)) * 8));
  };

  // prologue: A 4 units + B 6 units into buf 0
  SU(Agb, SM, 0); SU(Agb, SM, 1); SU(Agb, SM, 2); SU(Agb, SM, 3);
  SU(Bgb, SM + 8192, 0); SU(Bgb, SM + 8192, 1); SU(Bgb, SM + 8192, 2);
  SU(Bgb, SM + 8192, 3); SU(Bgb, SM + 8192, 4); SU(Bgb, SM + 8192, 5);
  __syncthreads();

  for (int t = 0; t < NT; ++t) {
    const int d = t & 1;
    const unsigned short* Ab = SM + d * 20480;
    const unsigned short* Bb = Ab + 8192;
    unsigned short* An = SM + (d ^ 1) * 20480;
    unsigned short* Bn = An + 8192;
    const unsigned short* Asrc = Agb + (t + 1) * 64;
    const unsigned short* Bsrc = Bgb + (t + 1) * 64;
    const bool pf = (t + 1 < NT);

    bf16x8 a0, a1, b[6];

    b[0] = LDB(Bb, 0, 0); b[1] = LDB(Bb, 1, 0); b[2] = LDB(Bb, 2, 0);
    b[3] = LDB(Bb, 3, 0); b[4] = LDB(Bb, 4, 0); b[5] = LDB(Bb, 5, 0);
    a0 = LDA(Ab, 0, 0); a1 = LDA(Ab, 1, 0);
    if (pf) { SU(Asrc, An, 0); SU(Asrc, An, 1); SU(Asrc, An, 2); SU(Asrc, An, 3); }
    __builtin_amdgcn_s_barrier();
    asm volatile("s_waitcnt lgkmcnt(0)" ::: "memory");
    __builtin_amdgcn_sched_barrier(0);
    __builtin_amdgcn_s_setprio(1);
    #pragma unroll
    for (int n = 0; n < 6; ++n) {
      acc[0][n] = __builtin_amdgcn_mfma_f32_16x16x32_bf16(a0, b[n], acc[0][n], 0, 0, 0);
      acc[1][n] = __builtin_amdgcn_mfma_f32_16x16x32_bf16(a1, b[n], acc[1][n], 0, 0, 0);
    }
    __builtin_amdgcn_s_setprio(0);
    __builtin_amdgcn_s_barrier();

    a0 = LDA(Ab, 2, 0); a1 = LDA(Ab, 3, 0);
    if (pf) { SU(Bsrc, Bn, 0); SU(Bsrc, Bn, 1); SU(Bsrc, Bn, 2); }
    __builtin_amdgcn_s_barrier();
    asm volatile("s_waitcnt lgkmcnt(0)" ::: "memory");
    __builtin_amdgcn_sched_barrier(0);
    __builtin_amdgcn_s_setprio(1);
    #pragma unroll
    for (int n = 0; n < 6; ++n) {
      acc[2][n] = __builtin_amdgcn_mfma_f32_16x16x32_bf16(a0, b[n], acc[2][n], 0, 0, 0);
      acc[3][n] = __builtin_amdgcn_mfma_f32_16x16x32_bf16(a1, b[n], acc[3][n], 0, 0, 0);
    }
    __builtin_amdgcn_s_setprio(0);
    __builtin_amdgcn_s_barrier();

    b[0] = LDB(Bb, 0, 1); b[1] = LDB(Bb, 1, 1); b[2] = LDB(Bb, 2, 1);
    b[3] = LDB(Bb, 3, 1); b[4] = LDB(Bb, 4, 1); b[5] = LDB(Bb, 5, 1);
    a0 = LDA(Ab, 0, 1); a1 = LDA(Ab, 1, 1);
    if (pf) { SU(Bsrc, Bn, 3); SU(Bsrc, Bn, 4); SU(Bsrc, Bn, 5); }
    __builtin_amdgcn_s_barrier();
    asm volatile("s_waitcnt lgkmcnt(0)" ::: "memory");
    __builtin_amdgcn_sched_barrier(0);
    __builtin_amdgcn_s_setprio(1);
    #pragma unroll
    for (int n = 0; n < 6; ++n) {
      acc[0][n] = __builtin_amdgcn_mfma_f32_16x16x32_bf16(a0, b[n], acc[0][n], 0, 0, 0);
      acc[1][n] = __builtin_amdgcn_mfma_f32_16x16x32_bf16(a1, b[n], acc[1][n], 0, 0, 0);
    }
    __builtin_amdgcn_s_setprio(0);
    __builtin_amdgcn_s_barrier();

    a0 = LDA(Ab, 2, 1); a1 = LDA(Ab, 3, 1);
    __builtin_amdgcn_s_barrier();
    asm volatile("s_waitcnt lgkmcnt(0)" ::: "memory");
    __builtin_amdgcn_sched_barrier(0);
    __builtin_amdgcn_s_setprio(1);
    #pragma unroll
    for (int n = 0; n < 6; ++n) {
      acc[2][n] = __builtin_amdgcn_mfma_f32_16x16x32_bf16(a0, b[n], acc[2][n], 0, 0, 0);
      acc[3][n] = __builtin_amdgcn_mfma_f32_16x16x32_bf16(a1, b[n], acc[3][n], 0, 0, 0);
    }
    __builtin_amdgcn_s_setprio(0);
    asm volatile("s_waitcnt vmcnt(0)" ::: "memory");
    __builtin_amdgcn_s_barrier();
  }

  if (MODE == 0) {
    float* outp = (float*)Cv;
    #pragma unroll
    for (int mi = 0; mi < 4; ++mi)
      #pragma unroll
      for (int n = 0; n < 6; ++n)
        #pragma unroll
        for (int rr = 0; rr < 4; ++rr) {
          const size_t idx = (size_t)(row0 + wm + mi * 16 + g * 4 + rr) * (size_t)N
                           + (col0 + wn + n * 16 + r);
          outp[idx] = acc[mi][n][rr];
        }
  } else {
    unsigned short* outp = (unsigned short*)Cv;
    const int hc0 = col0 + wn;               // head-aligned (multiple of 96)
    if (hc0 < 3840) {                        // Q or K head: fused RoPE
      #pragma unroll
      for (int mi = 0; mi < 4; ++mi)
        #pragma unroll
        for (int rr = 0; rr < 4; ++rr) {
          const int row = row0 + wm + mi * 16 + g * 4 + rr;
          const int cb = row * 96;
          const size_t rb = (size_t)row * N + hc0;
          #pragma unroll
          for (int n = 0; n < 3; ++n) {
            const int d = n * 16 + r;
            const float x1 = acc[mi][n][rr], x2 = acc[mi][n + 3][rr];
            const float c1 = cs[cb + d], s1 = sn[cb + d];
            const float c2 = cs[cb + d + 48], s2 = sn[cb + d + 48];
            outp[rb + d]      = f2bf(x1 * c1 - x2 * s1);
            outp[rb + d + 48] = f2bf(x2 * c2 + x1 * s2);
          }
        }
    } else {                                 // V head: plain bf16
      #pragma unroll
      for (int mi = 0; mi < 4; ++mi)
        #pragma unroll
        for (int n = 0; n < 6; ++n)
          #pragma unroll
          for (int rr = 0; rr < 4; ++rr) {
            const size_t idx = (size_t)(row0 + wm + mi * 16 + g * 4 + rr) * (size_t)N
                             + (col0 + wn + n * 16 + r);
            outp[idx] = f2bf(acc[mi][n][rr]);
          }
    }
  }
}

// ---------------- V transpose: qkv[b,s,3840+kvh*96+d] -> vt[b,kvh,d,s] ----------------
__global__ __launch_bounds__(256) void vtrans(const unsigned short* __restrict__ qkv,
                                              unsigned short* __restrict__ vt) {
  __shared__ __align__(16) unsigned short T[64 * 104];
  const int s0 = blockIdx.x * 64;
  const int kvh = blockIdx.y, b = blockIdx.z;
  const int tid = threadIdx.x;
  #pragma unroll
  for (int it = 0; it < 3; ++it) {
    const int c = it * 256 + tid;
    const int sr = c / 12, d0 = (c % 12) * 8;
    *(u32x4*)&T[sr * 104 + d0] =
        *(const u32x4*)&qkv[(size_t)(b * 2048 + s0 + sr) * 4608 + 3840 + kvh * 96 + d0];
  }
  __syncthreads();
  #pragma unroll
  for (int it = 0; it < 3; ++it) {
    const int c = it * 256 + tid;
    const int dr = c >> 3, k0 = (c & 7) * 8;
    u16x8 o;
    #pragma unroll
    for (int j = 0; j < 8; ++j) o[j] = T[(k0 + j) * 104 + dr];
    *(u16x8*)&vt[((size_t)(b * 8 + kvh) * 96 + dr) * 2048 + s0 + k0] = o;
  }
}

// ---------------- Flash attention, causal GQA, swapped QK^T (r12 exact) ----------------
__global__ __launch_bounds__(512) void attn_fwd(const unsigned short* __restrict__ qkv,
                                                const unsigned short* __restrict__ vt,
                                                unsigned short* __restrict__ ctx) {
  __shared__ __align__(16) unsigned short SMEM[40960];  // 80 KB
  const int wg = blockIdx.x;             // 0..255
  const int xcd = wg & 7, j = wg >> 3;   // j 0..31
  const int c = xcd + ((j >> 4) << 3);   // (b,kvh) id, 0..15
  const int b = c >> 3, kvh = c & 7;
  const int rj = j & 15;
  const int h = kvh * 4 + (rj >> 2);
  const int pr = rj & 3;                 // fold pair: qt in {7-pr, pr}
  const int tid = threadIdx.x;
  const int wave = tid >> 6, lane = tid & 63;
  const int g = lane >> 4, r = lane & 15;
  const float kLS = 0.14724445f;         // (1/sqrt(96)) * log2(e)

  const unsigned short* kgbase = qkv + (size_t)(b * 2048) * 4608 + 3072 + kvh * 96;
  const unsigned short* vgbase = vt + (size_t)(b * 8 + kvh) * 96 * 2048;

  auto STAGE = [&](int t, int bi) {
    const int kv0 = t * 64;
    unsigned short* kd = SMEM + bi * 6144;
    unsigned short* vd = SMEM + 12288 + bi * 6144;
    #pragma unroll
    for (int i = 0; i < 3; ++i) {
      const int l = i * 512 + tid;
      if (l < 768) {  // K: [dk][row][c], src chunk c^((row>>1)&3)
        const int dk = l >> 8, rem = l & 255;
        const int row = rem >> 2, cc = rem & 3;
        const int csrc = cc ^ ((row >> 1) & 3);
        gload_lds16(kgbase + (size_t)(kv0 + row) * 4608 + dk * 32 + csrc * 8, kd + l * 8);
      } else {        // V: [row][c], src chunk c^(row&7)
        const int lv = l - 768;
        const int row = lv >> 3, cc = lv & 7;
        const int csrc = cc ^ (row & 7);
        gload_lds16(vgbase + (size_t)row * 2048 + kv0 + csrc * 8, vd + lv * 8);
      }
    }
  };

  #pragma unroll 1
  for (int sel = 0; sel < 2; ++sel) {
    const int qt = sel ? pr : 7 - pr;
    const int nt = qt * 4 + 4;
    const int q0 = qt * 256 + wave * 32;

    __syncthreads();   // protect LDS (prev epilogue reads) before re-staging

    bf16x8 qf[2][3];
    #pragma unroll
    for (int qb = 0; qb < 2; ++qb)
      #pragma unroll
      for (int dk = 0; dk < 3; ++dk)
        qf[qb][dk] = ld_frag(&qkv[(size_t)(b * 2048 + q0 + qb * 16 + r) * 4608 + h * 96 + dk * 32 + g * 8]);

    f32x4 o[6][2] = {};
    float m_[2] = {-1e30f, -1e30f};
    float l_[2] = {0.f, 0.f};

    STAGE(0, 0);
    __syncthreads();

    for (int t = 0; t < nt; ++t) {
      const int cur = t & 1;
      if (t + 1 < nt) STAGE(t + 1, cur ^ 1);
      const int kv0 = t * 64;
      const unsigned short* Ks = SMEM + cur * 6144;
      const unsigned short* Vs = SMEM + 12288 + cur * 6144;
      unsigned short* Ps = SMEM + 24576 + wave * 2048;

      if (kv0 <= q0 + 31) {  // wave has at least one unmasked element
        f32x4 st[4][2] = {};
        #pragma unroll
        for (int dk = 0; dk < 3; ++dk) {
          bf16x8 af[4];
          #pragma unroll
          for (int kb = 0; kb < 4; ++kb)
            af[kb] = ld_frag(&Ks[dk * 2048 + (kb * 16 + r) * 32 + ((g ^ ((r >> 1) & 3)) * 8)]);
          __builtin_amdgcn_s_setprio(1);
          #pragma unroll
          for (int kb = 0; kb < 4; ++kb)
            #pragma unroll
            for (int qb = 0; qb < 2; ++qb)
              st[kb][qb] = __builtin_amdgcn_mfma_f32_16x16x32_bf16(af[kb], qf[qb][dk], st[kb][qb], 0, 0, 0);
          __builtin_amdgcn_s_setprio(0);
        }
        // scale (exp2 domain) + causal mask (k_abs <= q_abs)
        if (kv0 + 63 > q0) {
          #pragma unroll
          for (int kb = 0; kb < 4; ++kb)
            #pragma unroll
            for (int qb = 0; qb < 2; ++qb)
              #pragma unroll
              for (int rr = 0; rr < 4; ++rr) {
                const int ka = kv0 + kb * 16 + g * 4 + rr;
                const int qa = q0 + qb * 16 + r;
                const float s = st[kb][qb][rr] * kLS;
                st[kb][qb][rr] = (ka <= qa) ? s : -1e30f;
              }
        } else {
          #pragma unroll
          for (int kb = 0; kb < 4; ++kb)
            #pragma unroll
            for (int qb = 0; qb < 2; ++qb)
              #pragma unroll
              for (int rr = 0; rr < 4; ++rr)
                st[kb][qb][rr] *= kLS;
        }
        // online softmax (exp2 domain), per lane = its q column; T13 exact defer
        #pragma unroll
        for (int qb = 0; qb < 2; ++qb) {
          float mx = st[0][qb][0];
          #pragma unroll
          for (int kb = 0; kb < 4; ++kb)
            #pragma unroll
            for (int rr = 0; rr < 4; ++rr) mx = fmaxf(mx, st[kb][qb][rr]);
          mx = fmaxf(mx, __shfl_xor(mx, 16));
          mx = fmaxf(mx, __shfl_xor(mx, 32));
          if (__all(mx <= m_[qb])) {
            float rs = 0.f;
            #pragma unroll
            for (int kb = 0; kb < 4; ++kb)
              #pragma unroll
              for (int rr = 0; rr < 4; ++rr) {
                const float p = __builtin_amdgcn_exp2f(st[kb][qb][rr] - m_[qb]);
                st[kb][qb][rr] = p;
                rs += p;
              }
            rs += __shfl_xor(rs, 16);
            rs += __shfl_xor(rs, 32);
            l_[qb] += rs;
          } else {
            const float mnew = fmaxf(m_[qb], mx);
            const float corr = __builtin_amdgcn_exp2f(m_[qb] - mnew);
            m_[qb] = mnew;
            float rs = 0.f;
            #pragma unroll
            for (int kb = 0; kb < 4; ++kb)
              #pragma unroll
              for (int rr = 0; rr < 4; ++rr) {
                const float p = __builtin_amdgcn_exp2f(st[kb][qb][rr] - mnew);
                st[kb][qb][rr] = p;
                rs += p;
              }
            rs += __shfl_xor(rs, 16);
            rs += __shfl_xor(rs, 32);
            l_[qb] = l_[qb] * corr + rs;
            #pragma unroll
            for (int db = 0; db < 6; ++db) o[db][qb] *= corr;
          }
        }
        // P[q][k] (bf16) to per-wave LDS, swizzled
        #pragma unroll
        for (int kb = 0; kb < 4; ++kb)
          #pragma unroll
          for (int qb = 0; qb < 2; ++qb) {
            u16x4 w;
            #pragma unroll
            for (int rr = 0; rr < 4; ++rr) w[rr] = f2bf(st[kb][qb][rr]);
            const int q = qb * 16 + r;
            *(u16x4*)&Ps[q * 64 + (((2 * kb + (g >> 1)) ^ (r & 7)) << 3) + (g & 1) * 4] = w;
          }
        // O^T += V^T * P^T
        #pragma unroll
        for (int kk = 0; kk < 2; ++kk) {
          bf16x8 pb[2];
          #pragma unroll
          for (int qb = 0; qb < 2; ++qb)
            pb[qb] = ld_frag(&Ps[(qb * 16 + r) * 64 + ((kk * 4 + g) ^ (r & 7)) * 8]);
          __builtin_amdgcn_s_setprio(1);
          #pragma unroll
          for (int db = 0; db < 6; ++db) {
            const bf16x8 va = ld_frag(&Vs[(db * 16 + r) * 64 + ((kk * 4 + g) ^ (r & 7)) * 8]);
            #pragma unroll
            for (int qb = 0; qb < 2; ++qb)
              o[db][qb] = __builtin_amdgcn_mfma_f32_16x16x32_bf16(va, pb[qb], o[db][qb], 0, 0, 0);
          }
          __builtin_amdgcn_s_setprio(0);
        }
      }
      __syncthreads();
    }

    // epilogue: normalize, transpose through LDS (per-wave region), coalesced stores
    const float inv_l[2] = {1.f / l_[0], 1.f / l_[1]};
    unsigned short* obuf = SMEM + wave * 3328;  // 32 x 104 per wave
    #pragma unroll
    for (int db = 0; db < 6; ++db)
      #pragma unroll
      for (int qb = 0; qb < 2; ++qb) {
        u16x4 w;
        #pragma unroll
        for (int rr = 0; rr < 4; ++rr) w[rr] = f2bf(o[db][qb][rr] * inv_l[qb]);
        *(u16x4*)&obuf[(qb * 16 + r) * 104 + db * 16 + g * 4] = w;
      }
    #pragma unroll
    for (int it = 0; it < 6; ++it) {
      const int cc = it * 64 + lane;
      const int qr = cc / 12, d0 = (cc % 12) * 8;
      *(u32x4*)&ctx[(size_t)(b * 2048 + q0 + qr) * 3072 + h * 96 + d0] =
          *(const u32x4*)&obuf[qr * 104 + d0];
    }
  }
}

extern "C" void kernel_launch(void* const* d_in, const int* in_sizes, int n_in,
                              void* d_out, int out_size, void* d_ws, size_t ws_size,
                              hipStream_t stream) {
  const float* hs   = (const float*)d_in[0];
  const float* cosp = (const float*)d_in[1];
  const float* sinp = (const float*)d_in[2];
  const float* wqkv = (const float*)d_in[4];
  const float* wo   = (const float*)d_in[5];
  float* out = (float*)d_out;

  // workspace layout (bf16 elems): qkv 18,874,368 | hsb 12,582,912 | wqb 14,155,776
  // after GEMM1: hsb region reused as vt (3,145,728) + wob (9,437,184); wqb as ctx.
  unsigned short* qkv = (unsigned short*)d_ws;
  unsigned short* hsb = qkv + 18874368;
  unsigned short* wqb = hsb + 12582912;
  unsigned short* vt  = hsb;
  unsigned short* wob = hsb + 3145728;
  unsigned short* ctx = wqb;

  cvt_bf16<<<12288, 256, 0, stream>>>(hs,   hsb, 3145728);
  cvt_bf16<<<13824, 256, 0, stream>>>(wqkv, wqb, 3538944);
  gemm4w<1><<<768, 256, 0, stream>>>(hsb, wqb, (void*)qkv, cosp, sinp, 4096, 4608, 3072);
  vtrans<<<dim3(32, 8, 2), 256, 0, stream>>>(qkv, vt);
  cvt_bf16<<<9216, 256, 0, stream>>>(wo, wob, 2359296);
  attn_fwd<<<256, 512, 0, stream>>>(qkv, vt, ctx);
  gemm8p<0><<<256, 512, 0, stream>>>(ctx, wob, (void*)out, cosp, sinp, 4096, 3072, 3072);
}

// Round 17
// 345.986 us; speedup vs baseline: 1.6758x; 1.1636x over previous
//
#include <hip/hip_runtime.h>

typedef __attribute__((ext_vector_type(8))) __bf16 bf16x8;
typedef __attribute__((ext_vector_type(4))) float f32x4;
typedef __attribute__((ext_vector_type(4))) unsigned int u32x4;
typedef __attribute__((ext_vector_type(4))) unsigned short u16x4;
typedef __attribute__((ext_vector_type(8))) unsigned short u16x8;

__device__ __forceinline__ unsigned short f2bf(float x) {
  unsigned u = __builtin_bit_cast(unsigned, x);
  u += 0x7fffu + ((u >> 16) & 1u);
  return (unsigned short)(u >> 16);
}
__device__ __forceinline__ float bf2f(unsigned short h) {
  unsigned u = ((unsigned)h) << 16;
  return __builtin_bit_cast(float, u);
}
__device__ __forceinline__ bf16x8 ld_frag(const unsigned short* p) {
  u32x4 u = *(const u32x4*)p;
  return __builtin_bit_cast(bf16x8, u);
}
__device__ __forceinline__ void gload_lds16(const unsigned short* g, unsigned short* l) {
  __builtin_amdgcn_global_load_lds(
      (const __attribute__((address_space(1))) void*)g,
      (__attribute__((address_space(3))) void*)l, 16, 0, 0);
}

// ---------------- f32 -> bf16 conversion (vectorized) ----------------
__global__ __launch_bounds__(256) void cvt_bf16(const float* __restrict__ in,
                                                unsigned short* __restrict__ out, int n4) {
  int i = blockIdx.x * 256 + threadIdx.x;
  if (i >= n4) return;
  f32x4 v = *((const f32x4*)in + i);
  u16x4 o;
  #pragma unroll
  for (int j = 0; j < 4; ++j) o[j] = f2bf(v[j]);
  *((u16x4*)out + i) = o;
}

// ------- merged f32 -> bf16 conversion for two buffers (one launch) -------
__global__ __launch_bounds__(256) void cvt2_bf16(const float* __restrict__ a,
                                                 unsigned short* __restrict__ oa, int na4,
                                                 const float* __restrict__ b,
                                                 unsigned short* __restrict__ ob, int nb4) {
  const int i = blockIdx.x * 256 + threadIdx.x;
  if (i < na4) {
    f32x4 v = *((const f32x4*)a + i);
    u16x4 o;
    #pragma unroll
    for (int j = 0; j < 4; ++j) o[j] = f2bf(v[j]);
    *((u16x4*)oa + i) = o;
  } else {
    const int k = i - na4;
    if (k < nb4) {
      f32x4 v = *((const f32x4*)b + k);
      u16x4 o;
      #pragma unroll
      for (int j = 0; j < 4; ++j) o[j] = f2bf(v[j]);
      *((u16x4*)ob + k) = o;
    }
  }
}

// ---- 8-phase GEMM, 4M x 2N wave map (r12 structure + early staging issue) ----
// Blocks >= gemm_blocks run a grid-stride f32->bf16 conversion instead (fills
// the dispatch-tail idle CUs of round 2). cvt_dst MUST NOT alias A/B/C.
// MODE 0: f32 C (gemm2). MODE 1: bf16 C + fused RoPE on heads < 3840 (gemm1).
template <int MODE>
__global__ __launch_bounds__(512, 2) void gemm8p(const unsigned short* __restrict__ A,
                                                 const unsigned short* __restrict__ B,
                                                 void* __restrict__ Cv,
                                                 const float* __restrict__ cs,
                                                 const float* __restrict__ sn,
                                                 int M, int N, int K,
                                                 const float* __restrict__ cvt_src,
                                                 unsigned short* __restrict__ cvt_dst,
                                                 int cvt_n4, int gemm_blocks) {
  __shared__ __align__(16) unsigned short SM[57344];  // 112 KB
  if ((int)blockIdx.x >= gemm_blocks) {
    // tail-filler: vectorized f32 -> bf16 conversion (independent work)
    const int nthr = ((int)gridDim.x - gemm_blocks) * 512;
    for (int i = ((int)blockIdx.x - gemm_blocks) * 512 + (int)threadIdx.x;
         i < cvt_n4; i += nthr) {
      f32x4 v = *((const f32x4*)cvt_src + i);
      u16x4 o;
      #pragma unroll
      for (int j = 0; j < 4; ++j) o[j] = f2bf(v[j]);
      *((u16x4*)cvt_dst + i) = o;
    }
    return;
  }
  const int nwg = gemm_blocks;
  const int swz = (blockIdx.x & 7) * (nwg >> 3) + (blockIdx.x >> 3);
  const int bx = swz & 15, by = swz >> 4;      // M/256 == 16 for both GEMMs
  const int row0 = bx * 256, col0 = by * 192;
  const int tid = threadIdx.x;
  const int wave = tid >> 6, lane = tid & 63;
  const int g = lane >> 4, r = lane & 15;
  const int wm = (wave >> 1) * 64, wn = (wave & 1) * 96;
  const int NT = K >> 6;

  const unsigned short* Agb = A + (size_t)row0 * K;
  const unsigned short* Bgb = B + (size_t)col0 * K;

  f32x4 acc[4][6] = {};

  auto SU = [&](const unsigned short* src, unsigned short* dst, int u) {
    const int pos = u * 512 + tid;
    const int rw = pos >> 3, cc = pos & 7;
    gload_lds16(src + (size_t)rw * K + ((cc ^ (rw & 7)) * 8), dst + pos * 8);
  };
  auto LDA = [&](const unsigned short* base, int mi, int dk) {
    const int rw = wm + mi * 16 + r;
    return ld_frag(base + rw * 64 + (((dk * 4 + g) ^ (r & 7)) * 8));
  };
  auto LDB = [&](const unsigned short* base, int ni, int dk) {
    const int rw = wn + ni * 16 + r;
    return ld_frag(base + rw * 64 + (((dk * 4 + g) ^ (r & 7)) * 8));
  };

  SU(Agb, SM, 0); SU(Agb, SM, 1); SU(Agb, SM, 2); SU(Agb, SM, 3);
  SU(Bgb, SM + 16384, 0); SU(Bgb, SM + 16384, 1); SU(Bgb, SM + 16384, 2);
  __syncthreads();

  for (int t = 0; t < NT; ++t) {
    const int d = t & 1;
    const unsigned short* Ab = SM + d * 28672;
    const unsigned short* Bb = Ab + 16384;
    unsigned short* An = SM + (d ^ 1) * 28672;
    unsigned short* Bn = An + 16384;
    const unsigned short* Asrc = Agb + (t + 1) * 64;
    const unsigned short* Bsrc = Bgb + (t + 1) * 64;
    const bool pf = (t + 1 < NT);

    bf16x8 a0, a1, b[6];

    // ---- ph0: dk=0, mi 0-1; issue ALL A staging for t+1 ----
    b[0] = LDB(Bb, 0, 0); b[1] = LDB(Bb, 1, 0); b[2] = LDB(Bb, 2, 0);
    b[3] = LDB(Bb, 3, 0); b[4] = LDB(Bb, 4, 0); b[5] = LDB(Bb, 5, 0);
    a0 = LDA(Ab, 0, 0); a1 = LDA(Ab, 1, 0);
    if (pf) { SU(Asrc, An, 0); SU(Asrc, An, 1); SU(Asrc, An, 2); SU(Asrc, An, 3); }
    __builtin_amdgcn_s_barrier();
    asm volatile("s_waitcnt lgkmcnt(0)" ::: "memory");
    __builtin_amdgcn_sched_barrier(0);
    __builtin_amdgcn_s_setprio(1);
    #pragma unroll
    for (int n = 0; n < 6; ++n) {
      acc[0][n] = __builtin_amdgcn_mfma_f32_16x16x32_bf16(a0, b[n], acc[0][n], 0, 0, 0);
      acc[1][n] = __builtin_amdgcn_mfma_f32_16x16x32_bf16(a1, b[n], acc[1][n], 0, 0, 0);
    }
    __builtin_amdgcn_s_setprio(0);
    __builtin_amdgcn_s_barrier();

    // ---- ph1: dk=0, mi 2-3; issue ALL B staging for t+1 ----
    a0 = LDA(Ab, 2, 0); a1 = LDA(Ab, 3, 0);
    if (pf) { SU(Bsrc, Bn, 0); SU(Bsrc, Bn, 1); SU(Bsrc, Bn, 2); }
    __builtin_amdgcn_s_barrier();
    asm volatile("s_waitcnt lgkmcnt(0)" ::: "memory");
    __builtin_amdgcn_sched_barrier(0);
    __builtin_amdgcn_s_setprio(1);
    #pragma unroll
    for (int n = 0; n < 6; ++n) {
      acc[2][n] = __builtin_amdgcn_mfma_f32_16x16x32_bf16(a0, b[n], acc[2][n], 0, 0, 0);
      acc[3][n] = __builtin_amdgcn_mfma_f32_16x16x32_bf16(a1, b[n], acc[3][n], 0, 0, 0);
    }
    __builtin_amdgcn_s_setprio(0);
    __builtin_amdgcn_s_barrier();

    // ---- ph2: dk=1, mi 0-1 ----
    b[0] = LDB(Bb, 0, 1); b[1] = LDB(Bb, 1, 1); b[2] = LDB(Bb, 2, 1);
    b[3] = LDB(Bb, 3, 1); b[4] = LDB(Bb, 4, 1); b[5] = LDB(Bb, 5, 1);
    a0 = LDA(Ab, 0, 1); a1 = LDA(Ab, 1, 1);
    __builtin_amdgcn_s_barrier();
    asm volatile("s_waitcnt lgkmcnt(0)" ::: "memory");
    __builtin_amdgcn_sched_barrier(0);
    __builtin_amdgcn_s_setprio(1);
    #pragma unroll
    for (int n = 0; n < 6; ++n) {
      acc[0][n] = __builtin_amdgcn_mfma_f32_16x16x32_bf16(a0, b[n], acc[0][n], 0, 0, 0);
      acc[1][n] = __builtin_amdgcn_mfma_f32_16x16x32_bf16(a1, b[n], acc[1][n], 0, 0, 0);
    }
    __builtin_amdgcn_s_setprio(0);
    __builtin_amdgcn_s_barrier();

    // ---- ph3: dk=1, mi 2-3 ----
    a0 = LDA(Ab, 2, 1); a1 = LDA(Ab, 3, 1);
    __builtin_amdgcn_s_barrier();
    asm volatile("s_waitcnt lgkmcnt(0)" ::: "memory");
    __builtin_amdgcn_sched_barrier(0);
    __builtin_amdgcn_s_setprio(1);
    #pragma unroll
    for (int n = 0; n < 6; ++n) {
      acc[2][n] = __builtin_amdgcn_mfma_f32_16x16x32_bf16(a0, b[n], acc[2][n], 0, 0, 0);
      acc[3][n] = __builtin_amdgcn_mfma_f32_16x16x32_bf16(a1, b[n], acc[3][n], 0, 0, 0);
    }
    __builtin_amdgcn_s_setprio(0);
    asm volatile("s_waitcnt vmcnt(0)" ::: "memory");  // loads issued >=2.5 phases ago
    __builtin_amdgcn_s_barrier();
  }

  if (MODE == 0) {
    float* outp = (float*)Cv;
    #pragma unroll
    for (int mi = 0; mi < 4; ++mi)
      #pragma unroll
      for (int n = 0; n < 6; ++n)
        #pragma unroll
        for (int rr = 0; rr < 4; ++rr) {
          const size_t idx = (size_t)(row0 + wm + mi * 16 + g * 4 + rr) * (size_t)N
                           + (col0 + wn + n * 16 + r);
          outp[idx] = acc[mi][n][rr];
        }
  } else {
    unsigned short* outp = (unsigned short*)Cv;
    const int hc0 = col0 + wn;               // head-aligned (multiple of 96)
    if (hc0 < 3840) {                        // Q or K head: fused RoPE
      #pragma unroll
      for (int mi = 0; mi < 4; ++mi)
        #pragma unroll
        for (int rr = 0; rr < 4; ++rr) {
          const int row = row0 + wm + mi * 16 + g * 4 + rr;
          const int cb = row * 96;
          const size_t rb = (size_t)row * N + hc0;
          #pragma unroll
          for (int n = 0; n < 3; ++n) {
            const int d = n * 16 + r;
            const float x1 = acc[mi][n][rr], x2 = acc[mi][n + 3][rr];
            const float c1 = cs[cb + d], s1 = sn[cb + d];
            const float c2 = cs[cb + d + 48], s2 = sn[cb + d + 48];
            outp[rb + d]      = f2bf(x1 * c1 - x2 * s1);
            outp[rb + d + 48] = f2bf(x2 * c2 + x1 * s2);
          }
        }
    } else {                                 // V head: plain bf16
      #pragma unroll
      for (int mi = 0; mi < 4; ++mi)
        #pragma unroll
        for (int n = 0; n < 6; ++n)
          #pragma unroll
          for (int rr = 0; rr < 4; ++rr) {
            const size_t idx = (size_t)(row0 + wm + mi * 16 + g * 4 + rr) * (size_t)N
                             + (col0 + wn + n * 16 + r);
            outp[idx] = f2bf(acc[mi][n][rr]);
          }
    }
  }
}

// ---------------- V transpose: qkv[b,s,3840+kvh*96+d] -> vt[b,kvh,d,s] ----------------
__global__ __launch_bounds__(256) void vtrans(const unsigned short* __restrict__ qkv,
                                              unsigned short* __restrict__ vt) {
  __shared__ __align__(16) unsigned short T[64 * 104];
  const int s0 = blockIdx.x * 64;
  const int kvh = blockIdx.y, b = blockIdx.z;
  const int tid = threadIdx.x;
  #pragma unroll
  for (int it = 0; it < 3; ++it) {
    const int c = it * 256 + tid;
    const int sr = c / 12, d0 = (c % 12) * 8;
    *(u32x4*)&T[sr * 104 + d0] =
        *(const u32x4*)&qkv[(size_t)(b * 2048 + s0 + sr) * 4608 + 3840 + kvh * 96 + d0];
  }
  __syncthreads();
  #pragma unroll
  for (int it = 0; it < 3; ++it) {
    const int c = it * 256 + tid;
    const int dr = c >> 3, k0 = (c & 7) * 8;
    u16x8 o;
    #pragma unroll
    for (int j = 0; j < 8; ++j) o[j] = T[(k0 + j) * 104 + dr];
    *(u16x8*)&vt[((size_t)(b * 8 + kvh) * 96 + dr) * 2048 + s0 + k0] = o;
  }
}

// ---------------- Flash attention, causal GQA, swapped QK^T (r12 exact) ----------------
__global__ __launch_bounds__(512) void attn_fwd(const unsigned short* __restrict__ qkv,
                                                const unsigned short* __restrict__ vt,
                                                unsigned short* __restrict__ ctx) {
  __shared__ __align__(16) unsigned short SMEM[40960];  // 80 KB
  const int wg = blockIdx.x;             // 0..255
  const int xcd = wg & 7, j = wg >> 3;   // j 0..31
  const int c = xcd + ((j >> 4) << 3);   // (b,kvh) id, 0..15
  const int b = c >> 3, kvh = c & 7;
  const int rj = j & 15;
  const int h = kvh * 4 + (rj >> 2);
  const int pr = rj & 3;                 // fold pair: qt in {7-pr, pr}
  const int tid = threadIdx.x;
  const int wave = tid >> 6, lane = tid & 63;
  const int g = lane >> 4, r = lane & 15;
  const float kLS = 0.14724445f;         // (1/sqrt(96)) * log2(e)

  const unsigned short* kgbase = qkv + (size_t)(b * 2048) * 4608 + 3072 + kvh * 96;
  const unsigned short* vgbase = vt + (size_t)(b * 8 + kvh) * 96 * 2048;

  auto STAGE = [&](int t, int bi) {
    const int kv0 = t * 64;
    unsigned short* kd = SMEM + bi * 6144;
    unsigned short* vd = SMEM + 12288 + bi * 6144;
    #pragma unroll
    for (int i = 0; i < 3; ++i) {
      const int l = i * 512 + tid;
      if (l < 768) {  // K: [dk][row][c], src chunk c^((row>>1)&3)
        const int dk = l >> 8, rem = l & 255;
        const int row = rem >> 2, cc = rem & 3;
        const int csrc = cc ^ ((row >> 1) & 3);
        gload_lds16(kgbase + (size_t)(kv0 + row) * 4608 + dk * 32 + csrc * 8, kd + l * 8);
      } else {        // V: [row][c], src chunk c^(row&7)
        const int lv = l - 768;
        const int row = lv >> 3, cc = lv & 7;
        const int csrc = cc ^ (row & 7);
        gload_lds16(vgbase + (size_t)row * 2048 + kv0 + csrc * 8, vd + lv * 8);
      }
    }
  };

  #pragma unroll 1
  for (int sel = 0; sel < 2; ++sel) {
    const int qt = sel ? pr : 7 - pr;
    const int nt = qt * 4 + 4;
    const int q0 = qt * 256 + wave * 32;

    __syncthreads();   // protect LDS (prev epilogue reads) before re-staging

    bf16x8 qf[2][3];
    #pragma unroll
    for (int qb = 0; qb < 2; ++qb)
      #pragma unroll
      for (int dk = 0; dk < 3; ++dk)
        qf[qb][dk] = ld_frag(&qkv[(size_t)(b * 2048 + q0 + qb * 16 + r) * 4608 + h * 96 + dk * 32 + g * 8]);

    f32x4 o[6][2] = {};
    float m_[2] = {-1e30f, -1e30f};
    float l_[2] = {0.f, 0.f};

    STAGE(0, 0);
    __syncthreads();

    for (int t = 0; t < nt; ++t) {
      const int cur = t & 1;
      if (t + 1 < nt) STAGE(t + 1, cur ^ 1);
      const int kv0 = t * 64;
      const unsigned short* Ks = SMEM + cur * 6144;
      const unsigned short* Vs = SMEM + 12288 + cur * 6144;
      unsigned short* Ps = SMEM + 24576 + wave * 2048;

      if (kv0 <= q0 + 31) {  // wave has at least one unmasked element
        f32x4 st[4][2] = {};
        #pragma unroll
        for (int dk = 0; dk < 3; ++dk) {
          bf16x8 af[4];
          #pragma unroll
          for (int kb = 0; kb < 4; ++kb)
            af[kb] = ld_frag(&Ks[dk * 2048 + (kb * 16 + r) * 32 + ((g ^ ((r >> 1) & 3)) * 8)]);
          __builtin_amdgcn_s_setprio(1);
          #pragma unroll
          for (int kb = 0; kb < 4; ++kb)
            #pragma unroll
            for (int qb = 0; qb < 2; ++qb)
              st[kb][qb] = __builtin_amdgcn_mfma_f32_16x16x32_bf16(af[kb], qf[qb][dk], st[kb][qb], 0, 0, 0);
          __builtin_amdgcn_s_setprio(0);
        }
        // scale (exp2 domain) + causal mask (k_abs <= q_abs)
        if (kv0 + 63 > q0) {
          #pragma unroll
          for (int kb = 0; kb < 4; ++kb)
            #pragma unroll
            for (int qb = 0; qb < 2; ++qb)
              #pragma unroll
              for (int rr = 0; rr < 4; ++rr) {
                const int ka = kv0 + kb * 16 + g * 4 + rr;
                const int qa = q0 + qb * 16 + r;
                const float s = st[kb][qb][rr] * kLS;
                st[kb][qb][rr] = (ka <= qa) ? s : -1e30f;
              }
        } else {
          #pragma unroll
          for (int kb = 0; kb < 4; ++kb)
            #pragma unroll
            for (int qb = 0; qb < 2; ++qb)
              #pragma unroll
              for (int rr = 0; rr < 4; ++rr)
                st[kb][qb][rr] *= kLS;
        }
        // online softmax (exp2 domain), per lane = its q column; T13 exact defer
        #pragma unroll
        for (int qb = 0; qb < 2; ++qb) {
          float mx = st[0][qb][0];
          #pragma unroll
          for (int kb = 0; kb < 4; ++kb)
            #pragma unroll
            for (int rr = 0; rr < 4; ++rr) mx = fmaxf(mx, st[kb][qb][rr]);
          mx = fmaxf(mx, __shfl_xor(mx, 16));
          mx = fmaxf(mx, __shfl_xor(mx, 32));
          if (__all(mx <= m_[qb])) {
            float rs = 0.f;
            #pragma unroll
            for (int kb = 0; kb < 4; ++kb)
              #pragma unroll
              for (int rr = 0; rr < 4; ++rr) {
                const float p = __builtin_amdgcn_exp2f(st[kb][qb][rr] - m_[qb]);
                st[kb][qb][rr] = p;
                rs += p;
              }
            rs += __shfl_xor(rs, 16);
            rs += __shfl_xor(rs, 32);
            l_[qb] += rs;
          } else {
            const float mnew = fmaxf(m_[qb], mx);
            const float corr = __builtin_amdgcn_exp2f(m_[qb] - mnew);
            m_[qb] = mnew;
            float rs = 0.f;
            #pragma unroll
            for (int kb = 0; kb < 4; ++kb)
              #pragma unroll
              for (int rr = 0; rr < 4; ++rr) {
                const float p = __builtin_amdgcn_exp2f(st[kb][qb][rr] - mnew);
                st[kb][qb][rr] = p;
                rs += p;
              }
            rs += __shfl_xor(rs, 16);
            rs += __shfl_xor(rs, 32);
            l_[qb] = l_[qb] * corr + rs;
            #pragma unroll
            for (int db = 0; db < 6; ++db) o[db][qb] *= corr;
          }
        }
        // P[q][k] (bf16) to per-wave LDS, swizzled
        #pragma unroll
        for (int kb = 0; kb < 4; ++kb)
          #pragma unroll
          for (int qb = 0; qb < 2; ++qb) {
            u16x4 w;
            #pragma unroll
            for (int rr = 0; rr < 4; ++rr) w[rr] = f2bf(st[kb][qb][rr]);
            const int q = qb * 16 + r;
            *(u16x4*)&Ps[q * 64 + (((2 * kb + (g >> 1)) ^ (r & 7)) << 3) + (g & 1) * 4] = w;
          }
        // O^T += V^T * P^T
        #pragma unroll
        for (int kk = 0; kk < 2; ++kk) {
          bf16x8 pb[2];
          #pragma unroll
          for (int qb = 0; qb < 2; ++qb)
            pb[qb] = ld_frag(&Ps[(qb * 16 + r) * 64 + ((kk * 4 + g) ^ (r & 7)) * 8]);
          __builtin_amdgcn_s_setprio(1);
          #pragma unroll
          for (int db = 0; db < 6; ++db) {
            const bf16x8 va = ld_frag(&Vs[(db * 16 + r) * 64 + ((kk * 4 + g) ^ (r & 7)) * 8]);
            #pragma unroll
            for (int qb = 0; qb < 2; ++qb)
              o[db][qb] = __builtin_amdgcn_mfma_f32_16x16x32_bf16(va, pb[qb], o[db][qb], 0, 0, 0);
          }
          __builtin_amdgcn_s_setprio(0);
        }
      }
      __syncthreads();
    }

    // epilogue: normalize, transpose through LDS (per-wave region), coalesced stores
    const float inv_l[2] = {1.f / l_[0], 1.f / l_[1]};
    unsigned short* obuf = SMEM + wave * 3328;  // 32 x 104 per wave
    #pragma unroll
    for (int db = 0; db < 6; ++db)
      #pragma unroll
      for (int qb = 0; qb < 2; ++qb) {
        u16x4 w;
        #pragma unroll
        for (int rr = 0; rr < 4; ++rr) w[rr] = f2bf(o[db][qb][rr] * inv_l[qb]);
        *(u16x4*)&obuf[(qb * 16 + r) * 104 + db * 16 + g * 4] = w;
      }
    #pragma unroll
    for (int it = 0; it < 6; ++it) {
      const int cc = it * 64 + lane;
      const int qr = cc / 12, d0 = (cc % 12) * 8;
      *(u32x4*)&ctx[(size_t)(b * 2048 + q0 + qr) * 3072 + h * 96 + d0] =
          *(const u32x4*)&obuf[qr * 104 + d0];
    }
  }
}

extern "C" void kernel_launch(void* const* d_in, const int* in_sizes, int n_in,
                              void* d_out, int out_size, void* d_ws, size_t ws_size,
                              hipStream_t stream) {
  const float* hs   = (const float*)d_in[0];
  const float* cosp = (const float*)d_in[1];
  const float* sinp = (const float*)d_in[2];
  const float* wqkv = (const float*)d_in[4];
  const float* wo   = (const float*)d_in[5];
  float* out = (float*)d_out;

  // workspace (bf16 elems): qkv 18,874,368 | hsb 12,582,912 | wqb 14,155,776
  // vt (3,145,728) aliases hsb[0:...] (written after gemm1 by vtrans).
  // wob (9,437,184): if ws is big enough, FRESH region after wqb (enables the
  // in-gemm1 tail-fill conversion — no alias with A/B/C); otherwise alias
  // hsb+3145728 and convert AFTER gemm1 (r12 ordering). Deterministic: ws_size
  // is constant across calls.
  unsigned short* qkv = (unsigned short*)d_ws;
  unsigned short* hsb = qkv + 18874368;
  unsigned short* wqb = hsb + 12582912;
  unsigned short* vt  = hsb;
  unsigned short* ctx = wqb;

  const bool big_ws = ws_size >= (size_t)110100480;  // (45,613,056 + 9,437,184) * 2 B
  unsigned short* wob = big_ws ? (wqb + 14155776) : (hsb + 3145728);

  cvt2_bf16<<<26112, 256, 0, stream>>>(hs, hsb, 3145728, wqkv, wqb, 3538944);
  if (big_ws) {
    // gemm1: 384 gemm blocks + 128 tail-filler blocks converting wo -> wob
    gemm8p<1><<<512, 512, 0, stream>>>(hsb, wqb, (void*)qkv, cosp, sinp, 4096, 4608, 3072,
                                       wo, wob, 2359296, 384);
  } else {
    gemm8p<1><<<384, 512, 0, stream>>>(hsb, wqb, (void*)qkv, cosp, sinp, 4096, 4608, 3072,
                                       nullptr, nullptr, 0, 384);
    cvt_bf16<<<9216, 256, 0, stream>>>(wo, wob, 2359296);
  }
  vtrans<<<dim3(32, 8, 2), 256, 0, stream>>>(qkv, vt);
  attn_fwd<<<256, 512, 0, stream>>>(qkv, vt, ctx);
  gemm8p<0><<<256, 512, 0, stream>>>(ctx, wob, (void*)out, cosp, sinp, 4096, 3072, 3072,
                                     nullptr, nullptr, 0, 256);
}

// Round 18
// 332.141 us; speedup vs baseline: 1.7457x; 1.0417x over previous
//
#include <hip/hip_runtime.h>

typedef __attribute__((ext_vector_type(8))) __bf16 bf16x8;
typedef __attribute__((ext_vector_type(4))) float f32x4;
typedef __attribute__((ext_vector_type(4))) unsigned int u32x4;
typedef __attribute__((ext_vector_type(4))) unsigned short u16x4;
typedef __attribute__((ext_vector_type(8))) unsigned short u16x8;

__device__ __forceinline__ unsigned short f2bf(float x) {
  unsigned u = __builtin_bit_cast(unsigned, x);
  u += 0x7fffu + ((u >> 16) & 1u);
  return (unsigned short)(u >> 16);
}
__device__ __forceinline__ float bf2f(unsigned short h) {
  unsigned u = ((unsigned)h) << 16;
  return __builtin_bit_cast(float, u);
}
__device__ __forceinline__ bf16x8 ld_frag(const unsigned short* p) {
  u32x4 u = *(const u32x4*)p;
  return __builtin_bit_cast(bf16x8, u);
}
__device__ __forceinline__ void gload_lds16(const unsigned short* g, unsigned short* l) {
  __builtin_amdgcn_global_load_lds(
      (const __attribute__((address_space(1))) void*)g,
      (__attribute__((address_space(3))) void*)l, 16, 0, 0);
}

// ---------------- f32 -> bf16 conversion (vectorized) ----------------
__global__ __launch_bounds__(256) void cvt_bf16(const float* __restrict__ in,
                                                unsigned short* __restrict__ out, int n4) {
  int i = blockIdx.x * 256 + threadIdx.x;
  if (i >= n4) return;
  f32x4 v = *((const f32x4*)in + i);
  u16x4 o;
  #pragma unroll
  for (int j = 0; j < 4; ++j) o[j] = f2bf(v[j]);
  *((u16x4*)out + i) = o;
}

// ------- merged f32 -> bf16 conversion for two buffers (one launch) -------
__global__ __launch_bounds__(256) void cvt2_bf16(const float* __restrict__ a,
                                                 unsigned short* __restrict__ oa, int na4,
                                                 const float* __restrict__ b,
                                                 unsigned short* __restrict__ ob, int nb4) {
  const int i = blockIdx.x * 256 + threadIdx.x;
  if (i < na4) {
    f32x4 v = *((const f32x4*)a + i);
    u16x4 o;
    #pragma unroll
    for (int j = 0; j < 4; ++j) o[j] = f2bf(v[j]);
    *((u16x4*)oa + i) = o;
  } else {
    const int k = i - na4;
    if (k < nb4) {
      f32x4 v = *((const f32x4*)b + k);
      u16x4 o;
      #pragma unroll
      for (int j = 0; j < 4; ++j) o[j] = f2bf(v[j]);
      *((u16x4*)ob + k) = o;
    }
  }
}

// ---- 8-phase GEMM, 4M x 2N wave map (r12 staging spread + optional tail-fill) ----
// Blocks >= gemm_blocks run a grid-stride f32->bf16 conversion (fills round-2
// idle CUs). cvt_dst MUST NOT alias A/B/C.
// MODE 0: f32 C (gemm2). MODE 1: bf16 C + fused RoPE on heads < 3840 (gemm1).
template <int MODE>
__global__ __launch_bounds__(512, 2) void gemm8p(const unsigned short* __restrict__ A,
                                                 const unsigned short* __restrict__ B,
                                                 void* __restrict__ Cv,
                                                 const float* __restrict__ cs,
                                                 const float* __restrict__ sn,
                                                 int M, int N, int K,
                                                 const float* __restrict__ cvt_src,
                                                 unsigned short* __restrict__ cvt_dst,
                                                 int cvt_n4, int gemm_blocks) {
  __shared__ __align__(16) unsigned short SM[57344];  // 112 KB
  if ((int)blockIdx.x >= gemm_blocks) {
    const int nthr = ((int)gridDim.x - gemm_blocks) * 512;
    for (int i = ((int)blockIdx.x - gemm_blocks) * 512 + (int)threadIdx.x;
         i < cvt_n4; i += nthr) {
      f32x4 v = *((const f32x4*)cvt_src + i);
      u16x4 o;
      #pragma unroll
      for (int j = 0; j < 4; ++j) o[j] = f2bf(v[j]);
      *((u16x4*)cvt_dst + i) = o;
    }
    return;
  }
  const int nwg = gemm_blocks;
  const int swz = (blockIdx.x & 7) * (nwg >> 3) + (blockIdx.x >> 3);
  const int bx = swz & 15, by = swz >> 4;      // M/256 == 16 for both GEMMs
  const int row0 = bx * 256, col0 = by * 192;
  const int tid = threadIdx.x;
  const int wave = tid >> 6, lane = tid & 63;
  const int g = lane >> 4, r = lane & 15;
  const int wm = (wave >> 1) * 64, wn = (wave & 1) * 96;
  const int NT = K >> 6;

  const unsigned short* Agb = A + (size_t)row0 * K;
  const unsigned short* Bgb = B + (size_t)col0 * K;

  f32x4 acc[4][6] = {};

  auto SU = [&](const unsigned short* src, unsigned short* dst, int u) {
    const int pos = u * 512 + tid;
    const int rw = pos >> 3, cc = pos & 7;
    gload_lds16(src + (size_t)rw * K + ((cc ^ (rw & 7)) * 8), dst + pos * 8);
  };
  auto LDA = [&](const unsigned short* base, int mi, int dk) {
    const int rw = wm + mi * 16 + r;
    return ld_frag(base + rw * 64 + (((dk * 4 + g) ^ (r & 7)) * 8));
  };
  auto LDB = [&](const unsigned short* base, int ni, int dk) {
    const int rw = wn + ni * 16 + r;
    return ld_frag(base + rw * 64 + (((dk * 4 + g) ^ (r & 7)) * 8));
  };

  SU(Agb, SM, 0); SU(Agb, SM, 1); SU(Agb, SM, 2); SU(Agb, SM, 3);
  SU(Bgb, SM + 16384, 0); SU(Bgb, SM + 16384, 1); SU(Bgb, SM + 16384, 2);
  __syncthreads();

  for (int t = 0; t < NT; ++t) {
    const int d = t & 1;
    const unsigned short* Ab = SM + d * 28672;
    const unsigned short* Bb = Ab + 16384;
    unsigned short* An = SM + (d ^ 1) * 28672;
    unsigned short* Bn = An + 16384;
    const unsigned short* Asrc = Agb + (t + 1) * 64;
    const unsigned short* Bsrc = Bgb + (t + 1) * 64;
    const bool pf = (t + 1 < NT);

    bf16x8 a0, a1, b[6];

    // ---- ph0: dk=0, mi 0-1 (B dk0 held through ph1); stage A0-2 ----
    b[0] = LDB(Bb, 0, 0); b[1] = LDB(Bb, 1, 0); b[2] = LDB(Bb, 2, 0);
    b[3] = LDB(Bb, 3, 0); b[4] = LDB(Bb, 4, 0); b[5] = LDB(Bb, 5, 0);
    a0 = LDA(Ab, 0, 0); a1 = LDA(Ab, 1, 0);
    if (pf) { SU(Asrc, An, 0); SU(Asrc, An, 1); SU(Asrc, An, 2); }
    __builtin_amdgcn_s_barrier();
    asm volatile("s_waitcnt lgkmcnt(0)" ::: "memory");
    __builtin_amdgcn_sched_barrier(0);
    __builtin_amdgcn_s_setprio(1);
    #pragma unroll
    for (int n = 0; n < 6; ++n) {
      acc[0][n] = __builtin_amdgcn_mfma_f32_16x16x32_bf16(a0, b[n], acc[0][n], 0, 0, 0);
      acc[1][n] = __builtin_amdgcn_mfma_f32_16x16x32_bf16(a1, b[n], acc[1][n], 0, 0, 0);
    }
    __builtin_amdgcn_s_setprio(0);
    __builtin_amdgcn_s_barrier();

    // ---- ph1: dk=0, mi 2-3; stage A3 + B0 ----
    a0 = LDA(Ab, 2, 0); a1 = LDA(Ab, 3, 0);
    if (pf) { SU(Asrc, An, 3); SU(Bsrc, Bn, 0); }
    __builtin_amdgcn_s_barrier();
    asm volatile("s_waitcnt lgkmcnt(0)" ::: "memory");
    __builtin_amdgcn_sched_barrier(0);
    __builtin_amdgcn_s_setprio(1);
    #pragma unroll
    for (int n = 0; n < 6; ++n) {
      acc[2][n] = __builtin_amdgcn_mfma_f32_16x16x32_bf16(a0, b[n], acc[2][n], 0, 0, 0);
      acc[3][n] = __builtin_amdgcn_mfma_f32_16x16x32_bf16(a1, b[n], acc[3][n], 0, 0, 0);
    }
    __builtin_amdgcn_s_setprio(0);
    __builtin_amdgcn_s_barrier();

    // ---- ph2: dk=1, mi 0-1; stage B1-2 ----
    b[0] = LDB(Bb, 0, 1); b[1] = LDB(Bb, 1, 1); b[2] = LDB(Bb, 2, 1);
    b[3] = LDB(Bb, 3, 1); b[4] = LDB(Bb, 4, 1); b[5] = LDB(Bb, 5, 1);
    a0 = LDA(Ab, 0, 1); a1 = LDA(Ab, 1, 1);
    if (pf) { SU(Bsrc, Bn, 1); SU(Bsrc, Bn, 2); }
    __builtin_amdgcn_s_barrier();
    asm volatile("s_waitcnt lgkmcnt(0)" ::: "memory");
    __builtin_amdgcn_sched_barrier(0);
    __builtin_amdgcn_s_setprio(1);
    #pragma unroll
    for (int n = 0; n < 6; ++n) {
      acc[0][n] = __builtin_amdgcn_mfma_f32_16x16x32_bf16(a0, b[n], acc[0][n], 0, 0, 0);
      acc[1][n] = __builtin_amdgcn_mfma_f32_16x16x32_bf16(a1, b[n], acc[1][n], 0, 0, 0);
    }
    __builtin_amdgcn_s_setprio(0);
    __builtin_amdgcn_s_barrier();

    // ---- ph3: dk=1, mi 2-3 ----
    a0 = LDA(Ab, 2, 1); a1 = LDA(Ab, 3, 1);
    __builtin_amdgcn_s_barrier();
    asm volatile("s_waitcnt lgkmcnt(0)" ::: "memory");
    __builtin_amdgcn_sched_barrier(0);
    __builtin_amdgcn_s_setprio(1);
    #pragma unroll
    for (int n = 0; n < 6; ++n) {
      acc[2][n] = __builtin_amdgcn_mfma_f32_16x16x32_bf16(a0, b[n], acc[2][n], 0, 0, 0);
      acc[3][n] = __builtin_amdgcn_mfma_f32_16x16x32_bf16(a1, b[n], acc[3][n], 0, 0, 0);
    }
    __builtin_amdgcn_s_setprio(0);
    asm volatile("s_waitcnt vmcnt(0)" ::: "memory");
    __builtin_amdgcn_s_barrier();
  }

  if (MODE == 0) {
    float* outp = (float*)Cv;
    #pragma unroll
    for (int mi = 0; mi < 4; ++mi)
      #pragma unroll
      for (int n = 0; n < 6; ++n)
        #pragma unroll
        for (int rr = 0; rr < 4; ++rr) {
          const size_t idx = (size_t)(row0 + wm + mi * 16 + g * 4 + rr) * (size_t)N
                           + (col0 + wn + n * 16 + r);
          outp[idx] = acc[mi][n][rr];
        }
  } else {
    unsigned short* outp = (unsigned short*)Cv;
    const int hc0 = col0 + wn;               // head-aligned (multiple of 96)
    if (hc0 < 3840) {                        // Q or K head: fused RoPE
      #pragma unroll
      for (int mi = 0; mi < 4; ++mi)
        #pragma unroll
        for (int rr = 0; rr < 4; ++rr) {
          const int row = row0 + wm + mi * 16 + g * 4 + rr;
          const int cb = row * 96;
          const size_t rb = (size_t)row * N + hc0;
          #pragma unroll
          for (int n = 0; n < 3; ++n) {
            const int d = n * 16 + r;
            const float x1 = acc[mi][n][rr], x2 = acc[mi][n + 3][rr];
            const float c1 = cs[cb + d], s1 = sn[cb + d];
            const float c2 = cs[cb + d + 48], s2 = sn[cb + d + 48];
            outp[rb + d]      = f2bf(x1 * c1 - x2 * s1);
            outp[rb + d + 48] = f2bf(x2 * c2 + x1 * s2);
          }
        }
    } else {                                 // V head: plain bf16
      #pragma unroll
      for (int mi = 0; mi < 4; ++mi)
        #pragma unroll
        for (int n = 0; n < 6; ++n)
          #pragma unroll
          for (int rr = 0; rr < 4; ++rr) {
            const size_t idx = (size_t)(row0 + wm + mi * 16 + g * 4 + rr) * (size_t)N
                             + (col0 + wn + n * 16 + r);
            outp[idx] = f2bf(acc[mi][n][rr]);
          }
    }
  }
}

// ---------------- V transpose: qkv[b,s,3840+kvh*96+d] -> vt[b,kvh,d,s] ----------------
__global__ __launch_bounds__(256) void vtrans(const unsigned short* __restrict__ qkv,
                                              unsigned short* __restrict__ vt) {
  __shared__ __align__(16) unsigned short T[64 * 104];
  const int s0 = blockIdx.x * 64;
  const int kvh = blockIdx.y, b = blockIdx.z;
  const int tid = threadIdx.x;
  #pragma unroll
  for (int it = 0; it < 3; ++it) {
    const int c = it * 256 + tid;
    const int sr = c / 12, d0 = (c % 12) * 8;
    *(u32x4*)&T[sr * 104 + d0] =
        *(const u32x4*)&qkv[(size_t)(b * 2048 + s0 + sr) * 4608 + 3840 + kvh * 96 + d0];
  }
  __syncthreads();
  #pragma unroll
  for (int it = 0; it < 3; ++it) {
    const int c = it * 256 + tid;
    const int dr = c >> 3, k0 = (c & 7) * 8;
    u16x8 o;
    #pragma unroll
    for (int j = 0; j < 8; ++j) o[j] = T[(k0 + j) * 104 + dr];
    *(u16x8*)&vt[((size_t)(b * 8 + kvh) * 96 + dr) * 2048 + s0 + k0] = o;
  }
}

// ---------------- Flash attention, causal GQA, swapped QK^T (r12 exact) ----------------
__global__ __launch_bounds__(512) void attn_fwd(const unsigned short* __restrict__ qkv,
                                                const unsigned short* __restrict__ vt,
                                                unsigned short* __restrict__ ctx) {
  __shared__ __align__(16) unsigned short SMEM[40960];  // 80 KB
  const int wg = blockIdx.x;             // 0..255
  const int xcd = wg & 7, j = wg >> 3;   // j 0..31
  const int c = xcd + ((j >> 4) << 3);   // (b,kvh) id, 0..15
  const int b = c >> 3, kvh = c & 7;
  const int rj = j & 15;
  const int h = kvh * 4 + (rj >> 2);
  const int pr = rj & 3;                 // fold pair: qt in {7-pr, pr}
  const int tid = threadIdx.x;
  const int wave = tid >> 6, lane = tid & 63;
  const int g = lane >> 4, r = lane & 15;
  const float kLS = 0.14724445f;         // (1/sqrt(96)) * log2(e)

  const unsigned short* kgbase = qkv + (size_t)(b * 2048) * 4608 + 3072 + kvh * 96;
  const unsigned short* vgbase = vt + (size_t)(b * 8 + kvh) * 96 * 2048;

  auto STAGE = [&](int t, int bi) {
    const int kv0 = t * 64;
    unsigned short* kd = SMEM + bi * 6144;
    unsigned short* vd = SMEM + 12288 + bi * 6144;
    #pragma unroll
    for (int i = 0; i < 3; ++i) {
      const int l = i * 512 + tid;
      if (l < 768) {  // K: [dk][row][c], src chunk c^((row>>1)&3)
        const int dk = l >> 8, rem = l & 255;
        const int row = rem >> 2, cc = rem & 3;
        const int csrc = cc ^ ((row >> 1) & 3);
        gload_lds16(kgbase + (size_t)(kv0 + row) * 4608 + dk * 32 + csrc * 8, kd + l * 8);
      } else {        // V: [row][c], src chunk c^(row&7)
        const int lv = l - 768;
        const int row = lv >> 3, cc = lv & 7;
        const int csrc = cc ^ (row & 7);
        gload_lds16(vgbase + (size_t)row * 2048 + kv0 + csrc * 8, vd + lv * 8);
      }
    }
  };

  #pragma unroll 1
  for (int sel = 0; sel < 2; ++sel) {
    const int qt = sel ? pr : 7 - pr;
    const int nt = qt * 4 + 4;
    const int q0 = qt * 256 + wave * 32;

    __syncthreads();   // protect LDS (prev epilogue reads) before re-staging

    bf16x8 qf[2][3];
    #pragma unroll
    for (int qb = 0; qb < 2; ++qb)
      #pragma unroll
      for (int dk = 0; dk < 3; ++dk)
        qf[qb][dk] = ld_frag(&qkv[(size_t)(b * 2048 + q0 + qb * 16 + r) * 4608 + h * 96 + dk * 32 + g * 8]);

    f32x4 o[6][2] = {};
    float m_[2] = {-1e30f, -1e30f};
    float l_[2] = {0.f, 0.f};

    STAGE(0, 0);
    __syncthreads();

    for (int t = 0; t < nt; ++t) {
      const int cur = t & 1;
      if (t + 1 < nt) STAGE(t + 1, cur ^ 1);
      const int kv0 = t * 64;
      const unsigned short* Ks = SMEM + cur * 6144;
      const unsigned short* Vs = SMEM + 12288 + cur * 6144;
      unsigned short* Ps = SMEM + 24576 + wave * 2048;

      if (kv0 <= q0 + 31) {  // wave has at least one unmasked element
        f32x4 st[4][2] = {};
        #pragma unroll
        for (int dk = 0; dk < 3; ++dk) {
          bf16x8 af[4];
          #pragma unroll
          for (int kb = 0; kb < 4; ++kb)
            af[kb] = ld_frag(&Ks[dk * 2048 + (kb * 16 + r) * 32 + ((g ^ ((r >> 1) & 3)) * 8)]);
          __builtin_amdgcn_s_setprio(1);
          #pragma unroll
          for (int kb = 0; kb < 4; ++kb)
            #pragma unroll
            for (int qb = 0; qb < 2; ++qb)
              st[kb][qb] = __builtin_amdgcn_mfma_f32_16x16x32_bf16(af[kb], qf[qb][dk], st[kb][qb], 0, 0, 0);
          __builtin_amdgcn_s_setprio(0);
        }
        // scale (exp2 domain) + causal mask (k_abs <= q_abs)
        if (kv0 + 63 > q0) {
          #pragma unroll
          for (int kb = 0; kb < 4; ++kb)
            #pragma unroll
            for (int qb = 0; qb < 2; ++qb)
              #pragma unroll
              for (int rr = 0; rr < 4; ++rr) {
                const int ka = kv0 + kb * 16 + g * 4 + rr;
                const int qa = q0 + qb * 16 + r;
                const float s = st[kb][qb][rr] * kLS;
                st[kb][qb][rr] = (ka <= qa) ? s : -1e30f;
              }
        } else {
          #pragma unroll
          for (int kb = 0; kb < 4; ++kb)
            #pragma unroll
            for (int qb = 0; qb < 2; ++qb)
              #pragma unroll
              for (int rr = 0; rr < 4; ++rr)
                st[kb][qb][rr] *= kLS;
        }
        // online softmax (exp2 domain), per lane = its q column; T13 exact defer
        #pragma unroll
        for (int qb = 0; qb < 2; ++qb) {
          float mx = st[0][qb][0];
          #pragma unroll
          for (int kb = 0; kb < 4; ++kb)
            #pragma unroll
            for (int rr = 0; rr < 4; ++rr) mx = fmaxf(mx, st[kb][qb][rr]);
          mx = fmaxf(mx, __shfl_xor(mx, 16));
          mx = fmaxf(mx, __shfl_xor(mx, 32));
          if (__all(mx <= m_[qb])) {
            float rs = 0.f;
            #pragma unroll
            for (int kb = 0; kb < 4; ++kb)
              #pragma unroll
              for (int rr = 0; rr < 4; ++rr) {
                const float p = __builtin_amdgcn_exp2f(st[kb][qb][rr] - m_[qb]);
                st[kb][qb][rr] = p;
                rs += p;
              }
            rs += __shfl_xor(rs, 16);
            rs += __shfl_xor(rs, 32);
            l_[qb] += rs;
          } else {
            const float mnew = fmaxf(m_[qb], mx);
            const float corr = __builtin_amdgcn_exp2f(m_[qb] - mnew);
            m_[qb] = mnew;
            float rs = 0.f;
            #pragma unroll
            for (int kb = 0; kb < 4; ++kb)
              #pragma unroll
              for (int rr = 0; rr < 4; ++rr) {
                const float p = __builtin_amdgcn_exp2f(st[kb][qb][rr] - mnew);
                st[kb][qb][rr] = p;
                rs += p;
              }
            rs += __shfl_xor(rs, 16);
            rs += __shfl_xor(rs, 32);
            l_[qb] = l_[qb] * corr + rs;
            #pragma unroll
            for (int db = 0; db < 6; ++db) o[db][qb] *= corr;
          }
        }
        // P[q][k] (bf16) to per-wave LDS, swizzled
        #pragma unroll
        for (int kb = 0; kb < 4; ++kb)
          #pragma unroll
          for (int qb = 0; qb < 2; ++qb) {
            u16x4 w;
            #pragma unroll
            for (int rr = 0; rr < 4; ++rr) w[rr] = f2bf(st[kb][qb][rr]);
            const int q = qb * 16 + r;
            *(u16x4*)&Ps[q * 64 + (((2 * kb + (g >> 1)) ^ (r & 7)) << 3) + (g & 1) * 4] = w;
          }
        // O^T += V^T * P^T
        #pragma unroll
        for (int kk = 0; kk < 2; ++kk) {
          bf16x8 pb[2];
          #pragma unroll
          for (int qb = 0; qb < 2; ++qb)
            pb[qb] = ld_frag(&Ps[(qb * 16 + r) * 64 + ((kk * 4 + g) ^ (r & 7)) * 8]);
          __builtin_amdgcn_s_setprio(1);
          #pragma unroll
          for (int db = 0; db < 6; ++db) {
            const bf16x8 va = ld_frag(&Vs[(db * 16 + r) * 64 + ((kk * 4 + g) ^ (r & 7)) * 8]);
            #pragma unroll
            for (int qb = 0; qb < 2; ++qb)
              o[db][qb] = __builtin_amdgcn_mfma_f32_16x16x32_bf16(va, pb[qb], o[db][qb], 0, 0, 0);
          }
          __builtin_amdgcn_s_setprio(0);
        }
      }
      __syncthreads();
    }

    // epilogue: normalize, transpose through LDS (per-wave region), coalesced stores
    const float inv_l[2] = {1.f / l_[0], 1.f / l_[1]};
    unsigned short* obuf = SMEM + wave * 3328;  // 32 x 104 per wave
    #pragma unroll
    for (int db = 0; db < 6; ++db)
      #pragma unroll
      for (int qb = 0; qb < 2; ++qb) {
        u16x4 w;
        #pragma unroll
        for (int rr = 0; rr < 4; ++rr) w[rr] = f2bf(o[db][qb][rr] * inv_l[qb]);
        *(u16x4*)&obuf[(qb * 16 + r) * 104 + db * 16 + g * 4] = w;
      }
    #pragma unroll
    for (int it = 0; it < 6; ++it) {
      const int cc = it * 64 + lane;
      const int qr = cc / 12, d0 = (cc % 12) * 8;
      *(u32x4*)&ctx[(size_t)(b * 2048 + q0 + qr) * 3072 + h * 96 + d0] =
          *(const u32x4*)&obuf[qr * 104 + d0];
    }
  }
}

extern "C" void kernel_launch(void* const* d_in, const int* in_sizes, int n_in,
                              void* d_out, int out_size, void* d_ws, size_t ws_size,
                              hipStream_t stream) {
  const float* hs   = (const float*)d_in[0];
  const float* cosp = (const float*)d_in[1];
  const float* sinp = (const float*)d_in[2];
  const float* wqkv = (const float*)d_in[4];
  const float* wo   = (const float*)d_in[5];
  float* out = (float*)d_out;

  // workspace (bf16 elems): qkv 18,874,368 | hsb 12,582,912 | wqb 14,155,776
  // vt (3,145,728) aliases hsb (safe: written by vtrans after gemm1).
  // wob: fresh region after wqb when ws allows (enables in-gemm1 tail-fill,
  // no alias with A/B/C); else alias hsb+3145728 with post-gemm1 conversion.
  unsigned short* qkv = (unsigned short*)d_ws;
  unsigned short* hsb = qkv + 18874368;
  unsigned short* wqb = hsb + 12582912;
  unsigned short* vt  = hsb;
  unsigned short* ctx = wqb;

  const bool big_ws = ws_size >= (size_t)110100480;
  unsigned short* wob = big_ws ? (wqb + 14155776) : (hsb + 3145728);

  cvt2_bf16<<<26112, 256, 0, stream>>>(hs, hsb, 3145728, wqkv, wqb, 3538944);
  if (big_ws) {
    gemm8p<1><<<512, 512, 0, stream>>>(hsb, wqb, (void*)qkv, cosp, sinp, 4096, 4608, 3072,
                                       wo, wob, 2359296, 384);
  } else {
    gemm8p<1><<<384, 512, 0, stream>>>(hsb, wqb, (void*)qkv, cosp, sinp, 4096, 4608, 3072,
                                       nullptr, nullptr, 0, 384);
    cvt_bf16<<<9216, 256, 0, stream>>>(wo, wob, 2359296);
  }
  vtrans<<<dim3(32, 8, 2), 256, 0, stream>>>(qkv, vt);
  attn_fwd<<<256, 512, 0, stream>>>(qkv, vt, ctx);
  gemm8p<0><<<256, 512, 0, stream>>>(ctx, wob, (void*)out, cosp, sinp, 4096, 3072, 3072,
                                     nullptr, nullptr, 0, 256);
}

// Round 19
// 328.580 us; speedup vs baseline: 1.7646x; 1.0108x over previous
//
#include <hip/hip_runtime.h>

typedef __attribute__((ext_vector_type(8))) __bf16 bf16x8;
typedef __attribute__((ext_vector_type(4))) float f32x4;
typedef __attribute__((ext_vector_type(4))) unsigned int u32x4;
typedef __attribute__((ext_vector_type(4))) unsigned short u16x4;
typedef __attribute__((ext_vector_type(8))) unsigned short u16x8;

__device__ __forceinline__ unsigned short f2bf(float x) {
  unsigned u = __builtin_bit_cast(unsigned, x);
  u += 0x7fffu + ((u >> 16) & 1u);
  return (unsigned short)(u >> 16);
}
__device__ __forceinline__ float bf2f(unsigned short h) {
  unsigned u = ((unsigned)h) << 16;
  return __builtin_bit_cast(float, u);
}
__device__ __forceinline__ bf16x8 ld_frag(const unsigned short* p) {
  u32x4 u = *(const u32x4*)p;
  return __builtin_bit_cast(bf16x8, u);
}
__device__ __forceinline__ void gload_lds16(const unsigned short* g, unsigned short* l) {
  __builtin_amdgcn_global_load_lds(
      (const __attribute__((address_space(1))) void*)g,
      (__attribute__((address_space(3))) void*)l, 16, 0, 0);
}

// ---------------- f32 -> bf16 conversion (vectorized) ----------------
__global__ __launch_bounds__(256) void cvt_bf16(const float* __restrict__ in,
                                                unsigned short* __restrict__ out, int n4) {
  int i = blockIdx.x * 256 + threadIdx.x;
  if (i >= n4) return;
  f32x4 v = *((const f32x4*)in + i);
  u16x4 o;
  #pragma unroll
  for (int j = 0; j < 4; ++j) o[j] = f2bf(v[j]);
  *((u16x4*)out + i) = o;
}

// ------- merged f32 -> bf16 conversion for two buffers (one launch) -------
__global__ __launch_bounds__(256) void cvt2_bf16(const float* __restrict__ a,
                                                 unsigned short* __restrict__ oa, int na4,
                                                 const float* __restrict__ b,
                                                 unsigned short* __restrict__ ob, int nb4) {
  const int i = blockIdx.x * 256 + threadIdx.x;
  if (i < na4) {
    f32x4 v = *((const f32x4*)a + i);
    u16x4 o;
    #pragma unroll
    for (int j = 0; j < 4; ++j) o[j] = f2bf(v[j]);
    *((u16x4*)oa + i) = o;
  } else {
    const int k = i - na4;
    if (k < nb4) {
      f32x4 v = *((const f32x4*)b + k);
      u16x4 o;
      #pragma unroll
      for (int j = 0; j < 4; ++j) o[j] = f2bf(v[j]);
      *((u16x4*)ob + k) = o;
    }
  }
}

// ---- 8-phase GEMM, 4M x 2N wave map (r18 staging spread + tail-fill) ----
// Blocks >= gemm_blocks run a grid-stride f32->bf16 conversion (fills round-2
// idle CUs). cvt_dst MUST NOT alias A/B/C.
// MODE 0: f32 C (gemm2). MODE 1: bf16 C + fused RoPE on heads < 3840 (gemm1);
// if vtp != nullptr, V heads (>=3840) write TRANSPOSED vt[b,kvh,d,s] directly
// (vtp must not alias A/B) and skip the qkv V-region write.
template <int MODE>
__global__ __launch_bounds__(512, 2) void gemm8p(const unsigned short* __restrict__ A,
                                                 const unsigned short* __restrict__ B,
                                                 void* __restrict__ Cv,
                                                 const float* __restrict__ cs,
                                                 const float* __restrict__ sn,
                                                 int M, int N, int K,
                                                 const float* __restrict__ cvt_src,
                                                 unsigned short* __restrict__ cvt_dst,
                                                 int cvt_n4, int gemm_blocks,
                                                 unsigned short* __restrict__ vtp) {
  __shared__ __align__(16) unsigned short SM[57344];  // 112 KB
  if ((int)blockIdx.x >= gemm_blocks) {
    const int nthr = ((int)gridDim.x - gemm_blocks) * 512;
    for (int i = ((int)blockIdx.x - gemm_blocks) * 512 + (int)threadIdx.x;
         i < cvt_n4; i += nthr) {
      f32x4 v = *((const f32x4*)cvt_src + i);
      u16x4 o;
      #pragma unroll
      for (int j = 0; j < 4; ++j) o[j] = f2bf(v[j]);
      *((u16x4*)cvt_dst + i) = o;
    }
    return;
  }
  const int nwg = gemm_blocks;
  const int swz = (blockIdx.x & 7) * (nwg >> 3) + (blockIdx.x >> 3);
  const int bx = swz & 15, by = swz >> 4;      // M/256 == 16 for both GEMMs
  const int row0 = bx * 256, col0 = by * 192;
  const int tid = threadIdx.x;
  const int wave = tid >> 6, lane = tid & 63;
  const int g = lane >> 4, r = lane & 15;
  const int wm = (wave >> 1) * 64, wn = (wave & 1) * 96;
  const int NT = K >> 6;

  const unsigned short* Agb = A + (size_t)row0 * K;
  const unsigned short* Bgb = B + (size_t)col0 * K;

  f32x4 acc[4][6] = {};

  auto SU = [&](const unsigned short* src, unsigned short* dst, int u) {
    const int pos = u * 512 + tid;
    const int rw = pos >> 3, cc = pos & 7;
    gload_lds16(src + (size_t)rw * K + ((cc ^ (rw & 7)) * 8), dst + pos * 8);
  };
  auto LDA = [&](const unsigned short* base, int mi, int dk) {
    const int rw = wm + mi * 16 + r;
    return ld_frag(base + rw * 64 + (((dk * 4 + g) ^ (r & 7)) * 8));
  };
  auto LDB = [&](const unsigned short* base, int ni, int dk) {
    const int rw = wn + ni * 16 + r;
    return ld_frag(base + rw * 64 + (((dk * 4 + g) ^ (r & 7)) * 8));
  };

  SU(Agb, SM, 0); SU(Agb, SM, 1); SU(Agb, SM, 2); SU(Agb, SM, 3);
  SU(Bgb, SM + 16384, 0); SU(Bgb, SM + 16384, 1); SU(Bgb, SM + 16384, 2);
  __syncthreads();

  for (int t = 0; t < NT; ++t) {
    const int d = t & 1;
    const unsigned short* Ab = SM + d * 28672;
    const unsigned short* Bb = Ab + 16384;
    unsigned short* An = SM + (d ^ 1) * 28672;
    unsigned short* Bn = An + 16384;
    const unsigned short* Asrc = Agb + (t + 1) * 64;
    const unsigned short* Bsrc = Bgb + (t + 1) * 64;
    const bool pf = (t + 1 < NT);

    bf16x8 a0, a1, b[6];

    // ---- ph0: dk=0, mi 0-1 (B dk0 held through ph1); stage A0-2 ----
    b[0] = LDB(Bb, 0, 0); b[1] = LDB(Bb, 1, 0); b[2] = LDB(Bb, 2, 0);
    b[3] = LDB(Bb, 3, 0); b[4] = LDB(Bb, 4, 0); b[5] = LDB(Bb, 5, 0);
    a0 = LDA(Ab, 0, 0); a1 = LDA(Ab, 1, 0);
    if (pf) { SU(Asrc, An, 0); SU(Asrc, An, 1); SU(Asrc, An, 2); }
    __builtin_amdgcn_s_barrier();
    asm volatile("s_waitcnt lgkmcnt(0)" ::: "memory");
    __builtin_amdgcn_sched_barrier(0);
    __builtin_amdgcn_s_setprio(1);
    #pragma unroll
    for (int n = 0; n < 6; ++n) {
      acc[0][n] = __builtin_amdgcn_mfma_f32_16x16x32_bf16(a0, b[n], acc[0][n], 0, 0, 0);
      acc[1][n] = __builtin_amdgcn_mfma_f32_16x16x32_bf16(a1, b[n], acc[1][n], 0, 0, 0);
    }
    __builtin_amdgcn_s_setprio(0);
    __builtin_amdgcn_s_barrier();

    // ---- ph1: dk=0, mi 2-3; stage A3 + B0 ----
    a0 = LDA(Ab, 2, 0); a1 = LDA(Ab, 3, 0);
    if (pf) { SU(Asrc, An, 3); SU(Bsrc, Bn, 0); }
    __builtin_amdgcn_s_barrier();
    asm volatile("s_waitcnt lgkmcnt(0)" ::: "memory");
    __builtin_amdgcn_sched_barrier(0);
    __builtin_amdgcn_s_setprio(1);
    #pragma unroll
    for (int n = 0; n < 6; ++n) {
      acc[2][n] = __builtin_amdgcn_mfma_f32_16x16x32_bf16(a0, b[n], acc[2][n], 0, 0, 0);
      acc[3][n] = __builtin_amdgcn_mfma_f32_16x16x32_bf16(a1, b[n], acc[3][n], 0, 0, 0);
    }
    __builtin_amdgcn_s_setprio(0);
    __builtin_amdgcn_s_barrier();

    // ---- ph2: dk=1, mi 0-1; stage B1-2 ----
    b[0] = LDB(Bb, 0, 1); b[1] = LDB(Bb, 1, 1); b[2] = LDB(Bb, 2, 1);
    b[3] = LDB(Bb, 3, 1); b[4] = LDB(Bb, 4, 1); b[5] = LDB(Bb, 5, 1);
    a0 = LDA(Ab, 0, 1); a1 = LDA(Ab, 1, 1);
    if (pf) { SU(Bsrc, Bn, 1); SU(Bsrc, Bn, 2); }
    __builtin_amdgcn_s_barrier();
    asm volatile("s_waitcnt lgkmcnt(0)" ::: "memory");
    __builtin_amdgcn_sched_barrier(0);
    __builtin_amdgcn_s_setprio(1);
    #pragma unroll
    for (int n = 0; n < 6; ++n) {
      acc[0][n] = __builtin_amdgcn_mfma_f32_16x16x32_bf16(a0, b[n], acc[0][n], 0, 0, 0);
      acc[1][n] = __builtin_amdgcn_mfma_f32_16x16x32_bf16(a1, b[n], acc[1][n], 0, 0, 0);
    }
    __builtin_amdgcn_s_setprio(0);
    __builtin_amdgcn_s_barrier();

    // ---- ph3: dk=1, mi 2-3 ----
    a0 = LDA(Ab, 2, 1); a1 = LDA(Ab, 3, 1);
    __builtin_amdgcn_s_barrier();
    asm volatile("s_waitcnt lgkmcnt(0)" ::: "memory");
    __builtin_amdgcn_sched_barrier(0);
    __builtin_amdgcn_s_setprio(1);
    #pragma unroll
    for (int n = 0; n < 6; ++n) {
      acc[2][n] = __builtin_amdgcn_mfma_f32_16x16x32_bf16(a0, b[n], acc[2][n], 0, 0, 0);
      acc[3][n] = __builtin_amdgcn_mfma_f32_16x16x32_bf16(a1, b[n], acc[3][n], 0, 0, 0);
    }
    __builtin_amdgcn_s_setprio(0);
    asm volatile("s_waitcnt vmcnt(0)" ::: "memory");
    __builtin_amdgcn_s_barrier();
  }

  if (MODE == 0) {
    float* outp = (float*)Cv;
    #pragma unroll
    for (int mi = 0; mi < 4; ++mi)
      #pragma unroll
      for (int n = 0; n < 6; ++n)
        #pragma unroll
        for (int rr = 0; rr < 4; ++rr) {
          const size_t idx = (size_t)(row0 + wm + mi * 16 + g * 4 + rr) * (size_t)N
                           + (col0 + wn + n * 16 + r);
          outp[idx] = acc[mi][n][rr];
        }
  } else {
    unsigned short* outp = (unsigned short*)Cv;
    const int hc0 = col0 + wn;               // head-aligned (multiple of 96)
    if (hc0 < 3840) {                        // Q or K head: fused RoPE
      #pragma unroll
      for (int mi = 0; mi < 4; ++mi)
        #pragma unroll
        for (int rr = 0; rr < 4; ++rr) {
          const int row = row0 + wm + mi * 16 + g * 4 + rr;
          const int cb = row * 96;
          const size_t rb = (size_t)row * N + hc0;
          #pragma unroll
          for (int n = 0; n < 3; ++n) {
            const int d = n * 16 + r;
            const float x1 = acc[mi][n][rr], x2 = acc[mi][n + 3][rr];
            const float c1 = cs[cb + d], s1 = sn[cb + d];
            const float c2 = cs[cb + d + 48], s2 = sn[cb + d + 48];
            outp[rb + d]      = f2bf(x1 * c1 - x2 * s1);
            outp[rb + d + 48] = f2bf(x2 * c2 + x1 * s2);
          }
        }
    } else if (vtp) {                        // V head: transposed write to vt
      const int kvh = (hc0 - 3840) / 96;
      #pragma unroll
      for (int mi = 0; mi < 4; ++mi) {
        const int rowg = row0 + wm + mi * 16 + g * 4;   // 4 consecutive s
        const int bb = rowg >> 11, s = rowg & 2047;
        #pragma unroll
        for (int n = 0; n < 6; ++n) {
          const int dd = n * 16 + r;
          u16x4 w;
          #pragma unroll
          for (int rr = 0; rr < 4; ++rr) w[rr] = f2bf(acc[mi][n][rr]);
          *(u16x4*)&vtp[((size_t)(bb * 8 + kvh) * 96 + dd) * 2048 + s] = w;
        }
      }
    } else {                                 // V head: plain bf16 to qkv
      #pragma unroll
      for (int mi = 0; mi < 4; ++mi)
        #pragma unroll
        for (int n = 0; n < 6; ++n)
          #pragma unroll
          for (int rr = 0; rr < 4; ++rr) {
            const size_t idx = (size_t)(row0 + wm + mi * 16 + g * 4 + rr) * (size_t)N
                             + (col0 + wn + n * 16 + r);
            outp[idx] = f2bf(acc[mi][n][rr]);
          }
    }
  }
}

// ---------------- V transpose: qkv[b,s,3840+kvh*96+d] -> vt[b,kvh,d,s] ----------------
__global__ __launch_bounds__(256) void vtrans(const unsigned short* __restrict__ qkv,
                                              unsigned short* __restrict__ vt) {
  __shared__ __align__(16) unsigned short T[64 * 104];
  const int s0 = blockIdx.x * 64;
  const int kvh = blockIdx.y, b = blockIdx.z;
  const int tid = threadIdx.x;
  #pragma unroll
  for (int it = 0; it < 3; ++it) {
    const int c = it * 256 + tid;
    const int sr = c / 12, d0 = (c % 12) * 8;
    *(u32x4*)&T[sr * 104 + d0] =
        *(const u32x4*)&qkv[(size_t)(b * 2048 + s0 + sr) * 4608 + 3840 + kvh * 96 + d0];
  }
  __syncthreads();
  #pragma unroll
  for (int it = 0; it < 3; ++it) {
    const int c = it * 256 + tid;
    const int dr = c >> 3, k0 = (c & 7) * 8;
    u16x8 o;
    #pragma unroll
    for (int j = 0; j < 8; ++j) o[j] = T[(k0 + j) * 104 + dr];
    *(u16x8*)&vt[((size_t)(b * 8 + kvh) * 96 + dr) * 2048 + s0 + k0] = o;
  }
}

// ---------------- Flash attention, causal GQA, swapped QK^T (r12 exact) ----------------
__global__ __launch_bounds__(512) void attn_fwd(const unsigned short* __restrict__ qkv,
                                                const unsigned short* __restrict__ vt,
                                                unsigned short* __restrict__ ctx) {
  __shared__ __align__(16) unsigned short SMEM[40960];  // 80 KB
  const int wg = blockIdx.x;             // 0..255
  const int xcd = wg & 7, j = wg >> 3;   // j 0..31
  const int c = xcd + ((j >> 4) << 3);   // (b,kvh) id, 0..15
  const int b = c >> 3, kvh = c & 7;
  const int rj = j & 15;
  const int h = kvh * 4 + (rj >> 2);
  const int pr = rj & 3;                 // fold pair: qt in {7-pr, pr}
  const int tid = threadIdx.x;
  const int wave = tid >> 6, lane = tid & 63;
  const int g = lane >> 4, r = lane & 15;
  const float kLS = 0.14724445f;         // (1/sqrt(96)) * log2(e)

  const unsigned short* kgbase = qkv + (size_t)(b * 2048) * 4608 + 3072 + kvh * 96;
  const unsigned short* vgbase = vt + (size_t)(b * 8 + kvh) * 96 * 2048;

  auto STAGE = [&](int t, int bi) {
    const int kv0 = t * 64;
    unsigned short* kd = SMEM + bi * 6144;
    unsigned short* vd = SMEM + 12288 + bi * 6144;
    #pragma unroll
    for (int i = 0; i < 3; ++i) {
      const int l = i * 512 + tid;
      if (l < 768) {  // K: [dk][row][c], src chunk c^((row>>1)&3)
        const int dk = l >> 8, rem = l & 255;
        const int row = rem >> 2, cc = rem & 3;
        const int csrc = cc ^ ((row >> 1) & 3);
        gload_lds16(kgbase + (size_t)(kv0 + row) * 4608 + dk * 32 + csrc * 8, kd + l * 8);
      } else {        // V: [row][c], src chunk c^(row&7)
        const int lv = l - 768;
        const int row = lv >> 3, cc = lv & 7;
        const int csrc = cc ^ (row & 7);
        gload_lds16(vgbase + (size_t)row * 2048 + kv0 + csrc * 8, vd + lv * 8);
      }
    }
  };

  #pragma unroll 1
  for (int sel = 0; sel < 2; ++sel) {
    const int qt = sel ? pr : 7 - pr;
    const int nt = qt * 4 + 4;
    const int q0 = qt * 256 + wave * 32;

    __syncthreads();   // protect LDS (prev epilogue reads) before re-staging

    bf16x8 qf[2][3];
    #pragma unroll
    for (int qb = 0; qb < 2; ++qb)
      #pragma unroll
      for (int dk = 0; dk < 3; ++dk)
        qf[qb][dk] = ld_frag(&qkv[(size_t)(b * 2048 + q0 + qb * 16 + r) * 4608 + h * 96 + dk * 32 + g * 8]);

    f32x4 o[6][2] = {};
    float m_[2] = {-1e30f, -1e30f};
    float l_[2] = {0.f, 0.f};

    STAGE(0, 0);
    __syncthreads();

    for (int t = 0; t < nt; ++t) {
      const int cur = t & 1;
      if (t + 1 < nt) STAGE(t + 1, cur ^ 1);
      const int kv0 = t * 64;
      const unsigned short* Ks = SMEM + cur * 6144;
      const unsigned short* Vs = SMEM + 12288 + cur * 6144;
      unsigned short* Ps = SMEM + 24576 + wave * 2048;

      if (kv0 <= q0 + 31) {  // wave has at least one unmasked element
        f32x4 st[4][2] = {};
        #pragma unroll
        for (int dk = 0; dk < 3; ++dk) {
          bf16x8 af[4];
          #pragma unroll
          for (int kb = 0; kb < 4; ++kb)
            af[kb] = ld_frag(&Ks[dk * 2048 + (kb * 16 + r) * 32 + ((g ^ ((r >> 1) & 3)) * 8)]);
          __builtin_amdgcn_s_setprio(1);
          #pragma unroll
          for (int kb = 0; kb < 4; ++kb)
            #pragma unroll
            for (int qb = 0; qb < 2; ++qb)
              st[kb][qb] = __builtin_amdgcn_mfma_f32_16x16x32_bf16(af[kb], qf[qb][dk], st[kb][qb], 0, 0, 0);
          __builtin_amdgcn_s_setprio(0);
        }
        // scale (exp2 domain) + causal mask (k_abs <= q_abs)
        if (kv0 + 63 > q0) {
          #pragma unroll
          for (int kb = 0; kb < 4; ++kb)
            #pragma unroll
            for (int qb = 0; qb < 2; ++qb)
              #pragma unroll
              for (int rr = 0; rr < 4; ++rr) {
                const int ka = kv0 + kb * 16 + g * 4 + rr;
                const int qa = q0 + qb * 16 + r;
                const float s = st[kb][qb][rr] * kLS;
                st[kb][qb][rr] = (ka <= qa) ? s : -1e30f;
              }
        } else {
          #pragma unroll
          for (int kb = 0; kb < 4; ++kb)
            #pragma unroll
            for (int qb = 0; qb < 2; ++qb)
              #pragma unroll
              for (int rr = 0; rr < 4; ++rr)
                st[kb][qb][rr] *= kLS;
        }
        // online softmax (exp2 domain), per lane = its q column; T13 exact defer
        #pragma unroll
        for (int qb = 0; qb < 2; ++qb) {
          float mx = st[0][qb][0];
          #pragma unroll
          for (int kb = 0; kb < 4; ++kb)
            #pragma unroll
            for (int rr = 0; rr < 4; ++rr) mx = fmaxf(mx, st[kb][qb][rr]);
          mx = fmaxf(mx, __shfl_xor(mx, 16));
          mx = fmaxf(mx, __shfl_xor(mx, 32));
          if (__all(mx <= m_[qb])) {
            float rs = 0.f;
            #pragma unroll
            for (int kb = 0; kb < 4; ++kb)
              #pragma unroll
              for (int rr = 0; rr < 4; ++rr) {
                const float p = __builtin_amdgcn_exp2f(st[kb][qb][rr] - m_[qb]);
                st[kb][qb][rr] = p;
                rs += p;
              }
            rs += __shfl_xor(rs, 16);
            rs += __shfl_xor(rs, 32);
            l_[qb] += rs;
          } else {
            const float mnew = fmaxf(m_[qb], mx);
            const float corr = __builtin_amdgcn_exp2f(m_[qb] - mnew);
            m_[qb] = mnew;
            float rs = 0.f;
            #pragma unroll
            for (int kb = 0; kb < 4; ++kb)
              #pragma unroll
              for (int rr = 0; rr < 4; ++rr) {
                const float p = __builtin_amdgcn_exp2f(st[kb][qb][rr] - mnew);
                st[kb][qb][rr] = p;
                rs += p;
              }
            rs += __shfl_xor(rs, 16);
            rs += __shfl_xor(rs, 32);
            l_[qb] = l_[qb] * corr + rs;
            #pragma unroll
            for (int db = 0; db < 6; ++db) o[db][qb] *= corr;
          }
        }
        // P[q][k] (bf16) to per-wave LDS, swizzled
        #pragma unroll
        for (int kb = 0; kb < 4; ++kb)
          #pragma unroll
          for (int qb = 0; qb < 2; ++qb) {
            u16x4 w;
            #pragma unroll
            for (int rr = 0; rr < 4; ++rr) w[rr] = f2bf(st[kb][qb][rr]);
            const int q = qb * 16 + r;
            *(u16x4*)&Ps[q * 64 + (((2 * kb + (g >> 1)) ^ (r & 7)) << 3) + (g & 1) * 4] = w;
          }
        // O^T += V^T * P^T
        #pragma unroll
        for (int kk = 0; kk < 2; ++kk) {
          bf16x8 pb[2];
          #pragma unroll
          for (int qb = 0; qb < 2; ++qb)
            pb[qb] = ld_frag(&Ps[(qb * 16 + r) * 64 + ((kk * 4 + g) ^ (r & 7)) * 8]);
          __builtin_amdgcn_s_setprio(1);
          #pragma unroll
          for (int db = 0; db < 6; ++db) {
            const bf16x8 va = ld_frag(&Vs[(db * 16 + r) * 64 + ((kk * 4 + g) ^ (r & 7)) * 8]);
            #pragma unroll
            for (int qb = 0; qb < 2; ++qb)
              o[db][qb] = __builtin_amdgcn_mfma_f32_16x16x32_bf16(va, pb[qb], o[db][qb], 0, 0, 0);
          }
          __builtin_amdgcn_s_setprio(0);
        }
      }
      __syncthreads();
    }

    // epilogue: normalize, transpose through LDS (per-wave region), coalesced stores
    const float inv_l[2] = {1.f / l_[0], 1.f / l_[1]};
    unsigned short* obuf = SMEM + wave * 3328;  // 32 x 104 per wave
    #pragma unroll
    for (int db = 0; db < 6; ++db)
      #pragma unroll
      for (int qb = 0; qb < 2; ++qb) {
        u16x4 w;
        #pragma unroll
        for (int rr = 0; rr < 4; ++rr) w[rr] = f2bf(o[db][qb][rr] * inv_l[qb]);
        *(u16x4*)&obuf[(qb * 16 + r) * 104 + db * 16 + g * 4] = w;
      }
    #pragma unroll
    for (int it = 0; it < 6; ++it) {
      const int cc = it * 64 + lane;
      const int qr = cc / 12, d0 = (cc % 12) * 8;
      *(u32x4*)&ctx[(size_t)(b * 2048 + q0 + qr) * 3072 + h * 96 + d0] =
          *(const u32x4*)&obuf[qr * 104 + d0];
    }
  }
}

extern "C" void kernel_launch(void* const* d_in, const int* in_sizes, int n_in,
                              void* d_out, int out_size, void* d_ws, size_t ws_size,
                              hipStream_t stream) {
  const float* hs   = (const float*)d_in[0];
  const float* cosp = (const float*)d_in[1];
  const float* sinp = (const float*)d_in[2];
  const float* wqkv = (const float*)d_in[4];
  const float* wo   = (const float*)d_in[5];
  float* out = (float*)d_out;

  // workspace (bf16 elems): qkv 18,874,368 | hsb 12,582,912 | wqb 14,155,776
  // big_ws : wob fresh after wqb (in-gemm1 tail-fill, no alias).
  // big_ws2: vt fresh after wob (in-gemm1 transposed V write — vt must NOT
  //          alias hsb while gemm1 reads it; r16 lesson). Fallbacks preserve
  //          r18/r12 orderings. ws_size constant across calls -> deterministic.
  unsigned short* qkv = (unsigned short*)d_ws;
  unsigned short* hsb = qkv + 18874368;
  unsigned short* wqb = hsb + 12582912;
  unsigned short* ctx = wqb;

  const bool big_ws  = ws_size >= (size_t)110100480;
  const bool big_ws2 = ws_size >= (size_t)116391936;
  unsigned short* wob = big_ws ? (wqb + 14155776) : (hsb + 3145728);
  unsigned short* vt  = big_ws2 ? (wob + 9437184) : hsb;

  cvt2_bf16<<<26112, 256, 0, stream>>>(hs, hsb, 3145728, wqkv, wqb, 3538944);
  if (big_ws) {
    gemm8p<1><<<512, 512, 0, stream>>>(hsb, wqb, (void*)qkv, cosp, sinp, 4096, 4608, 3072,
                                       wo, wob, 2359296, 384, big_ws2 ? vt : nullptr);
  } else {
    gemm8p<1><<<384, 512, 0, stream>>>(hsb, wqb, (void*)qkv, cosp, sinp, 4096, 4608, 3072,
                                       nullptr, nullptr, 0, 384, nullptr);
    cvt_bf16<<<9216, 256, 0, stream>>>(wo, wob, 2359296);
  }
  if (!big_ws2) {
    vtrans<<<dim3(32, 8, 2), 256, 0, stream>>>(qkv, vt);
  }
  attn_fwd<<<256, 512, 0, stream>>>(qkv, vt, ctx);
  gemm8p<0><<<256, 512, 0, stream>>>(ctx, wob, (void*)out, cosp, sinp, 4096, 3072, 3072,
                                     nullptr, nullptr, 0, 256, nullptr);
}

// Round 20
// 325.872 us; speedup vs baseline: 1.7793x; 1.0083x over previous
//
#include <hip/hip_runtime.h>

typedef __attribute__((ext_vector_type(8))) __bf16 bf16x8;
typedef __attribute__((ext_vector_type(4))) float f32x4;
typedef __attribute__((ext_vector_type(4))) unsigned int u32x4;
typedef __attribute__((ext_vector_type(4))) unsigned short u16x4;
typedef __attribute__((ext_vector_type(8))) unsigned short u16x8;

__device__ __forceinline__ unsigned short f2bf(float x) {
  unsigned u = __builtin_bit_cast(unsigned, x);
  u += 0x7fffu + ((u >> 16) & 1u);
  return (unsigned short)(u >> 16);
}
__device__ __forceinline__ float bf2f(unsigned short h) {
  unsigned u = ((unsigned)h) << 16;
  return __builtin_bit_cast(float, u);
}
__device__ __forceinline__ bf16x8 ld_frag(const unsigned short* p) {
  u32x4 u = *(const u32x4*)p;
  return __builtin_bit_cast(bf16x8, u);
}
__device__ __forceinline__ void gload_lds16(const unsigned short* g, unsigned short* l) {
  __builtin_amdgcn_global_load_lds(
      (const __attribute__((address_space(1))) void*)g,
      (__attribute__((address_space(3))) void*)l, 16, 0, 0);
}

// ---------------- f32 -> bf16 conversion (vectorized) ----------------
__global__ __launch_bounds__(256) void cvt_bf16(const float* __restrict__ in,
                                                unsigned short* __restrict__ out, int n4) {
  int i = blockIdx.x * 256 + threadIdx.x;
  if (i >= n4) return;
  f32x4 v = *((const f32x4*)in + i);
  u16x4 o;
  #pragma unroll
  for (int j = 0; j < 4; ++j) o[j] = f2bf(v[j]);
  *((u16x4*)out + i) = o;
}

// ------- merged f32 -> bf16 conversion, 8 elems/thread (32B ld / 16B st) -------
__global__ __launch_bounds__(256) void cvt2_bf16(const float* __restrict__ a,
                                                 unsigned short* __restrict__ oa, int na8,
                                                 const float* __restrict__ b,
                                                 unsigned short* __restrict__ ob, int nb8) {
  const int i = blockIdx.x * 256 + threadIdx.x;
  const float* src;
  unsigned short* dst;
  int k;
  if (i < na8) { src = a; dst = oa; k = i; }
  else {
    k = i - na8;
    if (k >= nb8) return;
    src = b; dst = ob;
  }
  const f32x4 v0 = *((const f32x4*)src + k * 2);
  const f32x4 v1 = *((const f32x4*)src + k * 2 + 1);
  u16x8 o;
  #pragma unroll
  for (int j = 0; j < 4; ++j) { o[j] = f2bf(v0[j]); o[4 + j] = f2bf(v1[j]); }
  *((u16x8*)dst + k) = o;
}

// ---- 8-phase GEMM, 4M x 2N wave map (r18 staging spread + tail-fill) ----
// Blocks >= gemm_blocks run a grid-stride f32->bf16 conversion (fills round-2
// idle CUs). cvt_dst MUST NOT alias A/B/C.
// MODE 0: f32 C (gemm2). MODE 1: bf16 C + fused RoPE on heads < 3840 (gemm1);
// if vtp != nullptr, V heads (>=3840) write TRANSPOSED vt[b,kvh,d,s] directly
// (vtp must not alias A/B) and skip the qkv V-region write.
template <int MODE>
__global__ __launch_bounds__(512, 2) void gemm8p(const unsigned short* __restrict__ A,
                                                 const unsigned short* __restrict__ B,
                                                 void* __restrict__ Cv,
                                                 const float* __restrict__ cs,
                                                 const float* __restrict__ sn,
                                                 int M, int N, int K,
                                                 const float* __restrict__ cvt_src,
                                                 unsigned short* __restrict__ cvt_dst,
                                                 int cvt_n4, int gemm_blocks,
                                                 unsigned short* __restrict__ vtp) {
  __shared__ __align__(16) unsigned short SM[57344];  // 112 KB
  if ((int)blockIdx.x >= gemm_blocks) {
    const int nthr = ((int)gridDim.x - gemm_blocks) * 512;
    for (int i = ((int)blockIdx.x - gemm_blocks) * 512 + (int)threadIdx.x;
         i < cvt_n4; i += nthr) {
      f32x4 v = *((const f32x4*)cvt_src + i);
      u16x4 o;
      #pragma unroll
      for (int j = 0; j < 4; ++j) o[j] = f2bf(v[j]);
      *((u16x4*)cvt_dst + i) = o;
    }
    return;
  }
  const int nwg = gemm_blocks;
  const int swz = (blockIdx.x & 7) * (nwg >> 3) + (blockIdx.x >> 3);
  const int bx = swz & 15, by = swz >> 4;      // M/256 == 16 for both GEMMs
  const int row0 = bx * 256, col0 = by * 192;
  const int tid = threadIdx.x;
  const int wave = tid >> 6, lane = tid & 63;
  const int g = lane >> 4, r = lane & 15;
  const int wm = (wave >> 1) * 64, wn = (wave & 1) * 96;
  const int NT = K >> 6;

  const unsigned short* Agb = A + (size_t)row0 * K;
  const unsigned short* Bgb = B + (size_t)col0 * K;

  f32x4 acc[4][6] = {};

  auto SU = [&](const unsigned short* src, unsigned short* dst, int u) {
    const int pos = u * 512 + tid;
    const int rw = pos >> 3, cc = pos & 7;
    gload_lds16(src + (size_t)rw * K + ((cc ^ (rw & 7)) * 8), dst + pos * 8);
  };
  auto LDA = [&](const unsigned short* base, int mi, int dk) {
    const int rw = wm + mi * 16 + r;
    return ld_frag(base + rw * 64 + (((dk * 4 + g) ^ (r & 7)) * 8));
  };
  auto LDB = [&](const unsigned short* base, int ni, int dk) {
    const int rw = wn + ni * 16 + r;
    return ld_frag(base + rw * 64 + (((dk * 4 + g) ^ (r & 7)) * 8));
  };

  SU(Agb, SM, 0); SU(Agb, SM, 1); SU(Agb, SM, 2); SU(Agb, SM, 3);
  SU(Bgb, SM + 16384, 0); SU(Bgb, SM + 16384, 1); SU(Bgb, SM + 16384, 2);
  __syncthreads();

  for (int t = 0; t < NT; ++t) {
    const int d = t & 1;
    const unsigned short* Ab = SM + d * 28672;
    const unsigned short* Bb = Ab + 16384;
    unsigned short* An = SM + (d ^ 1) * 28672;
    unsigned short* Bn = An + 16384;
    const unsigned short* Asrc = Agb + (t + 1) * 64;
    const unsigned short* Bsrc = Bgb + (t + 1) * 64;
    const bool pf = (t + 1 < NT);

    bf16x8 a0, a1, b[6];

    // ---- ph0: dk=0, mi 0-1 (B dk0 held through ph1); stage A0-2 ----
    b[0] = LDB(Bb, 0, 0); b[1] = LDB(Bb, 1, 0); b[2] = LDB(Bb, 2, 0);
    b[3] = LDB(Bb, 3, 0); b[4] = LDB(Bb, 4, 0); b[5] = LDB(Bb, 5, 0);
    a0 = LDA(Ab, 0, 0); a1 = LDA(Ab, 1, 0);
    if (pf) { SU(Asrc, An, 0); SU(Asrc, An, 1); SU(Asrc, An, 2); }
    __builtin_amdgcn_s_barrier();
    asm volatile("s_waitcnt lgkmcnt(0)" ::: "memory");
    __builtin_amdgcn_sched_barrier(0);
    __builtin_amdgcn_s_setprio(1);
    #pragma unroll
    for (int n = 0; n < 6; ++n) {
      acc[0][n] = __builtin_amdgcn_mfma_f32_16x16x32_bf16(a0, b[n], acc[0][n], 0, 0, 0);
      acc[1][n] = __builtin_amdgcn_mfma_f32_16x16x32_bf16(a1, b[n], acc[1][n], 0, 0, 0);
    }
    __builtin_amdgcn_s_setprio(0);
    __builtin_amdgcn_s_barrier();

    // ---- ph1: dk=0, mi 2-3; stage A3 + B0 ----
    a0 = LDA(Ab, 2, 0); a1 = LDA(Ab, 3, 0);
    if (pf) { SU(Asrc, An, 3); SU(Bsrc, Bn, 0); }
    __builtin_amdgcn_s_barrier();
    asm volatile("s_waitcnt lgkmcnt(0)" ::: "memory");
    __builtin_amdgcn_sched_barrier(0);
    __builtin_amdgcn_s_setprio(1);
    #pragma unroll
    for (int n = 0; n < 6; ++n) {
      acc[2][n] = __builtin_amdgcn_mfma_f32_16x16x32_bf16(a0, b[n], acc[2][n], 0, 0, 0);
      acc[3][n] = __builtin_amdgcn_mfma_f32_16x16x32_bf16(a1, b[n], acc[3][n], 0, 0, 0);
    }
    __builtin_amdgcn_s_setprio(0);
    __builtin_amdgcn_s_barrier();

    // ---- ph2: dk=1, mi 0-1; stage B1-2 ----
    b[0] = LDB(Bb, 0, 1); b[1] = LDB(Bb, 1, 1); b[2] = LDB(Bb, 2, 1);
    b[3] = LDB(Bb, 3, 1); b[4] = LDB(Bb, 4, 1); b[5] = LDB(Bb, 5, 1);
    a0 = LDA(Ab, 0, 1); a1 = LDA(Ab, 1, 1);
    if (pf) { SU(Bsrc, Bn, 1); SU(Bsrc, Bn, 2); }
    __builtin_amdgcn_s_barrier();
    asm volatile("s_waitcnt lgkmcnt(0)" ::: "memory");
    __builtin_amdgcn_sched_barrier(0);
    __builtin_amdgcn_s_setprio(1);
    #pragma unroll
    for (int n = 0; n < 6; ++n) {
      acc[0][n] = __builtin_amdgcn_mfma_f32_16x16x32_bf16(a0, b[n], acc[0][n], 0, 0, 0);
      acc[1][n] = __builtin_amdgcn_mfma_f32_16x16x32_bf16(a1, b[n], acc[1][n], 0, 0, 0);
    }
    __builtin_amdgcn_s_setprio(0);
    __builtin_amdgcn_s_barrier();

    // ---- ph3: dk=1, mi 2-3 ----
    a0 = LDA(Ab, 2, 1); a1 = LDA(Ab, 3, 1);
    __builtin_amdgcn_s_barrier();
    asm volatile("s_waitcnt lgkmcnt(0)" ::: "memory");
    __builtin_amdgcn_sched_barrier(0);
    __builtin_amdgcn_s_setprio(1);
    #pragma unroll
    for (int n = 0; n < 6; ++n) {
      acc[2][n] = __builtin_amdgcn_mfma_f32_16x16x32_bf16(a0, b[n], acc[2][n], 0, 0, 0);
      acc[3][n] = __builtin_amdgcn_mfma_f32_16x16x32_bf16(a1, b[n], acc[3][n], 0, 0, 0);
    }
    __builtin_amdgcn_s_setprio(0);
    asm volatile("s_waitcnt vmcnt(0)" ::: "memory");
    __builtin_amdgcn_s_barrier();
  }

  if (MODE == 0) {
    float* outp = (float*)Cv;
    #pragma unroll
    for (int mi = 0; mi < 4; ++mi)
      #pragma unroll
      for (int n = 0; n < 6; ++n)
        #pragma unroll
        for (int rr = 0; rr < 4; ++rr) {
          const size_t idx = (size_t)(row0 + wm + mi * 16 + g * 4 + rr) * (size_t)N
                           + (col0 + wn + n * 16 + r);
          outp[idx] = acc[mi][n][rr];
        }
  } else {
    unsigned short* outp = (unsigned short*)Cv;
    const int hc0 = col0 + wn;               // head-aligned (multiple of 96)
    if (hc0 < 3840) {                        // Q or K head: fused RoPE
      #pragma unroll
      for (int mi = 0; mi < 4; ++mi)
        #pragma unroll
        for (int rr = 0; rr < 4; ++rr) {
          const int row = row0 + wm + mi * 16 + g * 4 + rr;
          const int cb = row * 96;
          const size_t rb = (size_t)row * N + hc0;
          #pragma unroll
          for (int n = 0; n < 3; ++n) {
            const int d = n * 16 + r;
            const float x1 = acc[mi][n][rr], x2 = acc[mi][n + 3][rr];
            const float c1 = cs[cb + d], s1 = sn[cb + d];
            const float c2 = cs[cb + d + 48], s2 = sn[cb + d + 48];
            outp[rb + d]      = f2bf(x1 * c1 - x2 * s1);
            outp[rb + d + 48] = f2bf(x2 * c2 + x1 * s2);
          }
        }
    } else if (vtp) {                        // V head: transposed write to vt
      const int kvh = (hc0 - 3840) / 96;
      #pragma unroll
      for (int mi = 0; mi < 4; ++mi) {
        const int rowg = row0 + wm + mi * 16 + g * 4;   // 4 consecutive s
        const int bb = rowg >> 11, s = rowg & 2047;
        #pragma unroll
        for (int n = 0; n < 6; ++n) {
          const int dd = n * 16 + r;
          u16x4 w;
          #pragma unroll
          for (int rr = 0; rr < 4; ++rr) w[rr] = f2bf(acc[mi][n][rr]);
          *(u16x4*)&vtp[((size_t)(bb * 8 + kvh) * 96 + dd) * 2048 + s] = w;
        }
      }
    } else {                                 // V head: plain bf16 to qkv
      #pragma unroll
      for (int mi = 0; mi < 4; ++mi)
        #pragma unroll
        for (int n = 0; n < 6; ++n)
          #pragma unroll
          for (int rr = 0; rr < 4; ++rr) {
            const size_t idx = (size_t)(row0 + wm + mi * 16 + g * 4 + rr) * (size_t)N
                             + (col0 + wn + n * 16 + r);
            outp[idx] = f2bf(acc[mi][n][rr]);
          }
    }
  }
}

// ---------------- V transpose: qkv[b,s,3840+kvh*96+d] -> vt[b,kvh,d,s] ----------------
__global__ __launch_bounds__(256) void vtrans(const unsigned short* __restrict__ qkv,
                                              unsigned short* __restrict__ vt) {
  __shared__ __align__(16) unsigned short T[64 * 104];
  const int s0 = blockIdx.x * 64;
  const int kvh = blockIdx.y, b = blockIdx.z;
  const int tid = threadIdx.x;
  #pragma unroll
  for (int it = 0; it < 3; ++it) {
    const int c = it * 256 + tid;
    const int sr = c / 12, d0 = (c % 12) * 8;
    *(u32x4*)&T[sr * 104 + d0] =
        *(const u32x4*)&qkv[(size_t)(b * 2048 + s0 + sr) * 4608 + 3840 + kvh * 96 + d0];
  }
  __syncthreads();
  #pragma unroll
  for (int it = 0; it < 3; ++it) {
    const int c = it * 256 + tid;
    const int dr = c >> 3, k0 = (c & 7) * 8;
    u16x8 o;
    #pragma unroll
    for (int j = 0; j < 8; ++j) o[j] = T[(k0 + j) * 104 + dr];
    *(u16x8*)&vt[((size_t)(b * 8 + kvh) * 96 + dr) * 2048 + s0 + k0] = o;
  }
}

// ---------------- Flash attention, causal GQA, swapped QK^T (r12 exact) ----------------
__global__ __launch_bounds__(512) void attn_fwd(const unsigned short* __restrict__ qkv,
                                                const unsigned short* __restrict__ vt,
                                                unsigned short* __restrict__ ctx) {
  __shared__ __align__(16) unsigned short SMEM[40960];  // 80 KB
  const int wg = blockIdx.x;             // 0..255
  const int xcd = wg & 7, j = wg >> 3;   // j 0..31
  const int c = xcd + ((j >> 4) << 3);   // (b,kvh) id, 0..15
  const int b = c >> 3, kvh = c & 7;
  const int rj = j & 15;
  const int h = kvh * 4 + (rj >> 2);
  const int pr = rj & 3;                 // fold pair: qt in {7-pr, pr}
  const int tid = threadIdx.x;
  const int wave = tid >> 6, lane = tid & 63;
  const int g = lane >> 4, r = lane & 15;
  const float kLS = 0.14724445f;         // (1/sqrt(96)) * log2(e)

  const unsigned short* kgbase = qkv + (size_t)(b * 2048) * 4608 + 3072 + kvh * 96;
  const unsigned short* vgbase = vt + (size_t)(b * 8 + kvh) * 96 * 2048;

  auto STAGE = [&](int t, int bi) {
    const int kv0 = t * 64;
    unsigned short* kd = SMEM + bi * 6144;
    unsigned short* vd = SMEM + 12288 + bi * 6144;
    #pragma unroll
    for (int i = 0; i < 3; ++i) {
      const int l = i * 512 + tid;
      if (l < 768) {  // K: [dk][row][c], src chunk c^((row>>1)&3)
        const int dk = l >> 8, rem = l & 255;
        const int row = rem >> 2, cc = rem & 3;
        const int csrc = cc ^ ((row >> 1) & 3);
        gload_lds16(kgbase + (size_t)(kv0 + row) * 4608 + dk * 32 + csrc * 8, kd + l * 8);
      } else {        // V: [row][c], src chunk c^(row&7)
        const int lv = l - 768;
        const int row = lv >> 3, cc = lv & 7;
        const int csrc = cc ^ (row & 7);
        gload_lds16(vgbase + (size_t)row * 2048 + kv0 + csrc * 8, vd + lv * 8);
      }
    }
  };

  #pragma unroll 1
  for (int sel = 0; sel < 2; ++sel) {
    const int qt = sel ? pr : 7 - pr;
    const int nt = qt * 4 + 4;
    const int q0 = qt * 256 + wave * 32;

    __syncthreads();   // protect LDS (prev epilogue reads) before re-staging

    bf16x8 qf[2][3];
    #pragma unroll
    for (int qb = 0; qb < 2; ++qb)
      #pragma unroll
      for (int dk = 0; dk < 3; ++dk)
        qf[qb][dk] = ld_frag(&qkv[(size_t)(b * 2048 + q0 + qb * 16 + r) * 4608 + h * 96 + dk * 32 + g * 8]);

    f32x4 o[6][2] = {};
    float m_[2] = {-1e30f, -1e30f};
    float l_[2] = {0.f, 0.f};

    STAGE(0, 0);
    __syncthreads();

    for (int t = 0; t < nt; ++t) {
      const int cur = t & 1;
      if (t + 1 < nt) STAGE(t + 1, cur ^ 1);
      const int kv0 = t * 64;
      const unsigned short* Ks = SMEM + cur * 6144;
      const unsigned short* Vs = SMEM + 12288 + cur * 6144;
      unsigned short* Ps = SMEM + 24576 + wave * 2048;

      if (kv0 <= q0 + 31) {  // wave has at least one unmasked element
        f32x4 st[4][2] = {};
        #pragma unroll
        for (int dk = 0; dk < 3; ++dk) {
          bf16x8 af[4];
          #pragma unroll
          for (int kb = 0; kb < 4; ++kb)
            af[kb] = ld_frag(&Ks[dk * 2048 + (kb * 16 + r) * 32 + ((g ^ ((r >> 1) & 3)) * 8)]);
          __builtin_amdgcn_s_setprio(1);
          #pragma unroll
          for (int kb = 0; kb < 4; ++kb)
            #pragma unroll
            for (int qb = 0; qb < 2; ++qb)
              st[kb][qb] = __builtin_amdgcn_mfma_f32_16x16x32_bf16(af[kb], qf[qb][dk], st[kb][qb], 0, 0, 0);
          __builtin_amdgcn_s_setprio(0);
        }
        // scale (exp2 domain) + causal mask (k_abs <= q_abs)
        if (kv0 + 63 > q0) {
          #pragma unroll
          for (int kb = 0; kb < 4; ++kb)
            #pragma unroll
            for (int qb = 0; qb < 2; ++qb)
              #pragma unroll
              for (int rr = 0; rr < 4; ++rr) {
                const int ka = kv0 + kb * 16 + g * 4 + rr;
                const int qa = q0 + qb * 16 + r;
                const float s = st[kb][qb][rr] * kLS;
                st[kb][qb][rr] = (ka <= qa) ? s : -1e30f;
              }
        } else {
          #pragma unroll
          for (int kb = 0; kb < 4; ++kb)
            #pragma unroll
            for (int qb = 0; qb < 2; ++qb)
              #pragma unroll
              for (int rr = 0; rr < 4; ++rr)
                st[kb][qb][rr] *= kLS;
        }
        // online softmax (exp2 domain), per lane = its q column; T13 exact defer
        #pragma unroll
        for (int qb = 0; qb < 2; ++qb) {
          float mx = st[0][qb][0];
          #pragma unroll
          for (int kb = 0; kb < 4; ++kb)
            #pragma unroll
            for (int rr = 0; rr < 4; ++rr) mx = fmaxf(mx, st[kb][qb][rr]);
          mx = fmaxf(mx, __shfl_xor(mx, 16));
          mx = fmaxf(mx, __shfl_xor(mx, 32));
          if (__all(mx <= m_[qb])) {
            float rs = 0.f;
            #pragma unroll
            for (int kb = 0; kb < 4; ++kb)
              #pragma unroll
              for (int rr = 0; rr < 4; ++rr) {
                const float p = __builtin_amdgcn_exp2f(st[kb][qb][rr] - m_[qb]);
                st[kb][qb][rr] = p;
                rs += p;
              }
            rs += __shfl_xor(rs, 16);
            rs += __shfl_xor(rs, 32);
            l_[qb] += rs;
          } else {
            const float mnew = fmaxf(m_[qb], mx);
            const float corr = __builtin_amdgcn_exp2f(m_[qb] - mnew);
            m_[qb] = mnew;
            float rs = 0.f;
            #pragma unroll
            for (int kb = 0; kb < 4; ++kb)
              #pragma unroll
              for (int rr = 0; rr < 4; ++rr) {
                const float p = __builtin_amdgcn_exp2f(st[kb][qb][rr] - mnew);
                st[kb][qb][rr] = p;
                rs += p;
              }
            rs += __shfl_xor(rs, 16);
            rs += __shfl_xor(rs, 32);
            l_[qb] = l_[qb] * corr + rs;
            #pragma unroll
            for (int db = 0; db < 6; ++db) o[db][qb] *= corr;
          }
        }
        // P[q][k] (bf16) to per-wave LDS, swizzled
        #pragma unroll
        for (int kb = 0; kb < 4; ++kb)
          #pragma unroll
          for (int qb = 0; qb < 2; ++qb) {
            u16x4 w;
            #pragma unroll
            for (int rr = 0; rr < 4; ++rr) w[rr] = f2bf(st[kb][qb][rr]);
            const int q = qb * 16 + r;
            *(u16x4*)&Ps[q * 64 + (((2 * kb + (g >> 1)) ^ (r & 7)) << 3) + (g & 1) * 4] = w;
          }
        // O^T += V^T * P^T
        #pragma unroll
        for (int kk = 0; kk < 2; ++kk) {
          bf16x8 pb[2];
          #pragma unroll
          for (int qb = 0; qb < 2; ++qb)
            pb[qb] = ld_frag(&Ps[(qb * 16 + r) * 64 + ((kk * 4 + g) ^ (r & 7)) * 8]);
          __builtin_amdgcn_s_setprio(1);
          #pragma unroll
          for (int db = 0; db < 6; ++db) {
            const bf16x8 va = ld_frag(&Vs[(db * 16 + r) * 64 + ((kk * 4 + g) ^ (r & 7)) * 8]);
            #pragma unroll
            for (int qb = 0; qb < 2; ++qb)
              o[db][qb] = __builtin_amdgcn_mfma_f32_16x16x32_bf16(va, pb[qb], o[db][qb], 0, 0, 0);
          }
          __builtin_amdgcn_s_setprio(0);
        }
      }
      __syncthreads();
    }

    // epilogue: normalize, transpose through LDS (per-wave region), coalesced stores
    const float inv_l[2] = {1.f / l_[0], 1.f / l_[1]};
    unsigned short* obuf = SMEM + wave * 3328;  // 32 x 104 per wave
    #pragma unroll
    for (int db = 0; db < 6; ++db)
      #pragma unroll
      for (int qb = 0; qb < 2; ++qb) {
        u16x4 w;
        #pragma unroll
        for (int rr = 0; rr < 4; ++rr) w[rr] = f2bf(o[db][qb][rr] * inv_l[qb]);
        *(u16x4*)&obuf[(qb * 16 + r) * 104 + db * 16 + g * 4] = w;
      }
    #pragma unroll
    for (int it = 0; it < 6; ++it) {
      const int cc = it * 64 + lane;
      const int qr = cc / 12, d0 = (cc % 12) * 8;
      *(u32x4*)&ctx[(size_t)(b * 2048 + q0 + qr) * 3072 + h * 96 + d0] =
          *(const u32x4*)&obuf[qr * 104 + d0];
    }
  }
}

extern "C" void kernel_launch(void* const* d_in, const int* in_sizes, int n_in,
                              void* d_out, int out_size, void* d_ws, size_t ws_size,
                              hipStream_t stream) {
  const float* hs   = (const float*)d_in[0];
  const float* cosp = (const float*)d_in[1];
  const float* sinp = (const float*)d_in[2];
  const float* wqkv = (const float*)d_in[4];
  const float* wo   = (const float*)d_in[5];
  float* out = (float*)d_out;

  // workspace (bf16 elems): qkv 18,874,368 | hsb 12,582,912 | wqb 14,155,776
  // big_ws : wob fresh after wqb (in-gemm1 tail-fill, no alias).
  // big_ws2: vt fresh after wob (in-gemm1 transposed V write — vt must NOT
  //          alias hsb while gemm1 reads it; r16 lesson). Fallbacks preserve
  //          r18/r12 orderings. ws_size constant across calls -> deterministic.
  unsigned short* qkv = (unsigned short*)d_ws;
  unsigned short* hsb = qkv + 18874368;
  unsigned short* wqb = hsb + 12582912;
  unsigned short* ctx = wqb;

  const bool big_ws  = ws_size >= (size_t)110100480;
  const bool big_ws2 = ws_size >= (size_t)116391936;
  unsigned short* wob = big_ws ? (wqb + 14155776) : (hsb + 3145728);
  unsigned short* vt  = big_ws2 ? (wob + 9437184) : hsb;

  // hs: 12,582,912 f32 = 1,572,864 x8; wqkv: 14,155,776 f32 = 1,769,472 x8
  cvt2_bf16<<<13056, 256, 0, stream>>>(hs, hsb, 1572864, wqkv, wqb, 1769472);
  if (big_ws) {
    gemm8p<1><<<512, 512, 0, stream>>>(hsb, wqb, (void*)qkv, cosp, sinp, 4096, 4608, 3072,
                                       wo, wob, 2359296, 384, big_ws2 ? vt : nullptr);
  } else {
    gemm8p<1><<<384, 512, 0, stream>>>(hsb, wqb, (void*)qkv, cosp, sinp, 4096, 4608, 3072,
                                       nullptr, nullptr, 0, 384, nullptr);
    cvt_bf16<<<9216, 256, 0, stream>>>(wo, wob, 2359296);
  }
  if (!big_ws2) {
    vtrans<<<dim3(32, 8, 2), 256, 0, stream>>>(qkv, vt);
  }
  attn_fwd<<<256, 512, 0, stream>>>(qkv, vt, ctx);
  gemm8p<0><<<256, 512, 0, stream>>>(ctx, wob, (void*)out, cosp, sinp, 4096, 3072, 3072,
                                     nullptr, nullptr, 0, 256, nullptr);
}

// Round 21
// 322.702 us; speedup vs baseline: 1.7968x; 1.0098x over previous
//
#include <hip/hip_runtime.h>

typedef __attribute__((ext_vector_type(8))) __bf16 bf16x8;
typedef __attribute__((ext_vector_type(4))) float f32x4;
typedef __attribute__((ext_vector_type(4))) unsigned int u32x4;
typedef __attribute__((ext_vector_type(4))) unsigned short u16x4;
typedef __attribute__((ext_vector_type(8))) unsigned short u16x8;

__device__ __forceinline__ unsigned short f2bf(float x) {
  unsigned u = __builtin_bit_cast(unsigned, x);
  u += 0x7fffu + ((u >> 16) & 1u);
  return (unsigned short)(u >> 16);
}
__device__ __forceinline__ float bf2f(unsigned short h) {
  unsigned u = ((unsigned)h) << 16;
  return __builtin_bit_cast(float, u);
}
__device__ __forceinline__ bf16x8 ld_frag(const unsigned short* p) {
  u32x4 u = *(const u32x4*)p;
  return __builtin_bit_cast(bf16x8, u);
}
__device__ __forceinline__ void gload_lds16(const unsigned short* g, unsigned short* l) {
  __builtin_amdgcn_global_load_lds(
      (const __attribute__((address_space(1))) void*)g,
      (__attribute__((address_space(3))) void*)l, 16, 0, 0);
}

// ---------------- f32 -> bf16 conversion (vectorized) ----------------
__global__ __launch_bounds__(256) void cvt_bf16(const float* __restrict__ in,
                                                unsigned short* __restrict__ out, int n4) {
  int i = blockIdx.x * 256 + threadIdx.x;
  if (i >= n4) return;
  f32x4 v = *((const f32x4*)in + i);
  u16x4 o;
  #pragma unroll
  for (int j = 0; j < 4; ++j) o[j] = f2bf(v[j]);
  *((u16x4*)out + i) = o;
}

// ------- merged f32 -> bf16 conversion, 8 elems/thread (32B ld / 16B st) -------
__global__ __launch_bounds__(256) void cvt2_bf16(const float* __restrict__ a,
                                                 unsigned short* __restrict__ oa, int na8,
                                                 const float* __restrict__ b,
                                                 unsigned short* __restrict__ ob, int nb8) {
  const int i = blockIdx.x * 256 + threadIdx.x;
  const float* src;
  unsigned short* dst;
  int k;
  if (i < na8) { src = a; dst = oa; k = i; }
  else {
    k = i - na8;
    if (k >= nb8) return;
    src = b; dst = ob;
  }
  const f32x4 v0 = *((const f32x4*)src + k * 2);
  const f32x4 v1 = *((const f32x4*)src + k * 2 + 1);
  u16x8 o;
  #pragma unroll
  for (int j = 0; j < 4; ++j) { o[j] = f2bf(v0[j]); o[4 + j] = f2bf(v1[j]); }
  *((u16x8*)dst + k) = o;
}

// ---- 8-phase GEMM, 4M x 2N wave map (r18 staging spread + tail-fill) ----
// Blocks >= gemm_blocks run a grid-stride f32->bf16 conversion (fills round-2
// idle CUs). cvt_dst MUST NOT alias A/B/C.
// MODE 0: f32 C (gemm2). MODE 1: bf16 C + fused RoPE on heads < 3840 (gemm1);
// if vtp != nullptr, V heads (>=3840) write TRANSPOSED vt[b,kvh,d,s] directly
// (vtp must not alias A/B) and skip the qkv V-region write.
template <int MODE>
__global__ __launch_bounds__(512, 2) void gemm8p(const unsigned short* __restrict__ A,
                                                 const unsigned short* __restrict__ B,
                                                 void* __restrict__ Cv,
                                                 const float* __restrict__ cs,
                                                 const float* __restrict__ sn,
                                                 int M, int N, int K,
                                                 const float* __restrict__ cvt_src,
                                                 unsigned short* __restrict__ cvt_dst,
                                                 int cvt_n4, int gemm_blocks,
                                                 unsigned short* __restrict__ vtp) {
  __shared__ __align__(16) unsigned short SM[57344];  // 112 KB
  if ((int)blockIdx.x >= gemm_blocks) {
    const int nthr = ((int)gridDim.x - gemm_blocks) * 512;
    for (int i = ((int)blockIdx.x - gemm_blocks) * 512 + (int)threadIdx.x;
         i < cvt_n4; i += nthr) {
      f32x4 v = *((const f32x4*)cvt_src + i);
      u16x4 o;
      #pragma unroll
      for (int j = 0; j < 4; ++j) o[j] = f2bf(v[j]);
      *((u16x4*)cvt_dst + i) = o;
    }
    return;
  }
  const int nwg = gemm_blocks;
  const int swz = (blockIdx.x & 7) * (nwg >> 3) + (blockIdx.x >> 3);
  const int bx = swz & 15, by = swz >> 4;      // M/256 == 16 for both GEMMs
  const int row0 = bx * 256, col0 = by * 192;
  const int tid = threadIdx.x;
  const int wave = tid >> 6, lane = tid & 63;
  const int g = lane >> 4, r = lane & 15;
  const int wm = (wave >> 1) * 64, wn = (wave & 1) * 96;
  const int NT = K >> 6;

  const unsigned short* Agb = A + (size_t)row0 * K;
  const unsigned short* Bgb = B + (size_t)col0 * K;

  f32x4 acc[4][6] = {};

  auto SU = [&](const unsigned short* src, unsigned short* dst, int u) {
    const int pos = u * 512 + tid;
    const int rw = pos >> 3, cc = pos & 7;
    gload_lds16(src + (size_t)rw * K + ((cc ^ (rw & 7)) * 8), dst + pos * 8);
  };
  auto LDA = [&](const unsigned short* base, int mi, int dk) {
    const int rw = wm + mi * 16 + r;
    return ld_frag(base + rw * 64 + (((dk * 4 + g) ^ (r & 7)) * 8));
  };
  auto LDB = [&](const unsigned short* base, int ni, int dk) {
    const int rw = wn + ni * 16 + r;
    return ld_frag(base + rw * 64 + (((dk * 4 + g) ^ (r & 7)) * 8));
  };

  SU(Agb, SM, 0); SU(Agb, SM, 1); SU(Agb, SM, 2); SU(Agb, SM, 3);
  SU(Bgb, SM + 16384, 0); SU(Bgb, SM + 16384, 1); SU(Bgb, SM + 16384, 2);
  __syncthreads();

  for (int t = 0; t < NT; ++t) {
    const int d = t & 1;
    const unsigned short* Ab = SM + d * 28672;
    const unsigned short* Bb = Ab + 16384;
    unsigned short* An = SM + (d ^ 1) * 28672;
    unsigned short* Bn = An + 16384;
    const unsigned short* Asrc = Agb + (t + 1) * 64;
    const unsigned short* Bsrc = Bgb + (t + 1) * 64;
    const bool pf = (t + 1 < NT);

    bf16x8 a0, a1, b[6];

    // ---- ph0: dk=0, mi 0-1 (B dk0 held through ph1); stage A0-2 ----
    b[0] = LDB(Bb, 0, 0); b[1] = LDB(Bb, 1, 0); b[2] = LDB(Bb, 2, 0);
    b[3] = LDB(Bb, 3, 0); b[4] = LDB(Bb, 4, 0); b[5] = LDB(Bb, 5, 0);
    a0 = LDA(Ab, 0, 0); a1 = LDA(Ab, 1, 0);
    if (pf) { SU(Asrc, An, 0); SU(Asrc, An, 1); SU(Asrc, An, 2); }
    __builtin_amdgcn_s_barrier();
    asm volatile("s_waitcnt lgkmcnt(0)" ::: "memory");
    __builtin_amdgcn_sched_barrier(0);
    __builtin_amdgcn_s_setprio(1);
    #pragma unroll
    for (int n = 0; n < 6; ++n) {
      acc[0][n] = __builtin_amdgcn_mfma_f32_16x16x32_bf16(a0, b[n], acc[0][n], 0, 0, 0);
      acc[1][n] = __builtin_amdgcn_mfma_f32_16x16x32_bf16(a1, b[n], acc[1][n], 0, 0, 0);
    }
    __builtin_amdgcn_s_setprio(0);
    __builtin_amdgcn_s_barrier();

    // ---- ph1: dk=0, mi 2-3; stage A3 + B0 ----
    a0 = LDA(Ab, 2, 0); a1 = LDA(Ab, 3, 0);
    if (pf) { SU(Asrc, An, 3); SU(Bsrc, Bn, 0); }
    __builtin_amdgcn_s_barrier();
    asm volatile("s_waitcnt lgkmcnt(0)" ::: "memory");
    __builtin_amdgcn_sched_barrier(0);
    __builtin_amdgcn_s_setprio(1);
    #pragma unroll
    for (int n = 0; n < 6; ++n) {
      acc[2][n] = __builtin_amdgcn_mfma_f32_16x16x32_bf16(a0, b[n], acc[2][n], 0, 0, 0);
      acc[3][n] = __builtin_amdgcn_mfma_f32_16x16x32_bf16(a1, b[n], acc[3][n], 0, 0, 0);
    }
    __builtin_amdgcn_s_setprio(0);
    __builtin_amdgcn_s_barrier();

    // ---- ph2: dk=1, mi 0-1; stage B1-2 ----
    b[0] = LDB(Bb, 0, 1); b[1] = LDB(Bb, 1, 1); b[2] = LDB(Bb, 2, 1);
    b[3] = LDB(Bb, 3, 1); b[4] = LDB(Bb, 4, 1); b[5] = LDB(Bb, 5, 1);
    a0 = LDA(Ab, 0, 1); a1 = LDA(Ab, 1, 1);
    if (pf) { SU(Bsrc, Bn, 1); SU(Bsrc, Bn, 2); }
    __builtin_amdgcn_s_barrier();
    asm volatile("s_waitcnt lgkmcnt(0)" ::: "memory");
    __builtin_amdgcn_sched_barrier(0);
    __builtin_amdgcn_s_setprio(1);
    #pragma unroll
    for (int n = 0; n < 6; ++n) {
      acc[0][n] = __builtin_amdgcn_mfma_f32_16x16x32_bf16(a0, b[n], acc[0][n], 0, 0, 0);
      acc[1][n] = __builtin_amdgcn_mfma_f32_16x16x32_bf16(a1, b[n], acc[1][n], 0, 0, 0);
    }
    __builtin_amdgcn_s_setprio(0);
    __builtin_amdgcn_s_barrier();

    // ---- ph3: dk=1, mi 2-3 ----
    a0 = LDA(Ab, 2, 1); a1 = LDA(Ab, 3, 1);
    __builtin_amdgcn_s_barrier();
    asm volatile("s_waitcnt lgkmcnt(0)" ::: "memory");
    __builtin_amdgcn_sched_barrier(0);
    __builtin_amdgcn_s_setprio(1);
    #pragma unroll
    for (int n = 0; n < 6; ++n) {
      acc[2][n] = __builtin_amdgcn_mfma_f32_16x16x32_bf16(a0, b[n], acc[2][n], 0, 0, 0);
      acc[3][n] = __builtin_amdgcn_mfma_f32_16x16x32_bf16(a1, b[n], acc[3][n], 0, 0, 0);
    }
    __builtin_amdgcn_s_setprio(0);
    asm volatile("s_waitcnt vmcnt(0)" ::: "memory");
    __builtin_amdgcn_s_barrier();
  }

  if (MODE == 0) {
    float* outp = (float*)Cv;
    #pragma unroll
    for (int mi = 0; mi < 4; ++mi)
      #pragma unroll
      for (int n = 0; n < 6; ++n)
        #pragma unroll
        for (int rr = 0; rr < 4; ++rr) {
          const size_t idx = (size_t)(row0 + wm + mi * 16 + g * 4 + rr) * (size_t)N
                           + (col0 + wn + n * 16 + r);
          outp[idx] = acc[mi][n][rr];
        }
  } else {
    unsigned short* outp = (unsigned short*)Cv;
    const int hc0 = col0 + wn;               // head-aligned (multiple of 96)
    if (hc0 < 3840) {                        // Q or K head: fused RoPE
      #pragma unroll
      for (int mi = 0; mi < 4; ++mi)
        #pragma unroll
        for (int rr = 0; rr < 4; ++rr) {
          const int row = row0 + wm + mi * 16 + g * 4 + rr;
          const int cb = row * 96;
          const size_t rb = (size_t)row * N + hc0;
          #pragma unroll
          for (int n = 0; n < 3; ++n) {
            const int d = n * 16 + r;
            const float x1 = acc[mi][n][rr], x2 = acc[mi][n + 3][rr];
            const float c1 = cs[cb + d], s1 = sn[cb + d];
            const float c2 = cs[cb + d + 48], s2 = sn[cb + d + 48];
            outp[rb + d]      = f2bf(x1 * c1 - x2 * s1);
            outp[rb + d + 48] = f2bf(x2 * c2 + x1 * s2);
          }
        }
    } else if (vtp) {                        // V head: transposed write to vt
      const int kvh = (hc0 - 3840) / 96;
      #pragma unroll
      for (int mi = 0; mi < 4; ++mi) {
        const int rowg = row0 + wm + mi * 16 + g * 4;   // 4 consecutive s
        const int bb = rowg >> 11, s = rowg & 2047;
        #pragma unroll
        for (int n = 0; n < 6; ++n) {
          const int dd = n * 16 + r;
          u16x4 w;
          #pragma unroll
          for (int rr = 0; rr < 4; ++rr) w[rr] = f2bf(acc[mi][n][rr]);
          *(u16x4*)&vtp[((size_t)(bb * 8 + kvh) * 96 + dd) * 2048 + s] = w;
        }
      }
    } else {                                 // V head: plain bf16 to qkv
      #pragma unroll
      for (int mi = 0; mi < 4; ++mi)
        #pragma unroll
        for (int n = 0; n < 6; ++n)
          #pragma unroll
          for (int rr = 0; rr < 4; ++rr) {
            const size_t idx = (size_t)(row0 + wm + mi * 16 + g * 4 + rr) * (size_t)N
                             + (col0 + wn + n * 16 + r);
            outp[idx] = f2bf(acc[mi][n][rr]);
          }
    }
  }
}

// ---------------- V transpose: qkv[b,s,3840+kvh*96+d] -> vt[b,kvh,d,s] ----------------
__global__ __launch_bounds__(256) void vtrans(const unsigned short* __restrict__ qkv,
                                              unsigned short* __restrict__ vt) {
  __shared__ __align__(16) unsigned short T[64 * 104];
  const int s0 = blockIdx.x * 64;
  const int kvh = blockIdx.y, b = blockIdx.z;
  const int tid = threadIdx.x;
  #pragma unroll
  for (int it = 0; it < 3; ++it) {
    const int c = it * 256 + tid;
    const int sr = c / 12, d0 = (c % 12) * 8;
    *(u32x4*)&T[sr * 104 + d0] =
        *(const u32x4*)&qkv[(size_t)(b * 2048 + s0 + sr) * 4608 + 3840 + kvh * 96 + d0];
  }
  __syncthreads();
  #pragma unroll
  for (int it = 0; it < 3; ++it) {
    const int c = it * 256 + tid;
    const int dr = c >> 3, k0 = (c & 7) * 8;
    u16x8 o;
    #pragma unroll
    for (int j = 0; j < 8; ++j) o[j] = T[(k0 + j) * 104 + dr];
    *(u16x8*)&vt[((size_t)(b * 8 + kvh) * 96 + dr) * 2048 + s0 + k0] = o;
  }
}

// ---------------- Flash attention, causal GQA, swapped QK^T ----------------
// r21: r12 body, but staged KV tile doubled to 128 (grid 256 = 1 block/CU ->
// whole 160KB LDS available; uses 128KB: K dbuf 2x24K + V dbuf 2x24K + Ps 32K).
// Compute runs as two 64-halves per staged tile (identical math); barriers &
// vmcnt-drains per block halve (36 -> 18). K swizzle key (row>>1)&3 invariant
// to +64 offset; V now 16 chunks keyed row&15 (= r at read), same 2-way-free.
__global__ __launch_bounds__(512) void attn_fwd(const unsigned short* __restrict__ qkv,
                                                const unsigned short* __restrict__ vt,
                                                unsigned short* __restrict__ ctx) {
  __shared__ __align__(16) unsigned short SMEM[65536];  // 128 KB
  const int wg = blockIdx.x;             // 0..255
  const int xcd = wg & 7, j = wg >> 3;   // j 0..31
  const int c = xcd + ((j >> 4) << 3);   // (b,kvh) id, 0..15
  const int b = c >> 3, kvh = c & 7;
  const int rj = j & 15;
  const int h = kvh * 4 + (rj >> 2);
  const int pr = rj & 3;                 // fold pair: qt in {7-pr, pr}
  const int tid = threadIdx.x;
  const int wave = tid >> 6, lane = tid & 63;
  const int g = lane >> 4, r = lane & 15;
  const float kLS = 0.14724445f;         // (1/sqrt(96)) * log2(e)

  const unsigned short* kgbase = qkv + (size_t)(b * 2048) * 4608 + 3072 + kvh * 96;
  const unsigned short* vgbase = vt + (size_t)(b * 8 + kvh) * 96 * 2048;

  // STAGE 128-kv tile t into buffer bi: K 1536 + V 1536 chunks, 6 iters x 512
  auto STAGE = [&](int t, int bi) {
    const int kv0 = t * 128;
    unsigned short* kd = SMEM + bi * 12288;
    unsigned short* vd = SMEM + 24576 + bi * 12288;
    #pragma unroll
    for (int i = 0; i < 3; ++i) {   // K: [dk][row 0..127][c 0..3], src c^((row>>1)&3)
      const int l = i * 512 + tid;
      const int dk = l >> 9, rem = l & 511;
      const int row = rem >> 2, cc = rem & 3;
      const int csrc = cc ^ ((row >> 1) & 3);
      gload_lds16(kgbase + (size_t)(kv0 + row) * 4608 + dk * 32 + csrc * 8, kd + l * 8);
    }
    #pragma unroll
    for (int i = 0; i < 3; ++i) {   // V: [d 0..95][c 0..15], src c^(d&15)
      const int l = i * 512 + tid;
      const int row = l >> 4, cc = l & 15;
      const int csrc = cc ^ (row & 15);
      gload_lds16(vgbase + (size_t)row * 2048 + kv0 + csrc * 8, vd + l * 8);
    }
  };

  #pragma unroll 1
  for (int sel = 0; sel < 2; ++sel) {
    const int qt = sel ? pr : 7 - pr;
    const int nt = qt * 2 + 2;           // 128-wide tiles
    const int q0 = qt * 256 + wave * 32;

    __syncthreads();   // protect LDS (prev epilogue reads) before re-staging

    bf16x8 qf[2][3];
    #pragma unroll
    for (int qb = 0; qb < 2; ++qb)
      #pragma unroll
      for (int dk = 0; dk < 3; ++dk)
        qf[qb][dk] = ld_frag(&qkv[(size_t)(b * 2048 + q0 + qb * 16 + r) * 4608 + h * 96 + dk * 32 + g * 8]);

    f32x4 o[6][2] = {};
    float m_[2] = {-1e30f, -1e30f};
    float l_[2] = {0.f, 0.f};

    STAGE(0, 0);
    __syncthreads();

    for (int t = 0; t < nt; ++t) {
      const int cur = t & 1;
      if (t + 1 < nt) STAGE(t + 1, cur ^ 1);
      const unsigned short* Ks = SMEM + cur * 12288;
      const unsigned short* Vs = SMEM + 24576 + cur * 12288;
      unsigned short* Ps = SMEM + 49152 + wave * 2048;

      #pragma unroll
      for (int hh = 0; hh < 2; ++hh) {
        const int kv0 = t * 128 + hh * 64;
        if (kv0 <= q0 + 31) {  // wave has at least one unmasked element
          f32x4 st[4][2] = {};
          #pragma unroll
          for (int dk = 0; dk < 3; ++dk) {
            bf16x8 af[4];
            #pragma unroll
            for (int kb = 0; kb < 4; ++kb)
              af[kb] = ld_frag(&Ks[dk * 4096 + (hh * 64 + kb * 16 + r) * 32 + ((g ^ ((r >> 1) & 3)) * 8)]);
            __builtin_amdgcn_s_setprio(1);
            #pragma unroll
            for (int kb = 0; kb < 4; ++kb)
              #pragma unroll
              for (int qb = 0; qb < 2; ++qb)
                st[kb][qb] = __builtin_amdgcn_mfma_f32_16x16x32_bf16(af[kb], qf[qb][dk], st[kb][qb], 0, 0, 0);
            __builtin_amdgcn_s_setprio(0);
          }
          // scale (exp2 domain) + causal mask (k_abs <= q_abs)
          if (kv0 + 63 > q0) {
            #pragma unroll
            for (int kb = 0; kb < 4; ++kb)
              #pragma unroll
              for (int qb = 0; qb < 2; ++qb)
                #pragma unroll
                for (int rr = 0; rr < 4; ++rr) {
                  const int ka = kv0 + kb * 16 + g * 4 + rr;
                  const int qa = q0 + qb * 16 + r;
                  const float s = st[kb][qb][rr] * kLS;
                  st[kb][qb][rr] = (ka <= qa) ? s : -1e30f;
                }
          } else {
            #pragma unroll
            for (int kb = 0; kb < 4; ++kb)
              #pragma unroll
              for (int qb = 0; qb < 2; ++qb)
                #pragma unroll
                for (int rr = 0; rr < 4; ++rr)
                  st[kb][qb][rr] *= kLS;
          }
          // online softmax (exp2 domain), per lane = its q column; T13 exact defer
          #pragma unroll
          for (int qb = 0; qb < 2; ++qb) {
            float mx = st[0][qb][0];
            #pragma unroll
            for (int kb = 0; kb < 4; ++kb)
              #pragma unroll
              for (int rr = 0; rr < 4; ++rr) mx = fmaxf(mx, st[kb][qb][rr]);
            mx = fmaxf(mx, __shfl_xor(mx, 16));
            mx = fmaxf(mx, __shfl_xor(mx, 32));
            if (__all(mx <= m_[qb])) {
              float rs = 0.f;
              #pragma unroll
              for (int kb = 0; kb < 4; ++kb)
                #pragma unroll
                for (int rr = 0; rr < 4; ++rr) {
                  const float p = __builtin_amdgcn_exp2f(st[kb][qb][rr] - m_[qb]);
                  st[kb][qb][rr] = p;
                  rs += p;
                }
              rs += __shfl_xor(rs, 16);
              rs += __shfl_xor(rs, 32);
              l_[qb] += rs;
            } else {
              const float mnew = fmaxf(m_[qb], mx);
              const float corr = __builtin_amdgcn_exp2f(m_[qb] - mnew);
              m_[qb] = mnew;
              float rs = 0.f;
              #pragma unroll
              for (int kb = 0; kb < 4; ++kb)
                #pragma unroll
                for (int rr = 0; rr < 4; ++rr) {
                  const float p = __builtin_amdgcn_exp2f(st[kb][qb][rr] - mnew);
                  st[kb][qb][rr] = p;
                  rs += p;
                }
              rs += __shfl_xor(rs, 16);
              rs += __shfl_xor(rs, 32);
              l_[qb] = l_[qb] * corr + rs;
              #pragma unroll
              for (int db = 0; db < 6; ++db) o[db][qb] *= corr;
            }
          }
          // P[q][k] (bf16) to per-wave LDS, swizzled (64-wide)
          #pragma unroll
          for (int kb = 0; kb < 4; ++kb)
            #pragma unroll
            for (int qb = 0; qb < 2; ++qb) {
              u16x4 w;
              #pragma unroll
              for (int rr = 0; rr < 4; ++rr) w[rr] = f2bf(st[kb][qb][rr]);
              const int q = qb * 16 + r;
              *(u16x4*)&Ps[q * 64 + (((2 * kb + (g >> 1)) ^ (r & 7)) << 3) + (g & 1) * 4] = w;
            }
          // O^T += V^T * P^T  (V rows 128-wide, chunk (hh*8+kk*4+g)^r)
          #pragma unroll
          for (int kk = 0; kk < 2; ++kk) {
            bf16x8 pb[2];
            #pragma unroll
            for (int qb = 0; qb < 2; ++qb)
              pb[qb] = ld_frag(&Ps[(qb * 16 + r) * 64 + ((kk * 4 + g) ^ (r & 7)) * 8]);
            __builtin_amdgcn_s_setprio(1);
            #pragma unroll
            for (int db = 0; db < 6; ++db) {
              const bf16x8 va = ld_frag(&Vs[(db * 16 + r) * 128 + (((hh * 8 + kk * 4 + g) ^ r) * 8)]);
              #pragma unroll
              for (int qb = 0; qb < 2; ++qb)
                o[db][qb] = __builtin_amdgcn_mfma_f32_16x16x32_bf16(va, pb[qb], o[db][qb], 0, 0, 0);
            }
            __builtin_amdgcn_s_setprio(0);
          }
        }
      }
      __syncthreads();
    }

    // epilogue: normalize, transpose through LDS (per-wave region), coalesced stores
    const float inv_l[2] = {1.f / l_[0], 1.f / l_[1]};
    unsigned short* obuf = SMEM + wave * 3328;  // 32 x 104 per wave
    #pragma unroll
    for (int db = 0; db < 6; ++db)
      #pragma unroll
      for (int qb = 0; qb < 2; ++qb) {
        u16x4 w;
        #pragma unroll
        for (int rr = 0; rr < 4; ++rr) w[rr] = f2bf(o[db][qb][rr] * inv_l[qb]);
        *(u16x4*)&obuf[(qb * 16 + r) * 104 + db * 16 + g * 4] = w;
      }
    #pragma unroll
    for (int it = 0; it < 6; ++it) {
      const int cc = it * 64 + lane;
      const int qr = cc / 12, d0 = (cc % 12) * 8;
      *(u32x4*)&ctx[(size_t)(b * 2048 + q0 - wave * 32 + wave * 32 + qr) * 3072 + h * 96 + d0] =
          *(const u32x4*)&obuf[qr * 104 + d0];
    }
  }
}

extern "C" void kernel_launch(void* const* d_in, const int* in_sizes, int n_in,
                              void* d_out, int out_size, void* d_ws, size_t ws_size,
                              hipStream_t stream) {
  const float* hs   = (const float*)d_in[0];
  const float* cosp = (const float*)d_in[1];
  const float* sinp = (const float*)d_in[2];
  const float* wqkv = (const float*)d_in[4];
  const float* wo   = (const float*)d_in[5];
  float* out = (float*)d_out;

  // workspace (bf16 elems): qkv 18,874,368 | hsb 12,582,912 | wqb 14,155,776
  // big_ws : wob fresh after wqb (in-gemm1 tail-fill, no alias).
  // big_ws2: vt fresh after wob (in-gemm1 transposed V write — vt must NOT
  //          alias hsb while gemm1 reads it; r16 lesson). Fallbacks preserve
  //          r18/r12 orderings. ws_size constant across calls -> deterministic.
  unsigned short* qkv = (unsigned short*)d_ws;
  unsigned short* hsb = qkv + 18874368;
  unsigned short* wqb = hsb + 12582912;
  unsigned short* ctx = wqb;

  const bool big_ws  = ws_size >= (size_t)110100480;
  const bool big_ws2 = ws_size >= (size_t)116391936;
  unsigned short* wob = big_ws ? (wqb + 14155776) : (hsb + 3145728);
  unsigned short* vt  = big_ws2 ? (wob + 9437184) : hsb;

  // hs: 12,582,912 f32 = 1,572,864 x8; wqkv: 14,155,776 f32 = 1,769,472 x8
  cvt2_bf16<<<13056, 256, 0, stream>>>(hs, hsb, 1572864, wqkv, wqb, 1769472);
  if (big_ws) {
    gemm8p<1><<<512, 512, 0, stream>>>(hsb, wqb, (void*)qkv, cosp, sinp, 4096, 4608, 3072,
                                       wo, wob, 2359296, 384, big_ws2 ? vt : nullptr);
  } else {
    gemm8p<1><<<384, 512, 0, stream>>>(hsb, wqb, (void*)qkv, cosp, sinp, 4096, 4608, 3072,
                                       nullptr, nullptr, 0, 384, nullptr);
    cvt_bf16<<<9216, 256, 0, stream>>>(wo, wob, 2359296);
  }
  if (!big_ws2) {
    vtrans<<<dim3(32, 8, 2), 256, 0, stream>>>(qkv, vt);
  }
  attn_fwd<<<256, 512, 0, stream>>>(qkv, vt, ctx);
  gemm8p<0><<<256, 512, 0, stream>>>(ctx, wob, (void*)out, cosp, sinp, 4096, 3072, 3072,
                                     nullptr, nullptr, 0, 256, nullptr);
}

// Round 22
// 322.677 us; speedup vs baseline: 1.7969x; 1.0001x over previous
//
#include <hip/hip_runtime.h>

typedef __attribute__((ext_vector_type(8))) __bf16 bf16x8;
typedef __attribute__((ext_vector_type(4))) float f32x4;
typedef __attribute__((ext_vector_type(4))) unsigned int u32x4;
typedef __attribute__((ext_vector_type(4))) unsigned short u16x4;
typedef __attribute__((ext_vector_type(8))) unsigned short u16x8;

__device__ __forceinline__ unsigned short f2bf(float x) {
  unsigned u = __builtin_bit_cast(unsigned, x);
  u += 0x7fffu + ((u >> 16) & 1u);
  return (unsigned short)(u >> 16);
}
__device__ __forceinline__ float bf2f(unsigned short h) {
  unsigned u = ((unsigned)h) << 16;
  return __builtin_bit_cast(float, u);
}
__device__ __forceinline__ bf16x8 ld_frag(const unsigned short* p) {
  u32x4 u = *(const u32x4*)p;
  return __builtin_bit_cast(bf16x8, u);
}
__device__ __forceinline__ void gload_lds16(const unsigned short* g, unsigned short* l) {
  __builtin_amdgcn_global_load_lds(
      (const __attribute__((address_space(1))) void*)g,
      (__attribute__((address_space(3))) void*)l, 16, 0, 0);
}

// ---------------- f32 -> bf16 conversion (vectorized) ----------------
__global__ __launch_bounds__(256) void cvt_bf16(const float* __restrict__ in,
                                                unsigned short* __restrict__ out, int n4) {
  int i = blockIdx.x * 256 + threadIdx.x;
  if (i >= n4) return;
  f32x4 v = *((const f32x4*)in + i);
  u16x4 o;
  #pragma unroll
  for (int j = 0; j < 4; ++j) o[j] = f2bf(v[j]);
  *((u16x4*)out + i) = o;
}

// ------- merged f32 -> bf16 conversion, 8 elems/thread (32B ld / 16B st) -------
__global__ __launch_bounds__(256) void cvt2_bf16(const float* __restrict__ a,
                                                 unsigned short* __restrict__ oa, int na8,
                                                 const float* __restrict__ b,
                                                 unsigned short* __restrict__ ob, int nb8) {
  const int i = blockIdx.x * 256 + threadIdx.x;
  const float* src;
  unsigned short* dst;
  int k;
  if (i < na8) { src = a; dst = oa; k = i; }
  else {
    k = i - na8;
    if (k >= nb8) return;
    src = b; dst = ob;
  }
  const f32x4 v0 = *((const f32x4*)src + k * 2);
  const f32x4 v1 = *((const f32x4*)src + k * 2 + 1);
  u16x8 o;
  #pragma unroll
  for (int j = 0; j < 4; ++j) { o[j] = f2bf(v0[j]); o[4 + j] = f2bf(v1[j]); }
  *((u16x8*)dst + k) = o;
}

// ---- 8-phase GEMM, 4M x 2N wave map (r18 staging spread + tail-fill) ----
// Blocks >= gemm_blocks run a grid-stride f32->bf16 conversion (fills round-2
// idle CUs). cvt_dst MUST NOT alias A/B/C.
// MODE 0: f32 C (gemm2). MODE 1: bf16 C + fused RoPE on heads < 3840 (gemm1);
// if vtp != nullptr, V heads (>=3840) write TRANSPOSED vt[b,kvh,d,s] directly
// (vtp must not alias A/B) and skip the qkv V-region write.
template <int MODE>
__global__ __launch_bounds__(512, 2) void gemm8p(const unsigned short* __restrict__ A,
                                                 const unsigned short* __restrict__ B,
                                                 void* __restrict__ Cv,
                                                 const float* __restrict__ cs,
                                                 const float* __restrict__ sn,
                                                 int M, int N, int K,
                                                 const float* __restrict__ cvt_src,
                                                 unsigned short* __restrict__ cvt_dst,
                                                 int cvt_n4, int gemm_blocks,
                                                 unsigned short* __restrict__ vtp) {
  __shared__ __align__(16) unsigned short SM[57344];  // 112 KB
  if ((int)blockIdx.x >= gemm_blocks) {
    const int nthr = ((int)gridDim.x - gemm_blocks) * 512;
    for (int i = ((int)blockIdx.x - gemm_blocks) * 512 + (int)threadIdx.x;
         i < cvt_n4; i += nthr) {
      f32x4 v = *((const f32x4*)cvt_src + i);
      u16x4 o;
      #pragma unroll
      for (int j = 0; j < 4; ++j) o[j] = f2bf(v[j]);
      *((u16x4*)cvt_dst + i) = o;
    }
    return;
  }
  const int nwg = gemm_blocks;
  const int swz = (blockIdx.x & 7) * (nwg >> 3) + (blockIdx.x >> 3);
  const int bx = swz & 15, by = swz >> 4;      // M/256 == 16 for both GEMMs
  const int row0 = bx * 256, col0 = by * 192;
  const int tid = threadIdx.x;
  const int wave = tid >> 6, lane = tid & 63;
  const int g = lane >> 4, r = lane & 15;
  const int wm = (wave >> 1) * 64, wn = (wave & 1) * 96;
  const int NT = K >> 6;

  const unsigned short* Agb = A + (size_t)row0 * K;
  const unsigned short* Bgb = B + (size_t)col0 * K;

  f32x4 acc[4][6] = {};

  auto SU = [&](const unsigned short* src, unsigned short* dst, int u) {
    const int pos = u * 512 + tid;
    const int rw = pos >> 3, cc = pos & 7;
    gload_lds16(src + (size_t)rw * K + ((cc ^ (rw & 7)) * 8), dst + pos * 8);
  };
  auto LDA = [&](const unsigned short* base, int mi, int dk) {
    const int rw = wm + mi * 16 + r;
    return ld_frag(base + rw * 64 + (((dk * 4 + g) ^ (r & 7)) * 8));
  };
  auto LDB = [&](const unsigned short* base, int ni, int dk) {
    const int rw = wn + ni * 16 + r;
    return ld_frag(base + rw * 64 + (((dk * 4 + g) ^ (r & 7)) * 8));
  };

  SU(Agb, SM, 0); SU(Agb, SM, 1); SU(Agb, SM, 2); SU(Agb, SM, 3);
  SU(Bgb, SM + 16384, 0); SU(Bgb, SM + 16384, 1); SU(Bgb, SM + 16384, 2);
  __syncthreads();

  for (int t = 0; t < NT; ++t) {
    const int d = t & 1;
    const unsigned short* Ab = SM + d * 28672;
    const unsigned short* Bb = Ab + 16384;
    unsigned short* An = SM + (d ^ 1) * 28672;
    unsigned short* Bn = An + 16384;
    const unsigned short* Asrc = Agb + (t + 1) * 64;
    const unsigned short* Bsrc = Bgb + (t + 1) * 64;
    const bool pf = (t + 1 < NT);

    bf16x8 a0, a1, b[6];

    // ---- ph0: dk=0, mi 0-1 (B dk0 held through ph1); stage A0-2 ----
    b[0] = LDB(Bb, 0, 0); b[1] = LDB(Bb, 1, 0); b[2] = LDB(Bb, 2, 0);
    b[3] = LDB(Bb, 3, 0); b[4] = LDB(Bb, 4, 0); b[5] = LDB(Bb, 5, 0);
    a0 = LDA(Ab, 0, 0); a1 = LDA(Ab, 1, 0);
    if (pf) { SU(Asrc, An, 0); SU(Asrc, An, 1); SU(Asrc, An, 2); }
    __builtin_amdgcn_s_barrier();
    asm volatile("s_waitcnt lgkmcnt(0)" ::: "memory");
    __builtin_amdgcn_sched_barrier(0);
    __builtin_amdgcn_s_setprio(1);
    #pragma unroll
    for (int n = 0; n < 6; ++n) {
      acc[0][n] = __builtin_amdgcn_mfma_f32_16x16x32_bf16(a0, b[n], acc[0][n], 0, 0, 0);
      acc[1][n] = __builtin_amdgcn_mfma_f32_16x16x32_bf16(a1, b[n], acc[1][n], 0, 0, 0);
    }
    __builtin_amdgcn_s_setprio(0);
    __builtin_amdgcn_s_barrier();

    // ---- ph1: dk=0, mi 2-3; stage A3 + B0 ----
    a0 = LDA(Ab, 2, 0); a1 = LDA(Ab, 3, 0);
    if (pf) { SU(Asrc, An, 3); SU(Bsrc, Bn, 0); }
    __builtin_amdgcn_s_barrier();
    asm volatile("s_waitcnt lgkmcnt(0)" ::: "memory");
    __builtin_amdgcn_sched_barrier(0);
    __builtin_amdgcn_s_setprio(1);
    #pragma unroll
    for (int n = 0; n < 6; ++n) {
      acc[2][n] = __builtin_amdgcn_mfma_f32_16x16x32_bf16(a0, b[n], acc[2][n], 0, 0, 0);
      acc[3][n] = __builtin_amdgcn_mfma_f32_16x16x32_bf16(a1, b[n], acc[3][n], 0, 0, 0);
    }
    __builtin_amdgcn_s_setprio(0);
    __builtin_amdgcn_s_barrier();

    // ---- ph2: dk=1, mi 0-1; stage B1-2 ----
    b[0] = LDB(Bb, 0, 1); b[1] = LDB(Bb, 1, 1); b[2] = LDB(Bb, 2, 1);
    b[3] = LDB(Bb, 3, 1); b[4] = LDB(Bb, 4, 1); b[5] = LDB(Bb, 5, 1);
    a0 = LDA(Ab, 0, 1); a1 = LDA(Ab, 1, 1);
    if (pf) { SU(Bsrc, Bn, 1); SU(Bsrc, Bn, 2); }
    __builtin_amdgcn_s_barrier();
    asm volatile("s_waitcnt lgkmcnt(0)" ::: "memory");
    __builtin_amdgcn_sched_barrier(0);
    __builtin_amdgcn_s_setprio(1);
    #pragma unroll
    for (int n = 0; n < 6; ++n) {
      acc[0][n] = __builtin_amdgcn_mfma_f32_16x16x32_bf16(a0, b[n], acc[0][n], 0, 0, 0);
      acc[1][n] = __builtin_amdgcn_mfma_f32_16x16x32_bf16(a1, b[n], acc[1][n], 0, 0, 0);
    }
    __builtin_amdgcn_s_setprio(0);
    __builtin_amdgcn_s_barrier();

    // ---- ph3: dk=1, mi 2-3 ----
    a0 = LDA(Ab, 2, 1); a1 = LDA(Ab, 3, 1);
    __builtin_amdgcn_s_barrier();
    asm volatile("s_waitcnt lgkmcnt(0)" ::: "memory");
    __builtin_amdgcn_sched_barrier(0);
    __builtin_amdgcn_s_setprio(1);
    #pragma unroll
    for (int n = 0; n < 6; ++n) {
      acc[2][n] = __builtin_amdgcn_mfma_f32_16x16x32_bf16(a0, b[n], acc[2][n], 0, 0, 0);
      acc[3][n] = __builtin_amdgcn_mfma_f32_16x16x32_bf16(a1, b[n], acc[3][n], 0, 0, 0);
    }
    __builtin_amdgcn_s_setprio(0);
    asm volatile("s_waitcnt vmcnt(0)" ::: "memory");
    __builtin_amdgcn_s_barrier();
  }

  if (MODE == 0) {
    float* outp = (float*)Cv;
    #pragma unroll
    for (int mi = 0; mi < 4; ++mi)
      #pragma unroll
      for (int n = 0; n < 6; ++n)
        #pragma unroll
        for (int rr = 0; rr < 4; ++rr) {
          const size_t idx = (size_t)(row0 + wm + mi * 16 + g * 4 + rr) * (size_t)N
                           + (col0 + wn + n * 16 + r);
          outp[idx] = acc[mi][n][rr];
        }
  } else {
    unsigned short* outp = (unsigned short*)Cv;
    const int hc0 = col0 + wn;               // head-aligned (multiple of 96)
    if (hc0 < 3840) {                        // Q or K head: fused RoPE
      #pragma unroll
      for (int mi = 0; mi < 4; ++mi)
        #pragma unroll
        for (int rr = 0; rr < 4; ++rr) {
          const int row = row0 + wm + mi * 16 + g * 4 + rr;
          const int cb = row * 96;
          const size_t rb = (size_t)row * N + hc0;
          #pragma unroll
          for (int n = 0; n < 3; ++n) {
            const int d = n * 16 + r;
            const float x1 = acc[mi][n][rr], x2 = acc[mi][n + 3][rr];
            const float c1 = cs[cb + d], s1 = sn[cb + d];
            const float c2 = cs[cb + d + 48], s2 = sn[cb + d + 48];
            outp[rb + d]      = f2bf(x1 * c1 - x2 * s1);
            outp[rb + d + 48] = f2bf(x2 * c2 + x1 * s2);
          }
        }
    } else if (vtp) {                        // V head: transposed write to vt
      const int kvh = (hc0 - 3840) / 96;
      #pragma unroll
      for (int mi = 0; mi < 4; ++mi) {
        const int rowg = row0 + wm + mi * 16 + g * 4;   // 4 consecutive s
        const int bb = rowg >> 11, s = rowg & 2047;
        #pragma unroll
        for (int n = 0; n < 6; ++n) {
          const int dd = n * 16 + r;
          u16x4 w;
          #pragma unroll
          for (int rr = 0; rr < 4; ++rr) w[rr] = f2bf(acc[mi][n][rr]);
          *(u16x4*)&vtp[((size_t)(bb * 8 + kvh) * 96 + dd) * 2048 + s] = w;
        }
      }
    } else {                                 // V head: plain bf16 to qkv
      #pragma unroll
      for (int mi = 0; mi < 4; ++mi)
        #pragma unroll
        for (int n = 0; n < 6; ++n)
          #pragma unroll
          for (int rr = 0; rr < 4; ++rr) {
            const size_t idx = (size_t)(row0 + wm + mi * 16 + g * 4 + rr) * (size_t)N
                             + (col0 + wn + n * 16 + r);
            outp[idx] = f2bf(acc[mi][n][rr]);
          }
    }
  }
}

// ---------------- V transpose: qkv[b,s,3840+kvh*96+d] -> vt[b,kvh,d,s] ----------------
__global__ __launch_bounds__(256) void vtrans(const unsigned short* __restrict__ qkv,
                                              unsigned short* __restrict__ vt) {
  __shared__ __align__(16) unsigned short T[64 * 104];
  const int s0 = blockIdx.x * 64;
  const int kvh = blockIdx.y, b = blockIdx.z;
  const int tid = threadIdx.x;
  #pragma unroll
  for (int it = 0; it < 3; ++it) {
    const int c = it * 256 + tid;
    const int sr = c / 12, d0 = (c % 12) * 8;
    *(u32x4*)&T[sr * 104 + d0] =
        *(const u32x4*)&qkv[(size_t)(b * 2048 + s0 + sr) * 4608 + 3840 + kvh * 96 + d0];
  }
  __syncthreads();
  #pragma unroll
  for (int it = 0; it < 3; ++it) {
    const int c = it * 256 + tid;
    const int dr = c >> 3, k0 = (c & 7) * 8;
    u16x8 o;
    #pragma unroll
    for (int j = 0; j < 8; ++j) o[j] = T[(k0 + j) * 104 + dr];
    *(u16x8*)&vt[((size_t)(b * 8 + kvh) * 96 + dr) * 2048 + s0 + k0] = o;
  }
}

// ---------------- Flash attention, causal GQA, swapped QK^T ----------------
// r21: r12 body, staged KV tile 128 (grid 256 = 1 block/CU -> 128KB LDS:
// K dbuf 2x24K + V dbuf 2x24K + Ps 32K). Two 64-halves per staged tile;
// barriers/drains per block halved. K swizzle key invariant to +64; V 16
// chunks keyed row&15 (= r at read).
__global__ __launch_bounds__(512) void attn_fwd(const unsigned short* __restrict__ qkv,
                                                const unsigned short* __restrict__ vt,
                                                unsigned short* __restrict__ ctx) {
  __shared__ __align__(16) unsigned short SMEM[65536];  // 128 KB
  const int wg = blockIdx.x;             // 0..255
  const int xcd = wg & 7, j = wg >> 3;   // j 0..31
  const int c = xcd + ((j >> 4) << 3);   // (b,kvh) id, 0..15
  const int b = c >> 3, kvh = c & 7;
  const int rj = j & 15;
  const int h = kvh * 4 + (rj >> 2);
  const int pr = rj & 3;                 // fold pair: qt in {7-pr, pr}
  const int tid = threadIdx.x;
  const int wave = tid >> 6, lane = tid & 63;
  const int g = lane >> 4, r = lane & 15;
  const float kLS = 0.14724445f;         // (1/sqrt(96)) * log2(e)

  const unsigned short* kgbase = qkv + (size_t)(b * 2048) * 4608 + 3072 + kvh * 96;
  const unsigned short* vgbase = vt + (size_t)(b * 8 + kvh) * 96 * 2048;

  // STAGE 128-kv tile t into buffer bi: K 1536 + V 1536 chunks, 6 iters x 512
  auto STAGE = [&](int t, int bi) {
    const int kv0 = t * 128;
    unsigned short* kd = SMEM + bi * 12288;
    unsigned short* vd = SMEM + 24576 + bi * 12288;
    #pragma unroll
    for (int i = 0; i < 3; ++i) {   // K: [dk][row 0..127][c 0..3], src c^((row>>1)&3)
      const int l = i * 512 + tid;
      const int dk = l >> 9, rem = l & 511;
      const int row = rem >> 2, cc = rem & 3;
      const int csrc = cc ^ ((row >> 1) & 3);
      gload_lds16(kgbase + (size_t)(kv0 + row) * 4608 + dk * 32 + csrc * 8, kd + l * 8);
    }
    #pragma unroll
    for (int i = 0; i < 3; ++i) {   // V: [d 0..95][c 0..15], src c^(d&15)
      const int l = i * 512 + tid;
      const int row = l >> 4, cc = l & 15;
      const int csrc = cc ^ (row & 15);
      gload_lds16(vgbase + (size_t)row * 2048 + kv0 + csrc * 8, vd + l * 8);
    }
  };

  #pragma unroll 1
  for (int sel = 0; sel < 2; ++sel) {
    const int qt = sel ? pr : 7 - pr;
    const int nt = qt * 2 + 2;           // 128-wide tiles
    const int q0 = qt * 256 + wave * 32;

    __syncthreads();   // protect LDS (prev epilogue reads) before re-staging

    bf16x8 qf[2][3];
    #pragma unroll
    for (int qb = 0; qb < 2; ++qb)
      #pragma unroll
      for (int dk = 0; dk < 3; ++dk)
        qf[qb][dk] = ld_frag(&qkv[(size_t)(b * 2048 + q0 + qb * 16 + r) * 4608 + h * 96 + dk * 32 + g * 8]);

    f32x4 o[6][2] = {};
    float m_[2] = {-1e30f, -1e30f};
    float l_[2] = {0.f, 0.f};

    STAGE(0, 0);
    __syncthreads();

    for (int t = 0; t < nt; ++t) {
      const int cur = t & 1;
      if (t + 1 < nt) STAGE(t + 1, cur ^ 1);
      const unsigned short* Ks = SMEM + cur * 12288;
      const unsigned short* Vs = SMEM + 24576 + cur * 12288;
      unsigned short* Ps = SMEM + 49152 + wave * 2048;

      #pragma unroll
      for (int hh = 0; hh < 2; ++hh) {
        const int kv0 = t * 128 + hh * 64;
        if (kv0 <= q0 + 31) {  // wave has at least one unmasked element
          f32x4 st[4][2] = {};
          #pragma unroll
          for (int dk = 0; dk < 3; ++dk) {
            bf16x8 af[4];
            #pragma unroll
            for (int kb = 0; kb < 4; ++kb)
              af[kb] = ld_frag(&Ks[dk * 4096 + (hh * 64 + kb * 16 + r) * 32 + ((g ^ ((r >> 1) & 3)) * 8)]);
            __builtin_amdgcn_s_setprio(1);
            #pragma unroll
            for (int kb = 0; kb < 4; ++kb)
              #pragma unroll
              for (int qb = 0; qb < 2; ++qb)
                st[kb][qb] = __builtin_amdgcn_mfma_f32_16x16x32_bf16(af[kb], qf[qb][dk], st[kb][qb], 0, 0, 0);
            __builtin_amdgcn_s_setprio(0);
          }
          // scale (exp2 domain) + causal mask (k_abs <= q_abs)
          if (kv0 + 63 > q0) {
            #pragma unroll
            for (int kb = 0; kb < 4; ++kb)
              #pragma unroll
              for (int qb = 0; qb < 2; ++qb)
                #pragma unroll
                for (int rr = 0; rr < 4; ++rr) {
                  const int ka = kv0 + kb * 16 + g * 4 + rr;
                  const int qa = q0 + qb * 16 + r;
                  const float s = st[kb][qb][rr] * kLS;
                  st[kb][qb][rr] = (ka <= qa) ? s : -1e30f;
                }
          } else {
            #pragma unroll
            for (int kb = 0; kb < 4; ++kb)
              #pragma unroll
              for (int qb = 0; qb < 2; ++qb)
                #pragma unroll
                for (int rr = 0; rr < 4; ++rr)
                  st[kb][qb][rr] *= kLS;
          }
          // online softmax (exp2 domain), per lane = its q column; T13 exact defer
          #pragma unroll
          for (int qb = 0; qb < 2; ++qb) {
            float mx = st[0][qb][0];
            #pragma unroll
            for (int kb = 0; kb < 4; ++kb)
              #pragma unroll
              for (int rr = 0; rr < 4; ++rr) mx = fmaxf(mx, st[kb][qb][rr]);
            mx = fmaxf(mx, __shfl_xor(mx, 16));
            mx = fmaxf(mx, __shfl_xor(mx, 32));
            if (__all(mx <= m_[qb])) {
              float rs = 0.f;
              #pragma unroll
              for (int kb = 0; kb < 4; ++kb)
                #pragma unroll
                for (int rr = 0; rr < 4; ++rr) {
                  const float p = __builtin_amdgcn_exp2f(st[kb][qb][rr] - m_[qb]);
                  st[kb][qb][rr] = p;
                  rs += p;
                }
              rs += __shfl_xor(rs, 16);
              rs += __shfl_xor(rs, 32);
              l_[qb] += rs;
            } else {
              const float mnew = fmaxf(m_[qb], mx);
              const float corr = __builtin_amdgcn_exp2f(m_[qb] - mnew);
              m_[qb] = mnew;
              float rs = 0.f;
              #pragma unroll
              for (int kb = 0; kb < 4; ++kb)
                #pragma unroll
                for (int rr = 0; rr < 4; ++rr) {
                  const float p = __builtin_amdgcn_exp2f(st[kb][qb][rr] - mnew);
                  st[kb][qb][rr] = p;
                  rs += p;
                }
              rs += __shfl_xor(rs, 16);
              rs += __shfl_xor(rs, 32);
              l_[qb] = l_[qb] * corr + rs;
              #pragma unroll
              for (int db = 0; db < 6; ++db) o[db][qb] *= corr;
            }
          }
          // P[q][k] (bf16) to per-wave LDS, swizzled (64-wide)
          #pragma unroll
          for (int kb = 0; kb < 4; ++kb)
            #pragma unroll
            for (int qb = 0; qb < 2; ++qb) {
              u16x4 w;
              #pragma unroll
              for (int rr = 0; rr < 4; ++rr) w[rr] = f2bf(st[kb][qb][rr]);
              const int q = qb * 16 + r;
              *(u16x4*)&Ps[q * 64 + (((2 * kb + (g >> 1)) ^ (r & 7)) << 3) + (g & 1) * 4] = w;
            }
          // O^T += V^T * P^T  (V rows 128-wide, chunk (hh*8+kk*4+g)^r)
          #pragma unroll
          for (int kk = 0; kk < 2; ++kk) {
            bf16x8 pb[2];
            #pragma unroll
            for (int qb = 0; qb < 2; ++qb)
              pb[qb] = ld_frag(&Ps[(qb * 16 + r) * 64 + ((kk * 4 + g) ^ (r & 7)) * 8]);
            __builtin_amdgcn_s_setprio(1);
            #pragma unroll
            for (int db = 0; db < 6; ++db) {
              const bf16x8 va = ld_frag(&Vs[(db * 16 + r) * 128 + (((hh * 8 + kk * 4 + g) ^ r) * 8)]);
              #pragma unroll
              for (int qb = 0; qb < 2; ++qb)
                o[db][qb] = __builtin_amdgcn_mfma_f32_16x16x32_bf16(va, pb[qb], o[db][qb], 0, 0, 0);
            }
            __builtin_amdgcn_s_setprio(0);
          }
        }
      }
      __syncthreads();
    }

    // epilogue: normalize, transpose through LDS (per-wave region), coalesced stores
    const float inv_l[2] = {1.f / l_[0], 1.f / l_[1]};
    unsigned short* obuf = SMEM + wave * 3328;  // 32 x 104 per wave
    #pragma unroll
    for (int db = 0; db < 6; ++db)
      #pragma unroll
      for (int qb = 0; qb < 2; ++qb) {
        u16x4 w;
        #pragma unroll
        for (int rr = 0; rr < 4; ++rr) w[rr] = f2bf(o[db][qb][rr] * inv_l[qb]);
        *(u16x4*)&obuf[(qb * 16 + r) * 104 + db * 16 + g * 4] = w;
      }
    #pragma unroll
    for (int it = 0; it < 6; ++it) {
      const int cc = it * 64 + lane;
      const int qr = cc / 12, d0 = (cc % 12) * 8;
      *(u32x4*)&ctx[(size_t)(b * 2048 + q0 - wave * 32 + wave * 32 + qr) * 3072 + h * 96 + d0] =
          *(const u32x4*)&obuf[qr * 104 + d0];
    }
  }
}

extern "C" void kernel_launch(void* const* d_in, const int* in_sizes, int n_in,
                              void* d_out, int out_size, void* d_ws, size_t ws_size,
                              hipStream_t stream) {
  const float* hs   = (const float*)d_in[0];
  const float* cosp = (const float*)d_in[1];
  const float* sinp = (const float*)d_in[2];
  const float* wqkv = (const float*)d_in[4];
  const float* wo   = (const float*)d_in[5];
  float* out = (float*)d_out;

  // workspace (bf16 elems): qkv 18,874,368 | hsb 12,582,912 | wqb 14,155,776
  // big_ws : wob fresh after wqb (in-gemm1 tail-fill, no alias).
  // big_ws2: vt fresh after wob (in-gemm1 transposed V write — vt must NOT
  //          alias hsb while gemm1 reads it; r16 lesson). Fallbacks preserve
  //          r18/r12 orderings. ws_size constant across calls -> deterministic.
  unsigned short* qkv = (unsigned short*)d_ws;
  unsigned short* hsb = qkv + 18874368;
  unsigned short* wqb = hsb + 12582912;
  unsigned short* ctx = wqb;

  const bool big_ws  = ws_size >= (size_t)110100480;
  const bool big_ws2 = ws_size >= (size_t)116391936;
  unsigned short* wob = big_ws ? (wqb + 14155776) : (hsb + 3145728);
  unsigned short* vt  = big_ws2 ? (wob + 9437184) : hsb;

  // hs: 12,582,912 f32 = 1,572,864 x8; wqkv: 14,155,776 f32 = 1,769,472 x8
  cvt2_bf16<<<13056, 256, 0, stream>>>(hs, hsb, 1572864, wqkv, wqb, 1769472);
  if (big_ws) {
    gemm8p<1><<<512, 512, 0, stream>>>(hsb, wqb, (void*)qkv, cosp, sinp, 4096, 4608, 3072,
                                       wo, wob, 2359296, 384, big_ws2 ? vt : nullptr);
  } else {
    gemm8p<1><<<384, 512, 0, stream>>>(hsb, wqb, (void*)qkv, cosp, sinp, 4096, 4608, 3072,
                                       nullptr, nullptr, 0, 384, nullptr);
    cvt_bf16<<<9216, 256, 0, stream>>>(wo, wob, 2359296);
  }
  if (!big_ws2) {
    vtrans<<<dim3(32, 8, 2), 256, 0, stream>>>(qkv, vt);
  }
  attn_fwd<<<256, 512, 0, stream>>>(qkv, vt, ctx);
  gemm8p<0><<<256, 512, 0, stream>>>(ctx, wob, (void*)out, cosp, sinp, 4096, 3072, 3072,
                                     nullptr, nullptr, 0, 256, nullptr);
}